// Round 1
// baseline (3366.213 us; speedup 1.0000x reference)
//
#include <hip/hip_runtime.h>
#include <math.h>

#define VN 9
#define NVOX 131072
#define GS 96
static constexpr float INVS = 0.9999950000374997f; // 1/sqrt(1+1e-5)

__device__ inline float4 ld4(const float* p){ return *reinterpret_cast<const float4*>(p); }
__device__ inline void st4(float* p, float4 v){ *reinterpret_cast<float4*>(p) = v; }

__device__ inline float grp_sum32(float v){
  v += __shfl_xor(v, 1, 32);
  v += __shfl_xor(v, 2, 32);
  v += __shfl_xor(v, 4, 32);
  v += __shfl_xor(v, 8, 32);
  v += __shfl_xor(v, 16, 32);
  return v;
}

// ---------------- weight transpose: [Co][Ci][K][K] -> [K*K][Ci][Co] ----------------
__global__ void k_wtrans(const float* __restrict__ in, float* __restrict__ out,
                         int Cout, int Cin, int K){
  int tid = blockIdx.x*256 + threadIdx.x;
  int total = Cout*Cin*K*K;
  if (tid >= total) return;
  int kk = tid % (K*K);
  int ci = (tid / (K*K)) % Cin;
  int co = tid / (K*K*Cin);
  out[(kk*Cin + ci)*Cout + co] = in[tid];
}

// ---------------- NCHW -> NHWC ----------------
__global__ void k_nhwc(const float* __restrict__ in, float* __restrict__ out,
                       int C, int H, int W, int total){
  int tid = blockIdx.x*256 + threadIdx.x;
  if (tid >= total) return;
  int c = tid % C;
  int x = (tid / C) % W;
  int y = (tid / (C*W)) % H;
  int v = tid / (C*W*H);
  out[tid] = in[((v*C + c)*H + y)*W + x];
}

// ---------------- direct conv NHWC, 4 outputs/thread, relu, optional residual ------
__global__ __launch_bounds__(256) void k_conv(
    const float* __restrict__ in, int Cin, int inStride,
    const float* __restrict__ wt, const float* __restrict__ bias,
    float* __restrict__ out, int Cout, int outStride, int outOff,
    int H, int W, int K, int addskip, int total){
  int tid = blockIdx.x*256 + threadIdx.x;
  if (tid >= total) return;
  int Co4 = Cout >> 2;
  int c4 = tid % Co4;
  int x  = (tid / Co4) % W;
  int y  = (tid / (Co4*W)) % H;
  int v  = tid / (Co4*W*H);
  int co = c4*4;
  float4 acc = ld4(bias + co);
  int pad = K >> 1;
  for (int ky = 0; ky < K; ++ky){
    int yy = y + ky - pad;
    if ((unsigned)yy >= (unsigned)H) continue;
    for (int kx = 0; kx < K; ++kx){
      int xx = x + kx - pad;
      if ((unsigned)xx >= (unsigned)W) continue;
      const float* ip = in + ((size_t)(v*H + yy)*W + xx)*inStride;
      const float* wp = wt + ((size_t)(ky*K + kx)*Cin)*Cout + co;
      #pragma unroll 4
      for (int ci = 0; ci < Cin; ++ci){
        float a = ip[ci];
        float4 wv = ld4(wp + (size_t)ci*Cout);
        acc.x += a*wv.x; acc.y += a*wv.y; acc.z += a*wv.z; acc.w += a*wv.w;
      }
    }
  }
  float4 r;
  r.x = fmaxf(acc.x, 0.f); r.y = fmaxf(acc.y, 0.f);
  r.z = fmaxf(acc.z, 0.f); r.w = fmaxf(acc.w, 0.f);
  if (addskip){
    const float* sp = in + ((size_t)(v*H + y)*W + x)*inStride + co;
    float4 sv = ld4(sp);
    r.x += sv.x; r.y += sv.y; r.z += sv.z; r.w += sv.w;
  }
  st4(out + ((size_t)(v*H + y)*W + x)*outStride + outOff + co, r);
}

// ---------------- bilinear 2x upsample (jax.image.resize semantics) ----------------
// in t1: (V,30,40,80) -> write fuse_cat (V,60,80,144) channels [0,80)
__global__ void k_resize(const float* __restrict__ t1, float* __restrict__ fc, int total){
  int tid = blockIdx.x*256 + threadIdx.x;
  if (tid >= total) return;
  int c4 = tid % 20;
  int x  = (tid / 20) % 80;
  int y  = (tid / 1600) % 60;
  int v  = tid / 96000;
  int c = c4*4;
  int ky = y >> 1; int y0, y1; float wy0, wy1;
  if ((y & 1) == 0){ y0 = ky-1; y1 = ky; wy0 = 0.25f; wy1 = 0.75f; if (y0 < 0){ y0 = 0; wy0 = 0.f; wy1 = 1.f; } }
  else             { y0 = ky; y1 = ky+1; wy0 = 0.75f; wy1 = 0.25f; if (y1 > 29){ y1 = 29; wy1 = 0.f; wy0 = 1.f; } }
  int kx = x >> 1; int x0, x1; float wx0, wx1;
  if ((x & 1) == 0){ x0 = kx-1; x1 = kx; wx0 = 0.25f; wx1 = 0.75f; if (x0 < 0){ x0 = 0; wx0 = 0.f; wx1 = 1.f; } }
  else             { x0 = kx; x1 = kx+1; wx0 = 0.75f; wx1 = 0.25f; if (x1 > 39){ x1 = 39; wx1 = 0.f; wx0 = 1.f; } }
  float4 a00 = ld4(t1 + ((size_t)(v*30 + y0)*40 + x0)*80 + c);
  float4 a01 = ld4(t1 + ((size_t)(v*30 + y0)*40 + x1)*80 + c);
  float4 a10 = ld4(t1 + ((size_t)(v*30 + y1)*40 + x0)*80 + c);
  float4 a11 = ld4(t1 + ((size_t)(v*30 + y1)*40 + x1)*80 + c);
  float w00 = wy0*wx0, w01 = wy0*wx1, w10 = wy1*wx0, w11 = wy1*wx1;
  float4 r;
  r.x = w00*a00.x + w01*a01.x + w10*a10.x + w11*a11.x;
  r.y = w00*a00.y + w01*a01.y + w10*a10.y + w11*a11.y;
  r.z = w00*a00.z + w01*a01.z + w10*a10.z + w11*a11.z;
  r.w = w00*a00.w + w01*a01.w + w10*a10.w + w11*a11.w;
  st4(fc + ((size_t)(v*60 + y)*80 + x)*144 + c, r);
}

// ---------------- 2x2 avg pool: t4 (V,120,160,24) -> fuse_cat channels [120,144) ---
__global__ void k_pool(const float* __restrict__ t4, float* __restrict__ fc, int total){
  int tid = blockIdx.x*256 + threadIdx.x;
  if (tid >= total) return;
  int c4 = tid % 6;
  int x  = (tid / 6) % 80;
  int y  = (tid / 480) % 60;
  int v  = tid / 28800;
  int c = c4*4;
  const float* b0 = t4 + ((size_t)(v*120 + 2*y)*160 + 2*x)*24 + c;
  float4 a = ld4(b0), b = ld4(b0 + 24), cc = ld4(b0 + 160*24), d = ld4(b0 + 160*24 + 24);
  float4 r;
  r.x = 0.25f*(a.x + b.x + cc.x + d.x);
  r.y = 0.25f*(a.y + b.y + cc.y + d.y);
  r.z = 0.25f*(a.z + b.z + cc.z + d.z);
  r.w = 0.25f*(a.w + b.w + cc.w + d.w);
  st4(fc + ((size_t)(v*60 + y)*80 + x)*144 + 120 + c, r);
}

// ---------------- grid scatter + coords passthrough ----------------
__global__ void k_scatter(const int* __restrict__ coords, const int* __restrict__ stage,
                          int* __restrict__ grid, int* __restrict__ scn,
                          float* __restrict__ coords_out){
  int n = blockIdx.x*256 + threadIdx.x;
  if (n >= NVOX) return;
  int c0 = coords[n*4], c1 = coords[n*4+1], c2 = coords[n*4+2], c3 = coords[n*4+3];
  coords_out[n*4+0] = (float)c0;
  coords_out[n*4+1] = (float)c1;
  coords_out[n*4+2] = (float)c2;
  coords_out[n*4+3] = (float)c3;
  int sh = 2 - stage[0];
  int s1 = c1 >> sh, s2 = c2 >> sh, s3 = c3 >> sh;
  scn[n*3+0] = s1; scn[n*3+1] = s2; scn[n*3+2] = s3;
  grid[(s1*GS + s2)*GS + s3] = n;
}

// ---------------- projection + bilinear sample + masked mean/var + bn0 -------------
__global__ __launch_bounds__(256) void k_sample(
    const float* __restrict__ fuse, const int* __restrict__ coords,
    const float* __restrict__ origin, const float* __restrict__ vsz,
    const float* __restrict__ KR, const float* __restrict__ bn0g,
    const float* __restrict__ bn0b, float* __restrict__ F0, float* __restrict__ cnt){
  int vox = blockIdx.x*8 + (threadIdx.x >> 5);
  int c = threadIdx.x & 31;
  float vs = vsz[0];
  float wx = (float)coords[vox*4+1]*vs + origin[0];
  float wy = (float)coords[vox*4+2]*vs + origin[1];
  float wz = (float)coords[vox*4+3]*vs + origin[2];
  float s = 0.f, s2 = 0.f, den = 0.f;
  for (int v = 0; v < VN; ++v){
    const float* P = KR + v*12;
    float ix = P[0]*wx + P[1]*wy + P[2]*wz + P[3];
    float iy = P[4]*wx + P[5]*wy + P[6]*wz + P[7];
    float iz = P[8]*wx + P[9]*wy + P[10]*wz + P[11];
    float gx = 2.f*(ix/iz)/159.f - 1.f;
    float gy = 2.f*(iy/iz)/119.f - 1.f;
    bool msk = (fabsf(gx) <= 1.f) && (fabsf(gy) <= 1.f) && (iz > 0.f);
    if (msk){
      float px = (gx + 1.f)*0.5f*79.f;
      float py = (gy + 1.f)*0.5f*59.f;
      float x0f = floorf(px), y0f = floorf(py);
      int x0 = (int)x0f, y0 = (int)y0f;
      float fx = px - x0f, fy = py - y0f;
      const float* base = fuse + (size_t)(v*60*80)*32 + c;
      float g = 0.f;
      if (x0   >= 0 && x0   <= 79 && y0   >= 0 && y0   <= 59) g += base[((size_t)y0*80 + x0  )*32] * ((1.f-fx)*(1.f-fy));
      if (x0+1 >= 0 && x0+1 <= 79 && y0   >= 0 && y0   <= 59) g += base[((size_t)y0*80 + x0+1)*32] * (fx*(1.f-fy));
      if (x0   >= 0 && x0   <= 79 && y0+1 >= 0 && y0+1 <= 59) g += base[((size_t)(y0+1)*80 + x0  )*32] * ((1.f-fx)*fy);
      if (x0+1 >= 0 && x0+1 <= 79 && y0+1 >= 0 && y0+1 <= 59) g += base[((size_t)(y0+1)*80 + x0+1)*32] * (fx*fy);
      s += g; s2 += g*g; den += 1.f;
    }
  }
  float mean = s/den;
  float var = fmaxf(s2/den - mean*mean, 0.f);
  F0[(size_t)vox*32 + c] = bn0g[c]*var*INVS + bn0b[c];
  if (c == 0) cnt[vox] = den;
}

// ---------------- subm sparse conv 32->32, 8 voxels/thread --------------------------
// MODE 0: out = relu(subm(in));  MODE 1: out = LN(relu(subm(in)) + in)
template<int MODE>
__global__ __launch_bounds__(256) void k_subm(
    const float* __restrict__ fin, const float* __restrict__ w,
    const int* __restrict__ scn, const int* __restrict__ grid,
    const float* __restrict__ lng, const float* __restrict__ lnb,
    float* __restrict__ fout){
  int j = threadIdx.x & 31;
  int g = threadIdx.x >> 5;
  int vbase = blockIdx.x*64 + g*8;
  int sx[8], sy[8], sz[8];
  #pragma unroll
  for (int r = 0; r < 8; ++r){
    sx[r] = scn[(vbase+r)*3+0];
    sy[r] = scn[(vbase+r)*3+1];
    sz[r] = scn[(vbase+r)*3+2];
  }
  float acc[8] = {0.f,0.f,0.f,0.f,0.f,0.f,0.f,0.f};
  #pragma unroll 1
  for (int k = 0; k < 27; ++k){
    int dx = k/9 - 1, dy = (k/3)%3 - 1, dz = k%3 - 1;
    float f[8];
    #pragma unroll
    for (int r = 0; r < 8; ++r){
      int nx = sx[r]+dx, ny = sy[r]+dy, nz = sz[r]+dz;
      float fv = 0.f;
      if (((unsigned)nx < 96u) && ((unsigned)ny < 96u) && ((unsigned)nz < 96u)){
        int idx = grid[(nx*GS + ny)*GS + nz];
        if (idx >= 0) fv = fin[(size_t)idx*32 + j];
      }
      f[r] = fv;
    }
    const float* wk = w + k*1024 + j;
    #pragma unroll
    for (int c = 0; c < 32; ++c){
      float wv = wk[c*32];
      #pragma unroll
      for (int r = 0; r < 8; ++r)
        acc[r] += __shfl(f[r], c, 32) * wv;
    }
  }
  #pragma unroll
  for (int r = 0; r < 8; ++r){
    int vox = vbase + r;
    float x = fmaxf(acc[r], 0.f);
    if (MODE == 1){
      x += fin[(size_t)vox*32 + j];
      float m = grp_sum32(x) * (1.f/32.f);
      float d = x - m;
      float var = grp_sum32(d*d) * (1.f/32.f);
      x = d / sqrtf(var + 1e-5f) * lng[j] + lnb[j];
    }
    fout[(size_t)vox*32 + j] = x;
  }
}

// ---------------- final subm 32->1 + bn ----------------
__global__ __launch_bounds__(256) void k_subm_s4(
    const float* __restrict__ fin, const float* __restrict__ w4,
    const int* __restrict__ scn, const int* __restrict__ grid,
    const float* __restrict__ bn4g, const float* __restrict__ bn4b,
    float* __restrict__ occ){
  int c = threadIdx.x & 31;
  int g = threadIdx.x >> 5;
  int vbase = blockIdx.x*64 + g*8;
  int sx[8], sy[8], sz[8];
  #pragma unroll
  for (int r = 0; r < 8; ++r){
    sx[r] = scn[(vbase+r)*3+0];
    sy[r] = scn[(vbase+r)*3+1];
    sz[r] = scn[(vbase+r)*3+2];
  }
  float acc[8] = {0.f,0.f,0.f,0.f,0.f,0.f,0.f,0.f};
  #pragma unroll 1
  for (int k = 0; k < 27; ++k){
    int dx = k/9 - 1, dy = (k/3)%3 - 1, dz = k%3 - 1;
    float wv = w4[k*32 + c];
    #pragma unroll
    for (int r = 0; r < 8; ++r){
      int nx = sx[r]+dx, ny = sy[r]+dy, nz = sz[r]+dz;
      float fv = 0.f;
      if (((unsigned)nx < 96u) && ((unsigned)ny < 96u) && ((unsigned)nz < 96u)){
        int idx = grid[(nx*GS + ny)*GS + nz];
        if (idx >= 0) fv = fin[(size_t)idx*32 + c];
      }
      acc[r] += fv * wv;
    }
  }
  #pragma unroll
  for (int r = 0; r < 8; ++r){
    float s = grp_sum32(acc[r]);
    if (c == 0) occ[vbase + r] = bn4g[0]*s*INVS + bn4b[0];
  }
}

extern "C" void kernel_launch(void* const* d_in, const int* in_sizes, int n_in,
                              void* d_out, int out_size, void* d_ws, size_t ws_size,
                              hipStream_t stream){
  const float* feats1 = (const float*)d_in[0];
  const float* feats2 = (const float*)d_in[1];
  const float* feats4 = (const float*)d_in[2];
  const int*   coords = (const int*)d_in[3];
  const float* origin = (const float*)d_in[4];
  const float* vsz    = (const float*)d_in[5];
  const float* KR     = (const float*)d_in[6];
  const float* w_f1 = (const float*)d_in[7];  const float* b_f1 = (const float*)d_in[8];
  const float* w_f2 = (const float*)d_in[9];  const float* b_f2 = (const float*)d_in[10];
  const float* w_f4 = (const float*)d_in[11]; const float* b_f4 = (const float*)d_in[12];
  const float* w_dn = (const float*)d_in[13]; const float* b_dn = (const float*)d_in[14];
  const float* w_p[4] = {(const float*)d_in[15], (const float*)d_in[17],
                         (const float*)d_in[19], (const float*)d_in[21]};
  const float* b_p[4] = {(const float*)d_in[16], (const float*)d_in[18],
                         (const float*)d_in[20], (const float*)d_in[22]};
  const float* bn0g = (const float*)d_in[23]; const float* bn0b = (const float*)d_in[24];
  const float* w_elan = (const float*)d_in[25];
  const float* w_s1 = (const float*)d_in[26]; const float* ln1g = (const float*)d_in[27]; const float* ln1b = (const float*)d_in[28];
  const float* w_s2 = (const float*)d_in[29]; const float* ln2g = (const float*)d_in[30]; const float* ln2b = (const float*)d_in[31];
  const float* w_s3 = (const float*)d_in[32]; const float* ln3g = (const float*)d_in[33]; const float* ln3b = (const float*)d_in[34];
  const float* w_s4 = (const float*)d_in[35]; const float* bn4g = (const float*)d_in[36]; const float* bn4b = (const float*)d_in[37];
  const int* stage  = (const int*)d_in[38];
  float* out = (float*)d_out;
  float* ws  = (float*)d_ws;

  // workspace layout (floats); B0/B1 alias early phase-A buffers (dead by then)
  float* B0    = ws + 0;
  float* B1    = ws + 4194304;
  float* nhwc1 = ws + 0;
  float* t1    = ws + 864000;
  float* nhwc2 = ws + 1728000;
  float* nhwc4 = ws + 3456000;
  float* t4    = ws + 7603200;
  float* fcat  = ws + 11750400;
  float* A     = ws + 17971200;
  float* B     = ws + 19353600;
  float* wtf1  = ws + 20736000;
  float* wtf2  = ws + 20793600;
  float* wtf4  = ws + 20808000;
  float* wtdn  = ws + 20813184;
  float* wtp0  = ws + 20817792;
  float* wtp1  = ws + 20827008;
  float* wtp2  = ws + 20836224;
  float* wtp3  = ws + 20845440;
  int*   grid  = (int*)(ws + 20854656);
  int*   scn   = (int*)(ws + 21739392);

  auto nb = [](int total){ return (total + 255)/256; };

  // weight transposes
  k_wtrans<<<nb(80*80*9),256,0,stream>>>(w_f1, wtf1, 80, 80, 3);
  k_wtrans<<<nb(40*40*9),256,0,stream>>>(w_f2, wtf2, 40, 40, 3);
  k_wtrans<<<nb(24*24*9),256,0,stream>>>(w_f4, wtf4, 24, 24, 3);
  k_wtrans<<<nb(32*144),256,0,stream>>>(w_dn, wtdn, 32, 144, 1);
  k_wtrans<<<nb(32*32*9),256,0,stream>>>(w_p[0], wtp0, 32, 32, 3);
  k_wtrans<<<nb(32*32*9),256,0,stream>>>(w_p[1], wtp1, 32, 32, 3);
  k_wtrans<<<nb(32*32*9),256,0,stream>>>(w_p[2], wtp2, 32, 32, 3);
  k_wtrans<<<nb(32*32*9),256,0,stream>>>(w_p[3], wtp3, 32, 32, 3);

  // NCHW -> NHWC
  { int t = 9*80*30*40;   k_nhwc<<<nb(t),256,0,stream>>>(feats1, nhwc1, 80, 30, 40, t); }
  { int t = 9*40*60*80;   k_nhwc<<<nb(t),256,0,stream>>>(feats2, nhwc2, 40, 60, 80, t); }
  { int t = 9*24*120*160; k_nhwc<<<nb(t),256,0,stream>>>(feats4, nhwc4, 24, 120, 160, t); }

  // feature head convs
  { int t = 9*30*40*20;   k_conv<<<nb(t),256,0,stream>>>(nhwc1, 80, 80, wtf1, b_f1, t1,   80, 80, 0,  30, 40, 3, 0, t); }
  { int t = 9*60*80*10;   k_conv<<<nb(t),256,0,stream>>>(nhwc2, 40, 40, wtf2, b_f2, fcat, 40, 144, 80, 60, 80, 3, 0, t); }
  { int t = 9*120*160*6;  k_conv<<<nb(t),256,0,stream>>>(nhwc4, 24, 24, wtf4, b_f4, t4,   24, 24, 0, 120, 160, 3, 0, t); }

  // resize + pool into concat buffer
  { int t = 9*60*80*20;   k_resize<<<nb(t),256,0,stream>>>(t1, fcat, t); }
  { int t = 9*60*80*6;    k_pool<<<nb(t),256,0,stream>>>(t4, fcat, t); }

  // down conv (1x1) and 4 residual blocks: A -> B -> A -> B -> A
  { int t = 9*60*80*8;
    k_conv<<<nb(t),256,0,stream>>>(fcat, 144, 144, wtdn, b_dn, A, 32, 32, 0, 60, 80, 1, 0, t);
    k_conv<<<nb(t),256,0,stream>>>(A, 32, 32, wtp0, b_p[0], B, 32, 32, 0, 60, 80, 3, 1, t);
    k_conv<<<nb(t),256,0,stream>>>(B, 32, 32, wtp1, b_p[1], A, 32, 32, 0, 60, 80, 3, 1, t);
    k_conv<<<nb(t),256,0,stream>>>(A, 32, 32, wtp2, b_p[2], B, 32, 32, 0, 60, 80, 3, 1, t);
    k_conv<<<nb(t),256,0,stream>>>(B, 32, 32, wtp3, b_p[3], A, 32, 32, 0, 60, 80, 3, 1, t);
  }

  // dense grid build
  hipMemsetAsync(grid, 0xFF, (size_t)GS*GS*GS*sizeof(int), stream);
  k_scatter<<<nb(NVOX),256,0,stream>>>(coords, stage, grid, scn, out + NVOX);

  // per-voxel sampling -> F0 (B0) + count
  k_sample<<<NVOX/8,256,0,stream>>>(A, coords, origin, vsz, KR, bn0g, bn0b, B0, out + 5*NVOX);

  // subm conv stack
  k_subm<0><<<NVOX/64,256,0,stream>>>(B0, w_elan, scn, grid, nullptr, nullptr, B1);
  k_subm<1><<<NVOX/64,256,0,stream>>>(B1, w_s1, scn, grid, ln1g, ln1b, B0);
  k_subm<1><<<NVOX/64,256,0,stream>>>(B0, w_s2, scn, grid, ln2g, ln2b, B1);
  k_subm<1><<<NVOX/64,256,0,stream>>>(B1, w_s3, scn, grid, ln3g, ln3b, B0);
  k_subm_s4<<<NVOX/64,256,0,stream>>>(B0, w_s4, scn, grid, bn4g, bn4b, out);
}

// Round 2
// 1081.699 us; speedup vs baseline: 3.1120x; 3.1120x over previous
//
#include <hip/hip_runtime.h>
#include <math.h>

#define VN 9
#define NVOX 131072
#define GS 96
static constexpr float INVS = 0.9999950000374997f; // 1/sqrt(1+1e-5)

typedef short bf16x8 __attribute__((ext_vector_type(8)));
typedef float f32x4v __attribute__((ext_vector_type(4)));

__device__ inline float4 ld4(const float* p){ return *reinterpret_cast<const float4*>(p); }
__device__ inline void st4(float* p, float4 v){ *reinterpret_cast<float4*>(p) = v; }

__device__ inline ushort f2b(float f){
  unsigned u = __float_as_uint(f);
  unsigned r = (u + 0x7fffu + ((u >> 16) & 1u)) >> 16;
  return (ushort)r;
}
__device__ inline float b2f(ushort s){ return __uint_as_float(((unsigned)s) << 16); }
__device__ inline float blo(unsigned u){ return __uint_as_float(u << 16); }
__device__ inline float bhi(unsigned u){ return __uint_as_float(u & 0xffff0000u); }

// ---------------- weight transpose: [Co][Ci][K][K] -> [K*K][Ci][Co] ----------------
__global__ void k_wtrans(const float* __restrict__ in, float* __restrict__ out,
                         int Cout, int Cin, int K){
  int tid = blockIdx.x*256 + threadIdx.x;
  int total = Cout*Cin*K*K;
  if (tid >= total) return;
  int kk = tid % (K*K);
  int ci = (tid / (K*K)) % Cin;
  int co = tid / (K*K*Cin);
  out[(kk*Cin + ci)*Cout + co] = in[tid];
}

// ---------------- subm weight prep: fp32 [27][ci][co] -> bf16 [27][co][ci] ---------
__global__ void k_wprep(const float* __restrict__ w, ushort* __restrict__ o){
  int tid = blockIdx.x*256 + threadIdx.x;
  if (tid >= 27*1024) return;
  int k = tid >> 10;
  int r = tid & 1023;
  int co = r >> 5;
  int ci = r & 31;
  o[tid] = f2b(w[k*1024 + ci*32 + co]);
}

// ---------------- NCHW -> NHWC ----------------
__global__ void k_nhwc(const float* __restrict__ in, float* __restrict__ out,
                       int C, int H, int W, int total){
  int tid = blockIdx.x*256 + threadIdx.x;
  if (tid >= total) return;
  int c = tid % C;
  int x = (tid / C) % W;
  int y = (tid / (C*W)) % H;
  int v = tid / (C*W*H);
  out[tid] = in[((v*C + c)*H + y)*W + x];
}

// ---------------- direct conv NHWC, 4 outputs/thread, relu, optional residual ------
__global__ __launch_bounds__(256) void k_conv(
    const float* __restrict__ in, int Cin, int inStride,
    const float* __restrict__ wt, const float* __restrict__ bias,
    float* __restrict__ out, int Cout, int outStride, int outOff,
    int H, int W, int K, int addskip, int total){
  int tid = blockIdx.x*256 + threadIdx.x;
  if (tid >= total) return;
  int Co4 = Cout >> 2;
  int c4 = tid % Co4;
  int x  = (tid / Co4) % W;
  int y  = (tid / (Co4*W)) % H;
  int v  = tid / (Co4*W*H);
  int co = c4*4;
  float4 acc = ld4(bias + co);
  int pad = K >> 1;
  for (int ky = 0; ky < K; ++ky){
    int yy = y + ky - pad;
    if ((unsigned)yy >= (unsigned)H) continue;
    for (int kx = 0; kx < K; ++kx){
      int xx = x + kx - pad;
      if ((unsigned)xx >= (unsigned)W) continue;
      const float* ip = in + ((size_t)(v*H + yy)*W + xx)*inStride;
      const float* wp = wt + ((size_t)(ky*K + kx)*Cin)*Cout + co;
      #pragma unroll 4
      for (int ci = 0; ci < Cin; ++ci){
        float a = ip[ci];
        float4 wv = ld4(wp + (size_t)ci*Cout);
        acc.x += a*wv.x; acc.y += a*wv.y; acc.z += a*wv.z; acc.w += a*wv.w;
      }
    }
  }
  float4 r;
  r.x = fmaxf(acc.x, 0.f); r.y = fmaxf(acc.y, 0.f);
  r.z = fmaxf(acc.z, 0.f); r.w = fmaxf(acc.w, 0.f);
  if (addskip){
    const float* sp = in + ((size_t)(v*H + y)*W + x)*inStride + co;
    float4 sv = ld4(sp);
    r.x += sv.x; r.y += sv.y; r.z += sv.z; r.w += sv.w;
  }
  st4(out + ((size_t)(v*H + y)*W + x)*outStride + outOff + co, r);
}

// ---------------- bilinear 2x upsample (jax.image.resize semantics) ----------------
__global__ void k_resize(const float* __restrict__ t1, float* __restrict__ fc, int total){
  int tid = blockIdx.x*256 + threadIdx.x;
  if (tid >= total) return;
  int c4 = tid % 20;
  int x  = (tid / 20) % 80;
  int y  = (tid / 1600) % 60;
  int v  = tid / 96000;
  int c = c4*4;
  int ky = y >> 1; int y0, y1; float wy0, wy1;
  if ((y & 1) == 0){ y0 = ky-1; y1 = ky; wy0 = 0.25f; wy1 = 0.75f; if (y0 < 0){ y0 = 0; wy0 = 0.f; wy1 = 1.f; } }
  else             { y0 = ky; y1 = ky+1; wy0 = 0.75f; wy1 = 0.25f; if (y1 > 29){ y1 = 29; wy1 = 0.f; wy0 = 1.f; } }
  int kx = x >> 1; int x0, x1; float wx0, wx1;
  if ((x & 1) == 0){ x0 = kx-1; x1 = kx; wx0 = 0.25f; wx1 = 0.75f; if (x0 < 0){ x0 = 0; wx0 = 0.f; wx1 = 1.f; } }
  else             { x0 = kx; x1 = kx+1; wx0 = 0.75f; wx1 = 0.25f; if (x1 > 39){ x1 = 39; wx1 = 0.f; wx0 = 1.f; } }
  float4 a00 = ld4(t1 + ((size_t)(v*30 + y0)*40 + x0)*80 + c);
  float4 a01 = ld4(t1 + ((size_t)(v*30 + y0)*40 + x1)*80 + c);
  float4 a10 = ld4(t1 + ((size_t)(v*30 + y1)*40 + x0)*80 + c);
  float4 a11 = ld4(t1 + ((size_t)(v*30 + y1)*40 + x1)*80 + c);
  float w00 = wy0*wx0, w01 = wy0*wx1, w10 = wy1*wx0, w11 = wy1*wx1;
  float4 r;
  r.x = w00*a00.x + w01*a01.x + w10*a10.x + w11*a11.x;
  r.y = w00*a00.y + w01*a01.y + w10*a10.y + w11*a11.y;
  r.z = w00*a00.z + w01*a01.z + w10*a10.z + w11*a11.z;
  r.w = w00*a00.w + w01*a01.w + w10*a10.w + w11*a11.w;
  st4(fc + ((size_t)(v*60 + y)*80 + x)*144 + c, r);
}

// ---------------- 2x2 avg pool ----------------
__global__ void k_pool(const float* __restrict__ t4, float* __restrict__ fc, int total){
  int tid = blockIdx.x*256 + threadIdx.x;
  if (tid >= total) return;
  int c4 = tid % 6;
  int x  = (tid / 6) % 80;
  int y  = (tid / 480) % 60;
  int v  = tid / 28800;
  int c = c4*4;
  const float* b0 = t4 + ((size_t)(v*120 + 2*y)*160 + 2*x)*24 + c;
  float4 a = ld4(b0), b = ld4(b0 + 24), cc = ld4(b0 + 160*24), d = ld4(b0 + 160*24 + 24);
  float4 r;
  r.x = 0.25f*(a.x + b.x + cc.x + d.x);
  r.y = 0.25f*(a.y + b.y + cc.y + d.y);
  r.z = 0.25f*(a.z + b.z + cc.z + d.z);
  r.w = 0.25f*(a.w + b.w + cc.w + d.w);
  st4(fc + ((size_t)(v*60 + y)*80 + x)*144 + 120 + c, r);
}

// ---------------- grid scatter + coords passthrough ----------------
__global__ void k_scatter(const int* __restrict__ coords, const int* __restrict__ stage,
                          int* __restrict__ grid, int* __restrict__ scn,
                          float* __restrict__ coords_out){
  int n = blockIdx.x*256 + threadIdx.x;
  if (n >= NVOX) return;
  int c0 = coords[n*4], c1 = coords[n*4+1], c2 = coords[n*4+2], c3 = coords[n*4+3];
  coords_out[n*4+0] = (float)c0;
  coords_out[n*4+1] = (float)c1;
  coords_out[n*4+2] = (float)c2;
  coords_out[n*4+3] = (float)c3;
  int sh = 2 - stage[0];
  int s1 = c1 >> sh, s2 = c2 >> sh, s3 = c3 >> sh;
  scn[n*3+0] = s1; scn[n*3+1] = s2; scn[n*3+2] = s3;
  grid[(s1*GS + s2)*GS + s3] = n;
}

// ---------------- neighbor index precompute: nbr[k][n] ----------------
__global__ void k_nbr(const int* __restrict__ scn, const int* __restrict__ grid,
                      int* __restrict__ nbr){
  int n = blockIdx.x*256 + threadIdx.x;
  if (n >= NVOX) return;
  int sx = scn[n*3+0], sy = scn[n*3+1], sz = scn[n*3+2];
  #pragma unroll 1
  for (int k = 0; k < 27; ++k){
    int dx = k/9 - 1, dy = (k/3)%3 - 1, dz = k%3 - 1;
    int nx = sx+dx, ny = sy+dy, nz = sz+dz;
    int idx = -1;
    if (((unsigned)nx < 96u) && ((unsigned)ny < 96u) && ((unsigned)nz < 96u))
      idx = grid[(nx*GS + ny)*GS + nz];
    nbr[k*NVOX + n] = idx;
  }
}

// ---------------- projection + bilinear sample + masked mean/var + bn0 (bf16 out) --
__global__ __launch_bounds__(256) void k_sample(
    const float* __restrict__ fuse, const int* __restrict__ coords,
    const float* __restrict__ origin, const float* __restrict__ vsz,
    const float* __restrict__ KR, const float* __restrict__ bn0g,
    const float* __restrict__ bn0b, ushort* __restrict__ F0, float* __restrict__ cnt){
  int vox = blockIdx.x*8 + (threadIdx.x >> 5);
  int c = threadIdx.x & 31;
  float vs = vsz[0];
  float wx = (float)coords[vox*4+1]*vs + origin[0];
  float wy = (float)coords[vox*4+2]*vs + origin[1];
  float wz = (float)coords[vox*4+3]*vs + origin[2];
  float s = 0.f, s2 = 0.f, den = 0.f;
  for (int v = 0; v < VN; ++v){
    const float* P = KR + v*12;
    float ix = P[0]*wx + P[1]*wy + P[2]*wz + P[3];
    float iy = P[4]*wx + P[5]*wy + P[6]*wz + P[7];
    float iz = P[8]*wx + P[9]*wy + P[10]*wz + P[11];
    float gx = 2.f*(ix/iz)/159.f - 1.f;
    float gy = 2.f*(iy/iz)/119.f - 1.f;
    bool msk = (fabsf(gx) <= 1.f) && (fabsf(gy) <= 1.f) && (iz > 0.f);
    if (msk){
      float px = (gx + 1.f)*0.5f*79.f;
      float py = (gy + 1.f)*0.5f*59.f;
      float x0f = floorf(px), y0f = floorf(py);
      int x0 = (int)x0f, y0 = (int)y0f;
      float fx = px - x0f, fy = py - y0f;
      const float* base = fuse + (size_t)(v*60*80)*32 + c;
      float g = 0.f;
      if (x0   >= 0 && x0   <= 79 && y0   >= 0 && y0   <= 59) g += base[((size_t)y0*80 + x0  )*32] * ((1.f-fx)*(1.f-fy));
      if (x0+1 >= 0 && x0+1 <= 79 && y0   >= 0 && y0   <= 59) g += base[((size_t)y0*80 + x0+1)*32] * (fx*(1.f-fy));
      if (x0   >= 0 && x0   <= 79 && y0+1 >= 0 && y0+1 <= 59) g += base[((size_t)(y0+1)*80 + x0  )*32] * ((1.f-fx)*fy);
      if (x0+1 >= 0 && x0+1 <= 79 && y0+1 >= 0 && y0+1 <= 59) g += base[((size_t)(y0+1)*80 + x0+1)*32] * (fx*fy);
      s += g; s2 += g*g; den += 1.f;
    }
  }
  float mean = s/den;
  float var = fmaxf(s2/den - mean*mean, 0.f);
  F0[(size_t)vox*32 + c] = f2b(bn0g[c]*var*INVS + bn0b[c]);
  if (c == 0) cnt[vox] = den;
}

// ---------------- subm sparse conv 32->32 via MFMA bf16 ----------------------------
// wave = 64 voxels: 4 A-frags (16 voxels each) x 2 B-frags (out ch 0-15 / 16-31).
// MODE 0: out = relu(subm(in));  MODE 1: out = LN(relu(subm(in)) + in)
template<int MODE>
__global__ __launch_bounds__(256, 4) void k_subm_mfma(
    const ushort* __restrict__ fin, const ushort* __restrict__ w2,
    const int* __restrict__ nbr,
    const float* __restrict__ lng, const float* __restrict__ lnb,
    ushort* __restrict__ fout){
  int lane = threadIdx.x & 63;
  int wave = threadIdx.x >> 6;
  int vbase = blockIdx.x*256 + wave*64;
  int m = lane & 15;     // A: voxel-in-tile ; B/C: out-channel
  int q = lane >> 4;     // k-chunk selector (8 input ch per chunk)

  f32x4v acc[4][2];
  #pragma unroll
  for (int t = 0; t < 4; ++t){ acc[t][0] = 0.f; acc[t][1] = 0.f; }

  bf16x8 zc = (short)0;
  bf16x8 A[4], b0, b1;

  // prologue: k = 0
  {
    #pragma unroll
    for (int t = 0; t < 4; ++t){
      int id = nbr[0*NVOX + vbase + t*16 + m];
      bf16x8 a = *(const bf16x8*)(fin + (size_t)(id < 0 ? 0 : id)*32 + q*8);
      A[t] = (id < 0) ? zc : a;
    }
    b0 = *(const bf16x8*)(w2 + (size_t)(0*32 + m)*32 + q*8);
    b1 = *(const bf16x8*)(w2 + (size_t)(0*32 + 16 + m)*32 + q*8);
  }

  #pragma unroll 1
  for (int k = 0; k < 27; ++k){
    int idxn[4];
    if (k < 26){
      #pragma unroll
      for (int t = 0; t < 4; ++t)
        idxn[t] = nbr[(size_t)(k+1)*NVOX + vbase + t*16 + m];
    }
    #pragma unroll
    for (int t = 0; t < 4; ++t){
      acc[t][0] = __builtin_amdgcn_mfma_f32_16x16x32_bf16(A[t], b0, acc[t][0], 0, 0, 0);
      acc[t][1] = __builtin_amdgcn_mfma_f32_16x16x32_bf16(A[t], b1, acc[t][1], 0, 0, 0);
    }
    if (k < 26){
      #pragma unroll
      for (int t = 0; t < 4; ++t){
        int id = idxn[t];
        bf16x8 a = *(const bf16x8*)(fin + (size_t)(id < 0 ? 0 : id)*32 + q*8);
        A[t] = (id < 0) ? zc : a;
      }
      b0 = *(const bf16x8*)(w2 + (size_t)((k+1)*32 + m)*32 + q*8);
      b1 = *(const bf16x8*)(w2 + (size_t)((k+1)*32 + 16 + m)*32 + q*8);
    }
  }

  // epilogue: C layout col = lane&15 (out ch), row = (lane>>4)*4 + reg (voxel)
  int ch0 = m, ch1 = 16 + m;
  float g0 = 0.f, g1 = 0.f, bb0 = 0.f, bb1 = 0.f;
  if (MODE == 1){ g0 = lng[ch0]; g1 = lng[ch1]; bb0 = lnb[ch0]; bb1 = lnb[ch1]; }
  #pragma unroll
  for (int t = 0; t < 4; ++t){
    #pragma unroll
    for (int r = 0; r < 4; ++r){
      int vox = vbase + t*16 + q*4 + r;
      float x0 = fmaxf(acc[t][0][r], 0.f);
      float x1 = fmaxf(acc[t][1][r], 0.f);
      if (MODE == 1){
        x0 += b2f(fin[(size_t)vox*32 + ch0]);
        x1 += b2f(fin[(size_t)vox*32 + ch1]);
        float s = x0 + x1;
        s += __shfl_xor(s, 1, 16);
        s += __shfl_xor(s, 2, 16);
        s += __shfl_xor(s, 4, 16);
        s += __shfl_xor(s, 8, 16);
        float mean = s * (1.f/32.f);
        float d0 = x0 - mean, d1 = x1 - mean;
        float v2 = d0*d0 + d1*d1;
        v2 += __shfl_xor(v2, 1, 16);
        v2 += __shfl_xor(v2, 2, 16);
        v2 += __shfl_xor(v2, 4, 16);
        v2 += __shfl_xor(v2, 8, 16);
        float rs = 1.f / sqrtf(v2*(1.f/32.f) + 1e-5f);
        x0 = d0*rs*g0 + bb0;
        x1 = d1*rs*g1 + bb1;
      }
      fout[(size_t)vox*32 + ch0] = f2b(x0);
      fout[(size_t)vox*32 + ch1] = f2b(x1);
    }
  }
}

// ---------------- final subm 32->1 + bn (lane per voxel) ----------------
__global__ __launch_bounds__(256) void k_s4(
    const ushort* __restrict__ fin, const float* __restrict__ w4,
    const int* __restrict__ nbr, const float* __restrict__ bn4g,
    const float* __restrict__ bn4b, float* __restrict__ occ){
  int n = blockIdx.x*256 + threadIdx.x;
  if (n >= NVOX) return;
  float acc = 0.f;
  #pragma unroll 1
  for (int k = 0; k < 27; ++k){
    int idx = nbr[(size_t)k*NVOX + n];
    if (idx >= 0){
      const uint4* r4 = (const uint4*)(fin + (size_t)idx*32);
      const float* wk = w4 + k*32;
      #pragma unroll
      for (int u = 0; u < 4; ++u){
        uint4 d = r4[u];
        const float* w8 = wk + u*8;
        acc += blo(d.x)*w8[0] + bhi(d.x)*w8[1];
        acc += blo(d.y)*w8[2] + bhi(d.y)*w8[3];
        acc += blo(d.z)*w8[4] + bhi(d.z)*w8[5];
        acc += blo(d.w)*w8[6] + bhi(d.w)*w8[7];
      }
    }
  }
  occ[n] = bn4g[0]*acc*INVS + bn4b[0];
}

extern "C" void kernel_launch(void* const* d_in, const int* in_sizes, int n_in,
                              void* d_out, int out_size, void* d_ws, size_t ws_size,
                              hipStream_t stream){
  const float* feats1 = (const float*)d_in[0];
  const float* feats2 = (const float*)d_in[1];
  const float* feats4 = (const float*)d_in[2];
  const int*   coords = (const int*)d_in[3];
  const float* origin = (const float*)d_in[4];
  const float* vsz    = (const float*)d_in[5];
  const float* KR     = (const float*)d_in[6];
  const float* w_f1 = (const float*)d_in[7];  const float* b_f1 = (const float*)d_in[8];
  const float* w_f2 = (const float*)d_in[9];  const float* b_f2 = (const float*)d_in[10];
  const float* w_f4 = (const float*)d_in[11]; const float* b_f4 = (const float*)d_in[12];
  const float* w_dn = (const float*)d_in[13]; const float* b_dn = (const float*)d_in[14];
  const float* w_p[4] = {(const float*)d_in[15], (const float*)d_in[17],
                         (const float*)d_in[19], (const float*)d_in[21]};
  const float* b_p[4] = {(const float*)d_in[16], (const float*)d_in[18],
                         (const float*)d_in[20], (const float*)d_in[22]};
  const float* bn0g = (const float*)d_in[23]; const float* bn0b = (const float*)d_in[24];
  const float* w_elan = (const float*)d_in[25];
  const float* w_s1 = (const float*)d_in[26]; const float* ln1g = (const float*)d_in[27]; const float* ln1b = (const float*)d_in[28];
  const float* w_s2 = (const float*)d_in[29]; const float* ln2g = (const float*)d_in[30]; const float* ln2b = (const float*)d_in[31];
  const float* w_s3 = (const float*)d_in[32]; const float* ln3g = (const float*)d_in[33]; const float* ln3b = (const float*)d_in[34];
  const float* w_s4 = (const float*)d_in[35]; const float* bn4g = (const float*)d_in[36]; const float* bn4b = (const float*)d_in[37];
  const int* stage  = (const int*)d_in[38];
  float* out = (float*)d_out;
  float* ws  = (float*)d_ws;

  // workspace layout (float offsets); sparse-stack buffers alias dead phase-A regions
  ushort* Fb0  = (ushort*)(ws + 0);        // N*32 bf16 (aliases nhwc1/t1/nhwc2 head)
  float* nhwc1 = ws + 0;
  float* t1    = ws + 864000;
  float* nhwc2 = ws + 1728000;
  float* nhwc4 = ws + 3456000;
  int*   nbr   = (int*)(ws + 3456000);     // 27*N ints (aliases nhwc4, dead)
  float* t4    = ws + 7603200;
  ushort* w2e  = (ushort*)(ws + 7603200);  // 4 x 27648 bf16 (aliases t4, dead)
  ushort* w2s1 = w2e + 27648;
  ushort* w2s2 = w2e + 55296;
  ushort* w2s3 = w2e + 82944;
  float* fcat  = ws + 11750400;
  ushort* Fb1  = (ushort*)(ws + 11750400); // N*32 bf16 (aliases fcat, dead)
  float* A     = ws + 17971200;
  float* B     = ws + 19353600;
  float* wtf1  = ws + 20736000;
  float* wtf2  = ws + 20793600;
  float* wtf4  = ws + 20808000;
  float* wtdn  = ws + 20813184;
  float* wtp0  = ws + 20817792;
  float* wtp1  = ws + 20827008;
  float* wtp2  = ws + 20836224;
  float* wtp3  = ws + 20845440;
  int*   grid  = (int*)(ws + 20854656);
  int*   scn   = (int*)(ws + 21739392);

  auto nb = [](int total){ return (total + 255)/256; };

  // conv weight transposes (fp32)
  k_wtrans<<<nb(80*80*9),256,0,stream>>>(w_f1, wtf1, 80, 80, 3);
  k_wtrans<<<nb(40*40*9),256,0,stream>>>(w_f2, wtf2, 40, 40, 3);
  k_wtrans<<<nb(24*24*9),256,0,stream>>>(w_f4, wtf4, 24, 24, 3);
  k_wtrans<<<nb(32*144),256,0,stream>>>(w_dn, wtdn, 32, 144, 1);
  k_wtrans<<<nb(32*32*9),256,0,stream>>>(w_p[0], wtp0, 32, 32, 3);
  k_wtrans<<<nb(32*32*9),256,0,stream>>>(w_p[1], wtp1, 32, 32, 3);
  k_wtrans<<<nb(32*32*9),256,0,stream>>>(w_p[2], wtp2, 32, 32, 3);
  k_wtrans<<<nb(32*32*9),256,0,stream>>>(w_p[3], wtp3, 32, 32, 3);

  // NCHW -> NHWC
  { int t = 9*80*30*40;   k_nhwc<<<nb(t),256,0,stream>>>(feats1, nhwc1, 80, 30, 40, t); }
  { int t = 9*40*60*80;   k_nhwc<<<nb(t),256,0,stream>>>(feats2, nhwc2, 40, 60, 80, t); }
  { int t = 9*24*120*160; k_nhwc<<<nb(t),256,0,stream>>>(feats4, nhwc4, 24, 120, 160, t); }

  // feature head convs
  { int t = 9*30*40*20;   k_conv<<<nb(t),256,0,stream>>>(nhwc1, 80, 80, wtf1, b_f1, t1,   80, 80, 0,  30, 40, 3, 0, t); }
  { int t = 9*60*80*10;   k_conv<<<nb(t),256,0,stream>>>(nhwc2, 40, 40, wtf2, b_f2, fcat, 40, 144, 80, 60, 80, 3, 0, t); }
  { int t = 9*120*160*6;  k_conv<<<nb(t),256,0,stream>>>(nhwc4, 24, 24, wtf4, b_f4, t4,   24, 24, 0, 120, 160, 3, 0, t); }

  // resize + pool into concat buffer
  { int t = 9*60*80*20;   k_resize<<<nb(t),256,0,stream>>>(t1, fcat, t); }
  { int t = 9*60*80*6;    k_pool<<<nb(t),256,0,stream>>>(t4, fcat, t); }

  // t4 now dead -> subm weight prep (bf16, [k][co][ci])
  k_wprep<<<nb(27648),256,0,stream>>>(w_elan, w2e);
  k_wprep<<<nb(27648),256,0,stream>>>(w_s1, w2s1);
  k_wprep<<<nb(27648),256,0,stream>>>(w_s2, w2s2);
  k_wprep<<<nb(27648),256,0,stream>>>(w_s3, w2s3);

  // down conv (1x1) and 4 residual blocks: fcat -> A -> B -> A -> B -> A
  { int t = 9*60*80*8;
    k_conv<<<nb(t),256,0,stream>>>(fcat, 144, 144, wtdn, b_dn, A, 32, 32, 0, 60, 80, 1, 0, t);
    k_conv<<<nb(t),256,0,stream>>>(A, 32, 32, wtp0, b_p[0], B, 32, 32, 0, 60, 80, 3, 1, t);
    k_conv<<<nb(t),256,0,stream>>>(B, 32, 32, wtp1, b_p[1], A, 32, 32, 0, 60, 80, 3, 1, t);
    k_conv<<<nb(t),256,0,stream>>>(A, 32, 32, wtp2, b_p[2], B, 32, 32, 0, 60, 80, 3, 1, t);
    k_conv<<<nb(t),256,0,stream>>>(B, 32, 32, wtp3, b_p[3], A, 32, 32, 0, 60, 80, 3, 1, t);
  }

  // dense grid build + neighbor table (shared by all 5 sparse layers)
  hipMemsetAsync(grid, 0xFF, (size_t)GS*GS*GS*sizeof(int), stream);
  k_scatter<<<nb(NVOX),256,0,stream>>>(coords, stage, grid, scn, out + NVOX);
  k_nbr<<<nb(NVOX),256,0,stream>>>(scn, grid, nbr);

  // per-voxel sampling -> F0 bf16 + count
  k_sample<<<NVOX/8,256,0,stream>>>(A, coords, origin, vsz, KR, bn0g, bn0b, Fb0, out + 5*NVOX);

  // sparse conv stack (MFMA)
  k_subm_mfma<0><<<NVOX/256,256,0,stream>>>(Fb0, w2e,  nbr, nullptr, nullptr, Fb1);
  k_subm_mfma<1><<<NVOX/256,256,0,stream>>>(Fb1, w2s1, nbr, ln1g, ln1b, Fb0);
  k_subm_mfma<1><<<NVOX/256,256,0,stream>>>(Fb0, w2s2, nbr, ln2g, ln2b, Fb1);
  k_subm_mfma<1><<<NVOX/256,256,0,stream>>>(Fb1, w2s3, nbr, ln3g, ln3b, Fb0);
  k_s4<<<nb(NVOX),256,0,stream>>>(Fb0, w_s4, nbr, bn4g, bn4b, out);
}

// Round 3
// 614.273 us; speedup vs baseline: 5.4800x; 1.7609x over previous
//
#include <hip/hip_runtime.h>
#include <math.h>

#define VN 9
#define NVOX 131072
#define GS 96
static constexpr float INVS = 0.9999950000374997f; // 1/sqrt(1+1e-5)

typedef short bf16x8 __attribute__((ext_vector_type(8)));
typedef float f32x4v __attribute__((ext_vector_type(4)));

__device__ inline ushort f2b(float f){
  unsigned u = __float_as_uint(f);
  unsigned r = (u + 0x7fffu + ((u >> 16) & 1u)) >> 16;
  return (ushort)r;
}
__device__ inline float b2f(ushort s){ return __uint_as_float(((unsigned)s) << 16); }
__device__ inline float blo(unsigned u){ return __uint_as_float(u << 16); }
__device__ inline float bhi(unsigned u){ return __uint_as_float(u & 0xffff0000u); }

__device__ inline float4 ld4b(const ushort* p){
  uint2 u = *reinterpret_cast<const uint2*>(p);
  float4 r; r.x = blo(u.x); r.y = bhi(u.x); r.z = blo(u.y); r.w = bhi(u.y); return r;
}
__device__ inline void st4b(ushort* p, float4 v){
  uint2 u;
  u.x = (unsigned)f2b(v.x) | ((unsigned)f2b(v.y) << 16);
  u.y = (unsigned)f2b(v.z) | ((unsigned)f2b(v.w) << 16);
  *reinterpret_cast<uint2*>(p) = u;
}

// ---- conv weight prep: fp32 [Co][Ci][K][K] -> bf16 [tap][ck][CoutPad][32] ----
__global__ void k_wprep2(const float* __restrict__ w, ushort* __restrict__ o,
                         int Cout, int Cin, int K, int CK, int CoutPad){
  int tid = blockIdx.x*256 + threadIdx.x;
  int total = K*K*CK*CoutPad*32;
  if (tid >= total) return;
  int ci32 = tid & 31;
  int co = (tid >> 5) % CoutPad;
  int ck = (tid / (32*CoutPad)) % CK;
  int tap = tid / (32*CoutPad*CK);
  int ci = ck*32 + ci32;
  float v = 0.f;
  if (co < Cout && ci < Cin) v = w[(size_t)(co*Cin + ci)*K*K + tap];
  o[tid] = f2b(v);
}

// ---- subm weight prep: fp32 [27][ci][co] -> bf16 [27][co][ci] ----
__global__ void k_wprep(const float* __restrict__ w, ushort* __restrict__ o){
  int tid = blockIdx.x*256 + threadIdx.x;
  if (tid >= 27*1024) return;
  int k = tid >> 10;
  int r = tid & 1023;
  int co = r >> 5;
  int ci = r & 31;
  o[tid] = f2b(w[k*1024 + ci*32 + co]);
}

// ---- NCHW fp32 -> NHWC bf16, channel-padded ----
__global__ void k_nhwcb(const float* __restrict__ in, ushort* __restrict__ out,
                        int C, int Cpad, int H, int W, int total){
  int tid = blockIdx.x*256 + threadIdx.x;
  if (tid >= total) return;
  int c = tid % Cpad;
  int x = (tid / Cpad) % W;
  int y = (tid / (Cpad*W)) % H;
  int v = tid / (Cpad*W*H);
  out[tid] = (c < C) ? f2b(in[((size_t)(v*C + c)*H + y)*W + x]) : (ushort)0;
}

// ---- implicit-GEMM conv via MFMA. wave=64 pixels (4 M-tiles), NT n-tiles ----
// out = relu(conv(in)+bias) [+ skipin]. Masked stores for co>=Cout / pixel>=total.
template<int CK, int NT, int TAPS>
__global__ __launch_bounds__(256) void k_conv_mfma(
    const ushort* __restrict__ fin, const ushort* __restrict__ w2,
    const float* __restrict__ bias, ushort* __restrict__ outp,
    int H, int W, int total, int Cout, int outStride, int outOff,
    const ushort* __restrict__ skipin){
  constexpr int CIN = CK*32;
  constexpr int COP = NT*16;
  int lane = threadIdx.x & 63;
  int wave = threadIdx.x >> 6;
  int vbase = blockIdx.x*256 + wave*64;
  int m = lane & 15, q = lane >> 4;
  int HW = H*W;
  int p[4], py[4], px[4]; bool pin[4];
  #pragma unroll
  for (int t = 0; t < 4; ++t){
    int pp = vbase + t*16 + m;
    pin[t] = pp < total;
    if (pp > total-1) pp = total-1;
    p[t] = pp;
    int v = pp / HW; int rem = pp - v*HW;
    int y = rem / W;
    py[t] = y; px[t] = rem - y*W;
  }
  f32x4v acc[4][NT];
  #pragma unroll
  for (int t = 0; t < 4; ++t)
    #pragma unroll
    for (int n = 0; n < NT; ++n) acc[t][n] = 0.f;
  bf16x8 z = (short)0;

  #pragma unroll 1
  for (int tap = 0; tap < TAPS; ++tap){
    int dy = (TAPS == 9) ? tap/3 - 1 : 0;
    int dx = (TAPS == 9) ? tap%3 - 1 : 0;
    int off = dy*W + dx;
    bool val[4];
    #pragma unroll
    for (int t = 0; t < 4; ++t)
      val[t] = pin[t] && ((unsigned)(py[t]+dy) < (unsigned)H)
                      && ((unsigned)(px[t]+dx) < (unsigned)W);
    #pragma unroll
    for (int ck = 0; ck < CK; ++ck){
      bf16x8 Af[4], Bf[NT];
      #pragma unroll
      for (int t = 0; t < 4; ++t){
        size_t idx = val[t] ? (size_t)(p[t]+off) : 0;
        bf16x8 a = *(const bf16x8*)(fin + idx*CIN + ck*32 + q*8);
        Af[t] = val[t] ? a : z;
      }
      #pragma unroll
      for (int n = 0; n < NT; ++n)
        Bf[n] = *(const bf16x8*)(w2 + ((size_t)((tap*CK+ck)*COP + n*16 + m))*32 + q*8);
      #pragma unroll
      for (int t = 0; t < 4; ++t)
        #pragma unroll
        for (int n = 0; n < NT; ++n)
          acc[t][n] = __builtin_amdgcn_mfma_f32_16x16x32_bf16(Af[t], Bf[n], acc[t][n], 0, 0, 0);
    }
  }

  // epilogue: C row = q*4+r (pixel), col = m (within n-tile)
  #pragma unroll
  for (int n = 0; n < NT; ++n){
    int co = n*16 + m;
    bool cok = co < Cout;
    float bs = cok ? bias[co] : 0.f;
    #pragma unroll
    for (int t = 0; t < 4; ++t){
      #pragma unroll
      for (int r = 0; r < 4; ++r){
        int pp = vbase + t*16 + q*4 + r;
        if (pp < total && cok){
          float x = fmaxf(acc[t][n][r] + bs, 0.f);
          if (skipin) x += b2f(skipin[(size_t)pp*CIN + co]);
          outp[(size_t)pp*outStride + outOff + co] = f2b(x);
        }
      }
    }
  }
}

// ---- bilinear 2x upsample, bf16 in/out: t1 (V,30,40,80) -> fcat[...,0:80) ----
__global__ void k_resize(const ushort* __restrict__ t1, ushort* __restrict__ fc, int total){
  int tid = blockIdx.x*256 + threadIdx.x;
  if (tid >= total) return;
  int c4 = tid % 20;
  int x  = (tid / 20) % 80;
  int y  = (tid / 1600) % 60;
  int v  = tid / 96000;
  int c = c4*4;
  int ky = y >> 1; int y0, y1; float wy0, wy1;
  if ((y & 1) == 0){ y0 = ky-1; y1 = ky; wy0 = 0.25f; wy1 = 0.75f; if (y0 < 0){ y0 = 0; wy0 = 0.f; wy1 = 1.f; } }
  else             { y0 = ky; y1 = ky+1; wy0 = 0.75f; wy1 = 0.25f; if (y1 > 29){ y1 = 29; wy1 = 0.f; wy0 = 1.f; } }
  int kx = x >> 1; int x0, x1; float wx0, wx1;
  if ((x & 1) == 0){ x0 = kx-1; x1 = kx; wx0 = 0.25f; wx1 = 0.75f; if (x0 < 0){ x0 = 0; wx0 = 0.f; wx1 = 1.f; } }
  else             { x0 = kx; x1 = kx+1; wx0 = 0.75f; wx1 = 0.25f; if (x1 > 39){ x1 = 39; wx1 = 0.f; wx0 = 1.f; } }
  float4 a00 = ld4b(t1 + ((size_t)(v*30 + y0)*40 + x0)*80 + c);
  float4 a01 = ld4b(t1 + ((size_t)(v*30 + y0)*40 + x1)*80 + c);
  float4 a10 = ld4b(t1 + ((size_t)(v*30 + y1)*40 + x0)*80 + c);
  float4 a11 = ld4b(t1 + ((size_t)(v*30 + y1)*40 + x1)*80 + c);
  float w00 = wy0*wx0, w01 = wy0*wx1, w10 = wy1*wx0, w11 = wy1*wx1;
  float4 r;
  r.x = w00*a00.x + w01*a01.x + w10*a10.x + w11*a11.x;
  r.y = w00*a00.y + w01*a01.y + w10*a10.y + w11*a11.y;
  r.z = w00*a00.z + w01*a01.z + w10*a10.z + w11*a11.z;
  r.w = w00*a00.w + w01*a01.w + w10*a10.w + w11*a11.w;
  st4b(fc + ((size_t)(v*60 + y)*80 + x)*160 + c, r);
}

// ---- 2x2 avg pool bf16: t4 (V,120,160,24) -> fcat[...,120:144) ----
__global__ void k_pool(const ushort* __restrict__ t4, ushort* __restrict__ fc, int total){
  int tid = blockIdx.x*256 + threadIdx.x;
  if (tid >= total) return;
  int c4 = tid % 6;
  int x  = (tid / 6) % 80;
  int y  = (tid / 480) % 60;
  int v  = tid / 28800;
  int c = c4*4;
  const ushort* b0 = t4 + ((size_t)(v*120 + 2*y)*160 + 2*x)*24 + c;
  float4 a = ld4b(b0), b = ld4b(b0 + 24), cc = ld4b(b0 + 160*24), d = ld4b(b0 + 160*24 + 24);
  float4 r;
  r.x = 0.25f*(a.x + b.x + cc.x + d.x);
  r.y = 0.25f*(a.y + b.y + cc.y + d.y);
  r.z = 0.25f*(a.z + b.z + cc.z + d.z);
  r.w = 0.25f*(a.w + b.w + cc.w + d.w);
  st4b(fc + ((size_t)(v*60 + y)*80 + x)*160 + 120 + c, r);
}

// ---- grid scatter + coords passthrough ----
__global__ void k_scatter(const int* __restrict__ coords, const int* __restrict__ stage,
                          int* __restrict__ grid, int* __restrict__ scn,
                          float* __restrict__ coords_out){
  int n = blockIdx.x*256 + threadIdx.x;
  if (n >= NVOX) return;
  int c0 = coords[n*4], c1 = coords[n*4+1], c2 = coords[n*4+2], c3 = coords[n*4+3];
  coords_out[n*4+0] = (float)c0;
  coords_out[n*4+1] = (float)c1;
  coords_out[n*4+2] = (float)c2;
  coords_out[n*4+3] = (float)c3;
  int sh = 2 - stage[0];
  int s1 = c1 >> sh, s2 = c2 >> sh, s3 = c3 >> sh;
  scn[n*3+0] = s1; scn[n*3+1] = s2; scn[n*3+2] = s3;
  grid[(s1*GS + s2)*GS + s3] = n;
}

// ---- neighbor index precompute: nbr[k][n] ----
__global__ void k_nbr(const int* __restrict__ scn, const int* __restrict__ grid,
                      int* __restrict__ nbr){
  int n = blockIdx.x*256 + threadIdx.x;
  if (n >= NVOX) return;
  int sx = scn[n*3+0], sy = scn[n*3+1], sz = scn[n*3+2];
  #pragma unroll 1
  for (int k = 0; k < 27; ++k){
    int dx = k/9 - 1, dy = (k/3)%3 - 1, dz = k%3 - 1;
    int nx = sx+dx, ny = sy+dy, nz = sz+dz;
    int idx = -1;
    if (((unsigned)nx < 96u) && ((unsigned)ny < 96u) && ((unsigned)nz < 96u))
      idx = grid[(nx*GS + ny)*GS + nz];
    nbr[k*NVOX + n] = idx;
  }
}

// ---- projection + bilinear sample + masked mean/var + bn0 (bf16 fuse, bf16 out) --
__global__ __launch_bounds__(256) void k_sample(
    const ushort* __restrict__ fuse, const int* __restrict__ coords,
    const float* __restrict__ origin, const float* __restrict__ vsz,
    const float* __restrict__ KR, const float* __restrict__ bn0g,
    const float* __restrict__ bn0b, ushort* __restrict__ F0, float* __restrict__ cnt){
  int vox = blockIdx.x*8 + (threadIdx.x >> 5);
  int c = threadIdx.x & 31;
  float vs = vsz[0];
  float wx = (float)coords[vox*4+1]*vs + origin[0];
  float wy = (float)coords[vox*4+2]*vs + origin[1];
  float wz = (float)coords[vox*4+3]*vs + origin[2];
  float s = 0.f, s2 = 0.f, den = 0.f;
  for (int v = 0; v < VN; ++v){
    const float* P = KR + v*12;
    float ix = P[0]*wx + P[1]*wy + P[2]*wz + P[3];
    float iy = P[4]*wx + P[5]*wy + P[6]*wz + P[7];
    float iz = P[8]*wx + P[9]*wy + P[10]*wz + P[11];
    float gx = 2.f*(ix/iz)/159.f - 1.f;
    float gy = 2.f*(iy/iz)/119.f - 1.f;
    bool msk = (fabsf(gx) <= 1.f) && (fabsf(gy) <= 1.f) && (iz > 0.f);
    if (msk){
      float px = (gx + 1.f)*0.5f*79.f;
      float py = (gy + 1.f)*0.5f*59.f;
      float x0f = floorf(px), y0f = floorf(py);
      int x0 = (int)x0f, y0 = (int)y0f;
      float fx = px - x0f, fy = py - y0f;
      const ushort* base = fuse + (size_t)(v*60*80)*32 + c;
      float g = 0.f;
      if (x0   >= 0 && x0   <= 79 && y0   >= 0 && y0   <= 59) g += b2f(base[((size_t)y0*80 + x0  )*32]) * ((1.f-fx)*(1.f-fy));
      if (x0+1 >= 0 && x0+1 <= 79 && y0   >= 0 && y0   <= 59) g += b2f(base[((size_t)y0*80 + x0+1)*32]) * (fx*(1.f-fy));
      if (x0   >= 0 && x0   <= 79 && y0+1 >= 0 && y0+1 <= 59) g += b2f(base[((size_t)(y0+1)*80 + x0  )*32]) * ((1.f-fx)*fy);
      if (x0+1 >= 0 && x0+1 <= 79 && y0+1 >= 0 && y0+1 <= 59) g += b2f(base[((size_t)(y0+1)*80 + x0+1)*32]) * (fx*fy);
      s += g; s2 += g*g; den += 1.f;
    }
  }
  float mean = s/den;
  float var = fmaxf(s2/den - mean*mean, 0.f);
  F0[(size_t)vox*32 + c] = f2b(bn0g[c]*var*INVS + bn0b[c]);
  if (c == 0) cnt[vox] = den;
}

// ---- subm sparse conv 32->32 via MFMA bf16 ----
template<int MODE>
__global__ __launch_bounds__(256, 4) void k_subm_mfma(
    const ushort* __restrict__ fin, const ushort* __restrict__ w2,
    const int* __restrict__ nbr,
    const float* __restrict__ lng, const float* __restrict__ lnb,
    ushort* __restrict__ fout){
  int lane = threadIdx.x & 63;
  int wave = threadIdx.x >> 6;
  int vbase = blockIdx.x*256 + wave*64;
  int m = lane & 15;
  int q = lane >> 4;

  f32x4v acc[4][2];
  #pragma unroll
  for (int t = 0; t < 4; ++t){ acc[t][0] = 0.f; acc[t][1] = 0.f; }

  bf16x8 zc = (short)0;
  bf16x8 A[4], b0, b1;

  {
    #pragma unroll
    for (int t = 0; t < 4; ++t){
      int id = nbr[0*NVOX + vbase + t*16 + m];
      bf16x8 a = *(const bf16x8*)(fin + (size_t)(id < 0 ? 0 : id)*32 + q*8);
      A[t] = (id < 0) ? zc : a;
    }
    b0 = *(const bf16x8*)(w2 + (size_t)(0*32 + m)*32 + q*8);
    b1 = *(const bf16x8*)(w2 + (size_t)(0*32 + 16 + m)*32 + q*8);
  }

  #pragma unroll 1
  for (int k = 0; k < 27; ++k){
    int idxn[4];
    if (k < 26){
      #pragma unroll
      for (int t = 0; t < 4; ++t)
        idxn[t] = nbr[(size_t)(k+1)*NVOX + vbase + t*16 + m];
    }
    #pragma unroll
    for (int t = 0; t < 4; ++t){
      acc[t][0] = __builtin_amdgcn_mfma_f32_16x16x32_bf16(A[t], b0, acc[t][0], 0, 0, 0);
      acc[t][1] = __builtin_amdgcn_mfma_f32_16x16x32_bf16(A[t], b1, acc[t][1], 0, 0, 0);
    }
    if (k < 26){
      #pragma unroll
      for (int t = 0; t < 4; ++t){
        int id = idxn[t];
        bf16x8 a = *(const bf16x8*)(fin + (size_t)(id < 0 ? 0 : id)*32 + q*8);
        A[t] = (id < 0) ? zc : a;
      }
      b0 = *(const bf16x8*)(w2 + (size_t)((k+1)*32 + m)*32 + q*8);
      b1 = *(const bf16x8*)(w2 + (size_t)((k+1)*32 + 16 + m)*32 + q*8);
    }
  }

  int ch0 = m, ch1 = 16 + m;
  float g0 = 0.f, g1 = 0.f, bb0 = 0.f, bb1 = 0.f;
  if (MODE == 1){ g0 = lng[ch0]; g1 = lng[ch1]; bb0 = lnb[ch0]; bb1 = lnb[ch1]; }
  #pragma unroll
  for (int t = 0; t < 4; ++t){
    #pragma unroll
    for (int r = 0; r < 4; ++r){
      int vox = vbase + t*16 + q*4 + r;
      float x0 = fmaxf(acc[t][0][r], 0.f);
      float x1 = fmaxf(acc[t][1][r], 0.f);
      if (MODE == 1){
        x0 += b2f(fin[(size_t)vox*32 + ch0]);
        x1 += b2f(fin[(size_t)vox*32 + ch1]);
        float s = x0 + x1;
        s += __shfl_xor(s, 1, 16);
        s += __shfl_xor(s, 2, 16);
        s += __shfl_xor(s, 4, 16);
        s += __shfl_xor(s, 8, 16);
        float mean = s * (1.f/32.f);
        float d0 = x0 - mean, d1 = x1 - mean;
        float v2 = d0*d0 + d1*d1;
        v2 += __shfl_xor(v2, 1, 16);
        v2 += __shfl_xor(v2, 2, 16);
        v2 += __shfl_xor(v2, 4, 16);
        v2 += __shfl_xor(v2, 8, 16);
        float rs = 1.f / sqrtf(v2*(1.f/32.f) + 1e-5f);
        x0 = d0*rs*g0 + bb0;
        x1 = d1*rs*g1 + bb1;
      }
      fout[(size_t)vox*32 + ch0] = f2b(x0);
      fout[(size_t)vox*32 + ch1] = f2b(x1);
    }
  }
}

// ---- final subm 32->1 + bn ----
__global__ __launch_bounds__(256) void k_s4(
    const ushort* __restrict__ fin, const float* __restrict__ w4,
    const int* __restrict__ nbr, const float* __restrict__ bn4g,
    const float* __restrict__ bn4b, float* __restrict__ occ){
  int n = blockIdx.x*256 + threadIdx.x;
  if (n >= NVOX) return;
  float acc = 0.f;
  #pragma unroll 1
  for (int k = 0; k < 27; ++k){
    int idx = nbr[(size_t)k*NVOX + n];
    if (idx >= 0){
      const uint4* r4 = (const uint4*)(fin + (size_t)idx*32);
      const float* wk = w4 + k*32;
      #pragma unroll
      for (int u = 0; u < 4; ++u){
        uint4 d = r4[u];
        const float* w8 = wk + u*8;
        acc += blo(d.x)*w8[0] + bhi(d.x)*w8[1];
        acc += blo(d.y)*w8[2] + bhi(d.y)*w8[3];
        acc += blo(d.z)*w8[4] + bhi(d.z)*w8[5];
        acc += blo(d.w)*w8[6] + bhi(d.w)*w8[7];
      }
    }
  }
  occ[n] = bn4g[0]*acc*INVS + bn4b[0];
}

extern "C" void kernel_launch(void* const* d_in, const int* in_sizes, int n_in,
                              void* d_out, int out_size, void* d_ws, size_t ws_size,
                              hipStream_t stream){
  const float* feats1 = (const float*)d_in[0];
  const float* feats2 = (const float*)d_in[1];
  const float* feats4 = (const float*)d_in[2];
  const int*   coords = (const int*)d_in[3];
  const float* origin = (const float*)d_in[4];
  const float* vsz    = (const float*)d_in[5];
  const float* KR     = (const float*)d_in[6];
  const float* w_f1 = (const float*)d_in[7];  const float* b_f1 = (const float*)d_in[8];
  const float* w_f2 = (const float*)d_in[9];  const float* b_f2 = (const float*)d_in[10];
  const float* w_f4 = (const float*)d_in[11]; const float* b_f4 = (const float*)d_in[12];
  const float* w_dn = (const float*)d_in[13]; const float* b_dn = (const float*)d_in[14];
  const float* w_p[4] = {(const float*)d_in[15], (const float*)d_in[17],
                         (const float*)d_in[19], (const float*)d_in[21]};
  const float* b_p[4] = {(const float*)d_in[16], (const float*)d_in[18],
                         (const float*)d_in[20], (const float*)d_in[22]};
  const float* bn0g = (const float*)d_in[23]; const float* bn0b = (const float*)d_in[24];
  const float* w_elan = (const float*)d_in[25];
  const float* w_s1 = (const float*)d_in[26]; const float* ln1g = (const float*)d_in[27]; const float* ln1b = (const float*)d_in[28];
  const float* w_s2 = (const float*)d_in[29]; const float* ln2g = (const float*)d_in[30]; const float* ln2b = (const float*)d_in[31];
  const float* w_s3 = (const float*)d_in[32]; const float* ln3g = (const float*)d_in[33]; const float* ln3b = (const float*)d_in[34];
  const float* w_s4 = (const float*)d_in[35]; const float* bn4g = (const float*)d_in[36]; const float* bn4b = (const float*)d_in[37];
  const int* stage  = (const int*)d_in[38];
  float* out = (float*)d_out;
  char* base = (char*)d_ws;

  // byte-offset workspace layout (total ~80.5 MB)
  size_t off = 0;
  auto alloc = [&](size_t bytes)->char*{ char* p = base + off; off += (bytes + 255) & ~(size_t)255; return p; };
  ushort* nhwc1 = (ushort*)alloc((size_t)9*30*40*96*2);    // 2.07 MB
  ushort* nhwc2 = (ushort*)alloc((size_t)9*60*80*64*2);    // 5.53 MB
  ushort* nhwc4 = (ushort*)alloc((size_t)9*120*160*32*2);  // 11.06 MB
  ushort* t1    = (ushort*)alloc((size_t)9*30*40*80*2);    // 1.73 MB
  ushort* t4    = (ushort*)alloc((size_t)9*120*160*24*2);  // 4.15 MB
  ushort* fcat  = (ushort*)alloc((size_t)9*60*80*160*2);   // 13.82 MB
  ushort* A     = (ushort*)alloc((size_t)9*60*80*32*2);    // 2.76 MB
  ushort* B     = (ushort*)alloc((size_t)9*60*80*32*2);    // 2.76 MB
  ushort* Fb0   = (ushort*)alloc((size_t)NVOX*32*2);       // 8.39 MB
  ushort* Fb1   = (ushort*)alloc((size_t)NVOX*32*2);       // 8.39 MB
  int*    nbr   = (int*)alloc((size_t)27*NVOX*4);          // 14.16 MB
  int*    grid  = (int*)alloc((size_t)GS*GS*GS*4);         // 3.54 MB
  int*    scn   = (int*)alloc((size_t)NVOX*3*4);           // 1.57 MB
  ushort* wf1   = (ushort*)alloc(9*3*80*32*2);
  ushort* wf2   = (ushort*)alloc(9*2*48*32*2);
  ushort* wf4   = (ushort*)alloc(9*1*32*32*2);
  ushort* wdn   = (ushort*)alloc(1*5*32*32*2);
  ushort* wp0   = (ushort*)alloc(9*1*32*32*2);
  ushort* wp1   = (ushort*)alloc(9*1*32*32*2);
  ushort* wp2   = (ushort*)alloc(9*1*32*32*2);
  ushort* wp3   = (ushort*)alloc(9*1*32*32*2);
  ushort* w2e   = (ushort*)alloc(27*1024*2);
  ushort* w2s1  = (ushort*)alloc(27*1024*2);
  ushort* w2s2  = (ushort*)alloc(27*1024*2);
  ushort* w2s3  = (ushort*)alloc(27*1024*2);

  auto nb = [](int total){ return (total + 255)/256; };

  // zero fcat (pad channels [144,160) must multiply cleanly) + grid init
  hipMemsetAsync(fcat, 0, (size_t)9*60*80*160*2, stream);
  hipMemsetAsync(grid, 0xFF, (size_t)GS*GS*GS*4, stream);

  // weight prep
  k_wprep2<<<nb(9*3*80*32),256,0,stream>>>(w_f1, wf1, 80, 80, 3, 3, 80);
  k_wprep2<<<nb(9*2*48*32),256,0,stream>>>(w_f2, wf2, 40, 40, 3, 2, 48);
  k_wprep2<<<nb(9*1*32*32),256,0,stream>>>(w_f4, wf4, 24, 24, 3, 1, 32);
  k_wprep2<<<nb(1*5*32*32),256,0,stream>>>(w_dn, wdn, 32, 144, 1, 5, 32);
  k_wprep2<<<nb(9*1*32*32),256,0,stream>>>(w_p[0], wp0, 32, 32, 3, 1, 32);
  k_wprep2<<<nb(9*1*32*32),256,0,stream>>>(w_p[1], wp1, 32, 32, 3, 1, 32);
  k_wprep2<<<nb(9*1*32*32),256,0,stream>>>(w_p[2], wp2, 32, 32, 3, 1, 32);
  k_wprep2<<<nb(9*1*32*32),256,0,stream>>>(w_p[3], wp3, 32, 32, 3, 1, 32);
  k_wprep<<<nb(27648),256,0,stream>>>(w_elan, w2e);
  k_wprep<<<nb(27648),256,0,stream>>>(w_s1, w2s1);
  k_wprep<<<nb(27648),256,0,stream>>>(w_s2, w2s2);
  k_wprep<<<nb(27648),256,0,stream>>>(w_s3, w2s3);

  // NCHW -> NHWC bf16 padded
  { int t = 9*30*40*96;   k_nhwcb<<<nb(t),256,0,stream>>>(feats1, nhwc1, 80, 96, 30, 40, t); }
  { int t = 9*60*80*64;   k_nhwcb<<<nb(t),256,0,stream>>>(feats2, nhwc2, 40, 64, 60, 80, t); }
  { int t = 9*120*160*32; k_nhwcb<<<nb(t),256,0,stream>>>(feats4, nhwc4, 24, 32, 120, 160, t); }

  // head convs (implicit-GEMM MFMA)
  k_conv_mfma<3,5,9><<<nb(10800),256,0,stream>>>(nhwc1, wf1, b_f1, t1, 30, 40, 10800, 80, 80, 0, nullptr);
  k_conv_mfma<2,3,9><<<nb(43200),256,0,stream>>>(nhwc2, wf2, b_f2, fcat, 60, 80, 43200, 40, 160, 80, nullptr);
  k_conv_mfma<1,2,9><<<nb(172800),256,0,stream>>>(nhwc4, wf4, b_f4, t4, 120, 160, 172800, 24, 24, 0, nullptr);

  // resize + pool into concat buffer
  { int t = 9*60*80*20; k_resize<<<nb(t),256,0,stream>>>(t1, fcat, t); }
  { int t = 9*60*80*6;  k_pool<<<nb(t),256,0,stream>>>(t4, fcat, t); }

  // down conv (1x1) + 4 residual blocks
  k_conv_mfma<5,2,1><<<nb(43200),256,0,stream>>>(fcat, wdn, b_dn, A, 60, 80, 43200, 32, 32, 0, nullptr);
  k_conv_mfma<1,2,9><<<nb(43200),256,0,stream>>>(A, wp0, b_p[0], B, 60, 80, 43200, 32, 32, 0, A);
  k_conv_mfma<1,2,9><<<nb(43200),256,0,stream>>>(B, wp1, b_p[1], A, 60, 80, 43200, 32, 32, 0, B);
  k_conv_mfma<1,2,9><<<nb(43200),256,0,stream>>>(A, wp2, b_p[2], B, 60, 80, 43200, 32, 32, 0, A);
  k_conv_mfma<1,2,9><<<nb(43200),256,0,stream>>>(B, wp3, b_p[3], A, 60, 80, 43200, 32, 32, 0, B);

  // grid scatter + neighbor table
  k_scatter<<<nb(NVOX),256,0,stream>>>(coords, stage, grid, scn, out + NVOX);
  k_nbr<<<nb(NVOX),256,0,stream>>>(scn, grid, nbr);

  // per-voxel sampling -> F0 bf16 + count
  k_sample<<<NVOX/8,256,0,stream>>>(A, coords, origin, vsz, KR, bn0g, bn0b, Fb0, out + 5*NVOX);

  // sparse conv stack (MFMA)
  k_subm_mfma<0><<<NVOX/256,256,0,stream>>>(Fb0, w2e,  nbr, nullptr, nullptr, Fb1);
  k_subm_mfma<1><<<NVOX/256,256,0,stream>>>(Fb1, w2s1, nbr, ln1g, ln1b, Fb0);
  k_subm_mfma<1><<<NVOX/256,256,0,stream>>>(Fb0, w2s2, nbr, ln2g, ln2b, Fb1);
  k_subm_mfma<1><<<NVOX/256,256,0,stream>>>(Fb1, w2s3, nbr, ln3g, ln3b, Fb0);
  k_s4<<<nb(NVOX),256,0,stream>>>(Fb0, w_s4, nbr, bn4g, bn4b, out);
}

// Round 4
// 487.924 us; speedup vs baseline: 6.8991x; 1.2590x over previous
//
#include <hip/hip_runtime.h>
#include <math.h>

#define VN 9
#define NVOX 131072
#define GS 96
static constexpr float INVS = 0.9999950000374997f; // 1/sqrt(1+1e-5)

typedef short bf16x8 __attribute__((ext_vector_type(8)));
typedef float f32x4v __attribute__((ext_vector_type(4)));

__device__ inline float4 ld4(const float* p){ return *reinterpret_cast<const float4*>(p); }

__device__ inline ushort f2b(float f){
  unsigned u = __float_as_uint(f);
  unsigned r = (u + 0x7fffu + ((u >> 16) & 1u)) >> 16;
  return (ushort)r;
}
__device__ inline float b2f(ushort s){ return __uint_as_float(((unsigned)s) << 16); }
__device__ inline float blo(unsigned u){ return __uint_as_float(u << 16); }
__device__ inline float bhi(unsigned u){ return __uint_as_float(u & 0xffff0000u); }

__device__ inline float4 ld4b(const ushort* p){
  uint2 u = *reinterpret_cast<const uint2*>(p);
  float4 r; r.x = blo(u.x); r.y = bhi(u.x); r.z = blo(u.y); r.w = bhi(u.y); return r;
}
__device__ inline void st4b(ushort* p, float4 v){
  uint2 u;
  u.x = (unsigned)f2b(v.x) | ((unsigned)f2b(v.y) << 16);
  u.y = (unsigned)f2b(v.z) | ((unsigned)f2b(v.w) << 16);
  *reinterpret_cast<uint2*>(p) = u;
}

// ---- conv weight prep: fp32 [Co][Ci][K][K] -> bf16 [tap][ck][CoutPad][32] ----
__global__ void k_wprep2(const float* __restrict__ w, ushort* __restrict__ o,
                         int Cout, int Cin, int K, int CK, int CoutPad){
  int tid = blockIdx.x*256 + threadIdx.x;
  int total = K*K*CK*CoutPad*32;
  if (tid >= total) return;
  int ci32 = tid & 31;
  int co = (tid >> 5) % CoutPad;
  int ck = (tid / (32*CoutPad)) % CK;
  int tap = tid / (32*CoutPad*CK);
  int ci = ck*32 + ci32;
  float v = 0.f;
  if (co < Cout && ci < Cin) v = w[(size_t)(co*Cin + ci)*K*K + tap];
  o[tid] = f2b(v);
}

// ---- subm weight prep: fp32 [27][ci][co] -> bf16 [27][co][ci] ----
__global__ void k_wprep(const float* __restrict__ w, ushort* __restrict__ o){
  int tid = blockIdx.x*256 + threadIdx.x;
  if (tid >= 27*1024) return;
  int k = tid >> 10;
  int r = tid & 1023;
  int co = r >> 5;
  int ci = r & 31;
  o[tid] = f2b(w[k*1024 + ci*32 + co]);
}

// ---- NCHW fp32 -> NHWC bf16, channel-padded ----
__global__ void k_nhwcb(const float* __restrict__ in, ushort* __restrict__ out,
                        int C, int Cpad, int H, int W, int total){
  int tid = blockIdx.x*256 + threadIdx.x;
  if (tid >= total) return;
  int c = tid % Cpad;
  int x = (tid / Cpad) % W;
  int y = (tid / (Cpad*W)) % H;
  int v = tid / (Cpad*W*H);
  out[tid] = (c < C) ? f2b(in[((size_t)(v*C + c)*H + y)*W + x]) : (ushort)0;
}

// ---- implicit-GEMM conv via MFMA. wave=64 pixels (4 M-tiles), NT n-tiles ----
template<int CK, int NT, int TAPS>
__global__ __launch_bounds__(256) void k_conv_mfma(
    const ushort* __restrict__ fin, const ushort* __restrict__ w2,
    const float* __restrict__ bias, ushort* __restrict__ outp,
    int H, int W, int total, int Cout, int outStride, int outOff,
    const ushort* __restrict__ skipin){
  constexpr int CIN = CK*32;
  constexpr int COP = NT*16;
  int lane = threadIdx.x & 63;
  int wave = threadIdx.x >> 6;
  int vbase = blockIdx.x*256 + wave*64;
  int m = lane & 15, q = lane >> 4;
  int HW = H*W;
  int p[4], py[4], px[4]; bool pin[4];
  #pragma unroll
  for (int t = 0; t < 4; ++t){
    int pp = vbase + t*16 + m;
    pin[t] = pp < total;
    if (pp > total-1) pp = total-1;
    p[t] = pp;
    int v = pp / HW; int rem = pp - v*HW;
    int y = rem / W;
    py[t] = y; px[t] = rem - y*W;
  }
  f32x4v acc[4][NT];
  #pragma unroll
  for (int t = 0; t < 4; ++t)
    #pragma unroll
    for (int n = 0; n < NT; ++n) acc[t][n] = 0.f;
  bf16x8 z = (short)0;

  #pragma unroll 1
  for (int tap = 0; tap < TAPS; ++tap){
    int dy = (TAPS == 9) ? tap/3 - 1 : 0;
    int dx = (TAPS == 9) ? tap%3 - 1 : 0;
    int off = dy*W + dx;
    bool val[4];
    #pragma unroll
    for (int t = 0; t < 4; ++t)
      val[t] = pin[t] && ((unsigned)(py[t]+dy) < (unsigned)H)
                      && ((unsigned)(px[t]+dx) < (unsigned)W);
    #pragma unroll
    for (int ck = 0; ck < CK; ++ck){
      bf16x8 Af[4], Bf[NT];
      #pragma unroll
      for (int t = 0; t < 4; ++t){
        size_t idx = val[t] ? (size_t)(p[t]+off) : 0;
        bf16x8 a = *(const bf16x8*)(fin + idx*CIN + ck*32 + q*8);
        Af[t] = val[t] ? a : z;
      }
      #pragma unroll
      for (int n = 0; n < NT; ++n)
        Bf[n] = *(const bf16x8*)(w2 + ((size_t)((tap*CK+ck)*COP + n*16 + m))*32 + q*8);
      #pragma unroll
      for (int t = 0; t < 4; ++t)
        #pragma unroll
        for (int n = 0; n < NT; ++n)
          acc[t][n] = __builtin_amdgcn_mfma_f32_16x16x32_bf16(Af[t], Bf[n], acc[t][n], 0, 0, 0);
    }
  }

  #pragma unroll
  for (int n = 0; n < NT; ++n){
    int co = n*16 + m;
    bool cok = co < Cout;
    float bs = cok ? bias[co] : 0.f;
    #pragma unroll
    for (int t = 0; t < 4; ++t){
      #pragma unroll
      for (int r = 0; r < 4; ++r){
        int pp = vbase + t*16 + q*4 + r;
        if (pp < total && cok){
          float x = fmaxf(acc[t][n][r] + bs, 0.f);
          if (skipin) x += b2f(skipin[(size_t)pp*CIN + co]);
          outp[(size_t)pp*outStride + outOff + co] = f2b(x);
        }
      }
    }
  }
}

// ---- bilinear 2x upsample, bf16 in/out ----
__global__ void k_resize(const ushort* __restrict__ t1, ushort* __restrict__ fc, int total){
  int tid = blockIdx.x*256 + threadIdx.x;
  if (tid >= total) return;
  int c4 = tid % 20;
  int x  = (tid / 20) % 80;
  int y  = (tid / 1600) % 60;
  int v  = tid / 96000;
  int c = c4*4;
  int ky = y >> 1; int y0, y1; float wy0, wy1;
  if ((y & 1) == 0){ y0 = ky-1; y1 = ky; wy0 = 0.25f; wy1 = 0.75f; if (y0 < 0){ y0 = 0; wy0 = 0.f; wy1 = 1.f; } }
  else             { y0 = ky; y1 = ky+1; wy0 = 0.75f; wy1 = 0.25f; if (y1 > 29){ y1 = 29; wy1 = 0.f; wy0 = 1.f; } }
  int kx = x >> 1; int x0, x1; float wx0, wx1;
  if ((x & 1) == 0){ x0 = kx-1; x1 = kx; wx0 = 0.25f; wx1 = 0.75f; if (x0 < 0){ x0 = 0; wx0 = 0.f; wx1 = 1.f; } }
  else             { x0 = kx; x1 = kx+1; wx0 = 0.75f; wx1 = 0.25f; if (x1 > 39){ x1 = 39; wx1 = 0.f; wx0 = 1.f; } }
  float4 a00 = ld4b(t1 + ((size_t)(v*30 + y0)*40 + x0)*80 + c);
  float4 a01 = ld4b(t1 + ((size_t)(v*30 + y0)*40 + x1)*80 + c);
  float4 a10 = ld4b(t1 + ((size_t)(v*30 + y1)*40 + x0)*80 + c);
  float4 a11 = ld4b(t1 + ((size_t)(v*30 + y1)*40 + x1)*80 + c);
  float w00 = wy0*wx0, w01 = wy0*wx1, w10 = wy1*wx0, w11 = wy1*wx1;
  float4 r;
  r.x = w00*a00.x + w01*a01.x + w10*a10.x + w11*a11.x;
  r.y = w00*a00.y + w01*a01.y + w10*a10.y + w11*a11.y;
  r.z = w00*a00.z + w01*a01.z + w10*a10.z + w11*a11.z;
  r.w = w00*a00.w + w01*a01.w + w10*a10.w + w11*a11.w;
  st4b(fc + ((size_t)(v*60 + y)*80 + x)*160 + c, r);
}

// ---- 2x2 avg pool bf16 ----
__global__ void k_pool(const ushort* __restrict__ t4, ushort* __restrict__ fc, int total){
  int tid = blockIdx.x*256 + threadIdx.x;
  if (tid >= total) return;
  int c4 = tid % 6;
  int x  = (tid / 6) % 80;
  int y  = (tid / 480) % 60;
  int v  = tid / 28800;
  int c = c4*4;
  const ushort* b0 = t4 + ((size_t)(v*120 + 2*y)*160 + 2*x)*24 + c;
  float4 a = ld4b(b0), b = ld4b(b0 + 24), cc = ld4b(b0 + 160*24), d = ld4b(b0 + 160*24 + 24);
  float4 r;
  r.x = 0.25f*(a.x + b.x + cc.x + d.x);
  r.y = 0.25f*(a.y + b.y + cc.y + d.y);
  r.z = 0.25f*(a.z + b.z + cc.z + d.z);
  r.w = 0.25f*(a.w + b.w + cc.w + d.w);
  st4b(fc + ((size_t)(v*60 + y)*80 + x)*160 + 120 + c, r);
}

// ---- grid scatter + coords passthrough ----
__global__ void k_scatter(const int* __restrict__ coords, const int* __restrict__ stage,
                          int* __restrict__ grid, int* __restrict__ scn,
                          float* __restrict__ coords_out){
  int n = blockIdx.x*256 + threadIdx.x;
  if (n >= NVOX) return;
  int c0 = coords[n*4], c1 = coords[n*4+1], c2 = coords[n*4+2], c3 = coords[n*4+3];
  coords_out[n*4+0] = (float)c0;
  coords_out[n*4+1] = (float)c1;
  coords_out[n*4+2] = (float)c2;
  coords_out[n*4+3] = (float)c3;
  int sh = 2 - stage[0];
  int s1 = c1 >> sh, s2 = c2 >> sh, s3 = c3 >> sh;
  scn[n*3+0] = s1; scn[n*3+1] = s2; scn[n*3+2] = s3;
  grid[(s1*GS + s2)*GS + s3] = n;
}

// ---- neighbor index precompute + per-64-voxel-group k-slice occupancy mask ----
__global__ void k_nbr(const int* __restrict__ scn, const int* __restrict__ grid,
                      int* __restrict__ nbr, unsigned* __restrict__ gmask){
  int n = blockIdx.x*256 + threadIdx.x;
  if (n >= NVOX) return;
  int sx = scn[n*3+0], sy = scn[n*3+1], sz = scn[n*3+2];
  unsigned msk = 0;
  #pragma unroll 1
  for (int k = 0; k < 27; ++k){
    int dx = k/9 - 1, dy = (k/3)%3 - 1, dz = k%3 - 1;
    int nx = sx+dx, ny = sy+dy, nz = sz+dz;
    int idx = -1;
    if (((unsigned)nx < 96u) && ((unsigned)ny < 96u) && ((unsigned)nz < 96u))
      idx = grid[(nx*GS + ny)*GS + nz];
    nbr[k*NVOX + n] = idx;
    if (__ballot(idx >= 0) != 0ull) msk |= (1u << k);
  }
  if ((threadIdx.x & 63) == 0) gmask[n >> 6] = msk;
}

// ---- projection + bilinear sample + masked mean/var + bn0 ----
// 8 lanes per voxel, 4 channels per lane (uint2 bf16x4 corner loads)
__global__ __launch_bounds__(256) void k_sample(
    const ushort* __restrict__ fuse, const int* __restrict__ coords,
    const float* __restrict__ origin, const float* __restrict__ vsz,
    const float* __restrict__ KR, const float* __restrict__ bn0g,
    const float* __restrict__ bn0b, ushort* __restrict__ F0, float* __restrict__ cnt){
  int tid = blockIdx.x*256 + threadIdx.x;
  int vox = tid >> 3;
  int c4 = tid & 7;
  int c = c4*4;
  float vs = vsz[0];
  float wx = (float)coords[vox*4+1]*vs + origin[0];
  float wy = (float)coords[vox*4+2]*vs + origin[1];
  float wz = (float)coords[vox*4+3]*vs + origin[2];
  float s0=0.f,s1=0.f,s2=0.f,s3=0.f;
  float q0=0.f,q1=0.f,q2=0.f,q3=0.f;
  float den=0.f;
  #pragma unroll 1
  for (int v = 0; v < VN; ++v){
    const float* P = KR + v*12;
    float ix = P[0]*wx + P[1]*wy + P[2]*wz + P[3];
    float iy = P[4]*wx + P[5]*wy + P[6]*wz + P[7];
    float iz = P[8]*wx + P[9]*wy + P[10]*wz + P[11];
    float rz = 1.f/iz;
    float gx = 2.f*(ix*rz)/159.f - 1.f;
    float gy = 2.f*(iy*rz)/119.f - 1.f;
    bool ok = (fabsf(gx) <= 1.f) && (fabsf(gy) <= 1.f) && (iz > 0.f);
    float px = ok ? (gx + 1.f)*0.5f*79.f : 0.f;
    float py = ok ? (gy + 1.f)*0.5f*59.f : 0.f;
    float x0f = floorf(px), y0f = floorf(py);
    float fx = px - x0f, fy = py - y0f;
    int x0 = (int)x0f, y0 = (int)y0f;
    int x1 = min(x0+1, 79), y1 = min(y0+1, 59);
    float mf = ok ? 1.f : 0.f;
    // px<=79 guarantees fx==0 whenever x0==79, so clamped-index corners get weight 0
    float w00 = (1.f-fx)*(1.f-fy)*mf, w01 = fx*(1.f-fy)*mf;
    float w10 = (1.f-fx)*fy*mf,       w11 = fx*fy*mf;
    const ushort* bp = fuse + (size_t)v*4800*32 + c;
    float4 a00 = ld4b(bp + ((size_t)y0*80 + x0)*32);
    float4 a01 = ld4b(bp + ((size_t)y0*80 + x1)*32);
    float4 a10 = ld4b(bp + ((size_t)y1*80 + x0)*32);
    float4 a11 = ld4b(bp + ((size_t)y1*80 + x1)*32);
    float g0 = w00*a00.x + w01*a01.x + w10*a10.x + w11*a11.x;
    float g1 = w00*a00.y + w01*a01.y + w10*a10.y + w11*a11.y;
    float g2 = w00*a00.z + w01*a01.z + w10*a10.z + w11*a11.z;
    float g3 = w00*a00.w + w01*a01.w + w10*a10.w + w11*a11.w;
    s0 += g0; q0 += g0*g0;
    s1 += g1; q1 += g1*g1;
    s2 += g2; q2 += g2*g2;
    s3 += g3; q3 += g3*g3;
    den += mf;
  }
  float iden = 1.f/den;
  float m0 = s0*iden, m1 = s1*iden, m2 = s2*iden, m3 = s3*iden;
  float4 g = ld4(bn0g + c);
  float4 b = ld4(bn0b + c);
  float4 r;
  r.x = g.x*fmaxf(q0*iden - m0*m0, 0.f)*INVS + b.x;
  r.y = g.y*fmaxf(q1*iden - m1*m1, 0.f)*INVS + b.y;
  r.z = g.z*fmaxf(q2*iden - m2*m2, 0.f)*INVS + b.z;
  r.w = g.w*fmaxf(q3*iden - m3*m3, 0.f)*INVS + b.w;
  st4b(F0 + (size_t)vox*32 + c, r);
  if (c4 == 0) cnt[vox] = den;
}

// ---- subm sparse conv 32->32 via MFMA bf16, k-slice skip by group mask ----
template<int MODE>
__global__ __launch_bounds__(256, 4) void k_subm_mfma(
    const ushort* __restrict__ fin, const ushort* __restrict__ w2,
    const int* __restrict__ nbr, const unsigned* __restrict__ gmask,
    const float* __restrict__ lng, const float* __restrict__ lnb,
    ushort* __restrict__ fout){
  int lane = threadIdx.x & 63;
  int wave = threadIdx.x >> 6;
  int vbase = blockIdx.x*256 + wave*64;
  int m = lane & 15;
  int q = lane >> 4;

  f32x4v acc[4][2];
  #pragma unroll
  for (int t = 0; t < 4; ++t){ acc[t][0] = 0.f; acc[t][1] = 0.f; }

  bf16x8 zc = (short)0;
  unsigned rem = gmask[vbase >> 6];
  int id[4] = {-1,-1,-1,-1};
  int k = -1;
  if (rem){
    k = __ffs(rem) - 1; rem &= rem - 1;
    #pragma unroll
    for (int t = 0; t < 4; ++t)
      id[t] = nbr[(size_t)k*NVOX + vbase + t*16 + m];
  }
  while (k >= 0){
    bf16x8 A[4];
    #pragma unroll
    for (int t = 0; t < 4; ++t){
      int i = id[t];
      bf16x8 a = *(const bf16x8*)(fin + (size_t)(i < 0 ? 0 : i)*32 + q*8);
      A[t] = (i < 0) ? zc : a;
    }
    bf16x8 b0 = *(const bf16x8*)(w2 + (size_t)(k*32 + m)*32 + q*8);
    bf16x8 b1 = *(const bf16x8*)(w2 + (size_t)(k*32 + 16 + m)*32 + q*8);
    int k2 = -1;
    int id2[4] = {-1,-1,-1,-1};
    if (rem){
      k2 = __ffs(rem) - 1; rem &= rem - 1;
      #pragma unroll
      for (int t = 0; t < 4; ++t)
        id2[t] = nbr[(size_t)k2*NVOX + vbase + t*16 + m];
    }
    #pragma unroll
    for (int t = 0; t < 4; ++t){
      acc[t][0] = __builtin_amdgcn_mfma_f32_16x16x32_bf16(A[t], b0, acc[t][0], 0, 0, 0);
      acc[t][1] = __builtin_amdgcn_mfma_f32_16x16x32_bf16(A[t], b1, acc[t][1], 0, 0, 0);
    }
    #pragma unroll
    for (int t = 0; t < 4; ++t) id[t] = id2[t];
    k = k2;
  }

  int ch0 = m, ch1 = 16 + m;
  float g0 = 0.f, g1 = 0.f, bb0 = 0.f, bb1 = 0.f;
  if (MODE == 1){ g0 = lng[ch0]; g1 = lng[ch1]; bb0 = lnb[ch0]; bb1 = lnb[ch1]; }
  #pragma unroll
  for (int t = 0; t < 4; ++t){
    #pragma unroll
    for (int r = 0; r < 4; ++r){
      int vox = vbase + t*16 + q*4 + r;
      float x0 = fmaxf(acc[t][0][r], 0.f);
      float x1 = fmaxf(acc[t][1][r], 0.f);
      if (MODE == 1){
        x0 += b2f(fin[(size_t)vox*32 + ch0]);
        x1 += b2f(fin[(size_t)vox*32 + ch1]);
        float s = x0 + x1;
        s += __shfl_xor(s, 1, 16);
        s += __shfl_xor(s, 2, 16);
        s += __shfl_xor(s, 4, 16);
        s += __shfl_xor(s, 8, 16);
        float mean = s * (1.f/32.f);
        float d0 = x0 - mean, d1 = x1 - mean;
        float v2 = d0*d0 + d1*d1;
        v2 += __shfl_xor(v2, 1, 16);
        v2 += __shfl_xor(v2, 2, 16);
        v2 += __shfl_xor(v2, 4, 16);
        v2 += __shfl_xor(v2, 8, 16);
        float rs = 1.f / sqrtf(v2*(1.f/32.f) + 1e-5f);
        x0 = d0*rs*g0 + bb0;
        x1 = d1*rs*g1 + bb1;
      }
      fout[(size_t)vox*32 + ch0] = f2b(x0);
      fout[(size_t)vox*32 + ch1] = f2b(x1);
    }
  }
}

// ---- final subm 32->1 + bn, k-slice skip by group mask ----
__global__ __launch_bounds__(256) void k_s4(
    const ushort* __restrict__ fin, const float* __restrict__ w4,
    const int* __restrict__ nbr, const unsigned* __restrict__ gmask,
    const float* __restrict__ bn4g, const float* __restrict__ bn4b,
    float* __restrict__ occ){
  int n = blockIdx.x*256 + threadIdx.x;
  if (n >= NVOX) return;
  unsigned gm = gmask[(blockIdx.x*256 + (threadIdx.x & ~63)) >> 6];
  float acc = 0.f;
  #pragma unroll 1
  for (int k = 0; k < 27; ++k){
    if (!((gm >> k) & 1u)) continue;
    int idx = nbr[(size_t)k*NVOX + n];
    if (idx >= 0){
      const uint4* r4 = (const uint4*)(fin + (size_t)idx*32);
      const float* wk = w4 + k*32;
      #pragma unroll
      for (int u = 0; u < 4; ++u){
        uint4 d = r4[u];
        const float* w8 = wk + u*8;
        acc += blo(d.x)*w8[0] + bhi(d.x)*w8[1];
        acc += blo(d.y)*w8[2] + bhi(d.y)*w8[3];
        acc += blo(d.z)*w8[4] + bhi(d.z)*w8[5];
        acc += blo(d.w)*w8[6] + bhi(d.w)*w8[7];
      }
    }
  }
  occ[n] = bn4g[0]*acc*INVS + bn4b[0];
}

extern "C" void kernel_launch(void* const* d_in, const int* in_sizes, int n_in,
                              void* d_out, int out_size, void* d_ws, size_t ws_size,
                              hipStream_t stream){
  const float* feats1 = (const float*)d_in[0];
  const float* feats2 = (const float*)d_in[1];
  const float* feats4 = (const float*)d_in[2];
  const int*   coords = (const int*)d_in[3];
  const float* origin = (const float*)d_in[4];
  const float* vsz    = (const float*)d_in[5];
  const float* KR     = (const float*)d_in[6];
  const float* w_f1 = (const float*)d_in[7];  const float* b_f1 = (const float*)d_in[8];
  const float* w_f2 = (const float*)d_in[9];  const float* b_f2 = (const float*)d_in[10];
  const float* w_f4 = (const float*)d_in[11]; const float* b_f4 = (const float*)d_in[12];
  const float* w_dn = (const float*)d_in[13]; const float* b_dn = (const float*)d_in[14];
  const float* w_p[4] = {(const float*)d_in[15], (const float*)d_in[17],
                         (const float*)d_in[19], (const float*)d_in[21]};
  const float* b_p[4] = {(const float*)d_in[16], (const float*)d_in[18],
                         (const float*)d_in[20], (const float*)d_in[22]};
  const float* bn0g = (const float*)d_in[23]; const float* bn0b = (const float*)d_in[24];
  const float* w_elan = (const float*)d_in[25];
  const float* w_s1 = (const float*)d_in[26]; const float* ln1g = (const float*)d_in[27]; const float* ln1b = (const float*)d_in[28];
  const float* w_s2 = (const float*)d_in[29]; const float* ln2g = (const float*)d_in[30]; const float* ln2b = (const float*)d_in[31];
  const float* w_s3 = (const float*)d_in[32]; const float* ln3g = (const float*)d_in[33]; const float* ln3b = (const float*)d_in[34];
  const float* w_s4 = (const float*)d_in[35]; const float* bn4g = (const float*)d_in[36]; const float* bn4b = (const float*)d_in[37];
  const int* stage  = (const int*)d_in[38];
  float* out = (float*)d_out;
  char* base = (char*)d_ws;

  size_t off = 0;
  auto alloc = [&](size_t bytes)->char*{ char* p = base + off; off += (bytes + 255) & ~(size_t)255; return p; };
  ushort* nhwc1 = (ushort*)alloc((size_t)9*30*40*96*2);
  ushort* nhwc2 = (ushort*)alloc((size_t)9*60*80*64*2);
  ushort* nhwc4 = (ushort*)alloc((size_t)9*120*160*32*2);
  ushort* t1    = (ushort*)alloc((size_t)9*30*40*80*2);
  ushort* t4    = (ushort*)alloc((size_t)9*120*160*24*2);
  ushort* fcat  = (ushort*)alloc((size_t)9*60*80*160*2);
  ushort* A     = (ushort*)alloc((size_t)9*60*80*32*2);
  ushort* B     = (ushort*)alloc((size_t)9*60*80*32*2);
  ushort* Fb0   = (ushort*)alloc((size_t)NVOX*32*2);
  ushort* Fb1   = (ushort*)alloc((size_t)NVOX*32*2);
  int*    nbr   = (int*)alloc((size_t)27*NVOX*4);
  int*    grid  = (int*)alloc((size_t)GS*GS*GS*4);
  int*    scn   = (int*)alloc((size_t)NVOX*3*4);
  unsigned* gmask = (unsigned*)alloc((size_t)(NVOX/64)*4);
  ushort* wf1   = (ushort*)alloc(9*3*80*32*2);
  ushort* wf2   = (ushort*)alloc(9*2*48*32*2);
  ushort* wf4   = (ushort*)alloc(9*1*32*32*2);
  ushort* wdn   = (ushort*)alloc(1*5*32*32*2);
  ushort* wp0   = (ushort*)alloc(9*1*32*32*2);
  ushort* wp1   = (ushort*)alloc(9*1*32*32*2);
  ushort* wp2   = (ushort*)alloc(9*1*32*32*2);
  ushort* wp3   = (ushort*)alloc(9*1*32*32*2);
  ushort* w2e   = (ushort*)alloc(27*1024*2);
  ushort* w2s1  = (ushort*)alloc(27*1024*2);
  ushort* w2s2  = (ushort*)alloc(27*1024*2);
  ushort* w2s3  = (ushort*)alloc(27*1024*2);

  auto nb = [](int total){ return (total + 255)/256; };

  hipMemsetAsync(fcat, 0, (size_t)9*60*80*160*2, stream);
  hipMemsetAsync(grid, 0xFF, (size_t)GS*GS*GS*4, stream);

  k_wprep2<<<nb(9*3*80*32),256,0,stream>>>(w_f1, wf1, 80, 80, 3, 3, 80);
  k_wprep2<<<nb(9*2*48*32),256,0,stream>>>(w_f2, wf2, 40, 40, 3, 2, 48);
  k_wprep2<<<nb(9*1*32*32),256,0,stream>>>(w_f4, wf4, 24, 24, 3, 1, 32);
  k_wprep2<<<nb(1*5*32*32),256,0,stream>>>(w_dn, wdn, 32, 144, 1, 5, 32);
  k_wprep2<<<nb(9*1*32*32),256,0,stream>>>(w_p[0], wp0, 32, 32, 3, 1, 32);
  k_wprep2<<<nb(9*1*32*32),256,0,stream>>>(w_p[1], wp1, 32, 32, 3, 1, 32);
  k_wprep2<<<nb(9*1*32*32),256,0,stream>>>(w_p[2], wp2, 32, 32, 3, 1, 32);
  k_wprep2<<<nb(9*1*32*32),256,0,stream>>>(w_p[3], wp3, 32, 32, 3, 1, 32);
  k_wprep<<<nb(27648),256,0,stream>>>(w_elan, w2e);
  k_wprep<<<nb(27648),256,0,stream>>>(w_s1, w2s1);
  k_wprep<<<nb(27648),256,0,stream>>>(w_s2, w2s2);
  k_wprep<<<nb(27648),256,0,stream>>>(w_s3, w2s3);

  { int t = 9*30*40*96;   k_nhwcb<<<nb(t),256,0,stream>>>(feats1, nhwc1, 80, 96, 30, 40, t); }
  { int t = 9*60*80*64;   k_nhwcb<<<nb(t),256,0,stream>>>(feats2, nhwc2, 40, 64, 60, 80, t); }
  { int t = 9*120*160*32; k_nhwcb<<<nb(t),256,0,stream>>>(feats4, nhwc4, 24, 32, 120, 160, t); }

  k_conv_mfma<3,5,9><<<nb(10800),256,0,stream>>>(nhwc1, wf1, b_f1, t1, 30, 40, 10800, 80, 80, 0, nullptr);
  k_conv_mfma<2,3,9><<<nb(43200),256,0,stream>>>(nhwc2, wf2, b_f2, fcat, 60, 80, 43200, 40, 160, 80, nullptr);
  k_conv_mfma<1,2,9><<<nb(172800),256,0,stream>>>(nhwc4, wf4, b_f4, t4, 120, 160, 172800, 24, 24, 0, nullptr);

  { int t = 9*60*80*20; k_resize<<<nb(t),256,0,stream>>>(t1, fcat, t); }
  { int t = 9*60*80*6;  k_pool<<<nb(t),256,0,stream>>>(t4, fcat, t); }

  k_conv_mfma<5,2,1><<<nb(43200),256,0,stream>>>(fcat, wdn, b_dn, A, 60, 80, 43200, 32, 32, 0, nullptr);
  k_conv_mfma<1,2,9><<<nb(43200),256,0,stream>>>(A, wp0, b_p[0], B, 60, 80, 43200, 32, 32, 0, A);
  k_conv_mfma<1,2,9><<<nb(43200),256,0,stream>>>(B, wp1, b_p[1], A, 60, 80, 43200, 32, 32, 0, B);
  k_conv_mfma<1,2,9><<<nb(43200),256,0,stream>>>(A, wp2, b_p[2], B, 60, 80, 43200, 32, 32, 0, A);
  k_conv_mfma<1,2,9><<<nb(43200),256,0,stream>>>(B, wp3, b_p[3], A, 60, 80, 43200, 32, 32, 0, B);

  k_scatter<<<nb(NVOX),256,0,stream>>>(coords, stage, grid, scn, out + NVOX);
  k_nbr<<<nb(NVOX),256,0,stream>>>(scn, grid, nbr, gmask);

  k_sample<<<NVOX/32,256,0,stream>>>(A, coords, origin, vsz, KR, bn0g, bn0b, Fb0, out + 5*NVOX);

  k_subm_mfma<0><<<NVOX/256,256,0,stream>>>(Fb0, w2e,  nbr, gmask, nullptr, nullptr, Fb1);
  k_subm_mfma<1><<<NVOX/256,256,0,stream>>>(Fb1, w2s1, nbr, gmask, ln1g, ln1b, Fb0);
  k_subm_mfma<1><<<NVOX/256,256,0,stream>>>(Fb0, w2s2, nbr, gmask, ln2g, ln2b, Fb1);
  k_subm_mfma<1><<<NVOX/256,256,0,stream>>>(Fb1, w2s3, nbr, gmask, ln3g, ln3b, Fb0);
  k_s4<<<nb(NVOX),256,0,stream>>>(Fb0, w_s4, nbr, gmask, bn4g, bn4b, out);
}

// Round 5
// 455.420 us; speedup vs baseline: 7.3915x; 1.0714x over previous
//
#include <hip/hip_runtime.h>
#include <math.h>

#define VN 9
#define NVOX 131072
#define GS 96
static constexpr float INVS = 0.9999950000374997f; // 1/sqrt(1+1e-5)

typedef short bf16x8 __attribute__((ext_vector_type(8)));
typedef float f32x4v __attribute__((ext_vector_type(4)));

__device__ inline float4 ld4(const float* p){ return *reinterpret_cast<const float4*>(p); }

__device__ inline ushort f2b(float f){
  unsigned u = __float_as_uint(f);
  unsigned r = (u + 0x7fffu + ((u >> 16) & 1u)) >> 16;
  return (ushort)r;
}
__device__ inline float b2f(ushort s){ return __uint_as_float(((unsigned)s) << 16); }
__device__ inline float blo(unsigned u){ return __uint_as_float(u << 16); }
__device__ inline float bhi(unsigned u){ return __uint_as_float(u & 0xffff0000u); }

__device__ inline float4 ld4b(const ushort* p){
  uint2 u = *reinterpret_cast<const uint2*>(p);
  float4 r; r.x = blo(u.x); r.y = bhi(u.x); r.z = blo(u.y); r.w = bhi(u.y); return r;
}
__device__ inline void st4b(ushort* p, float4 v){
  uint2 u;
  u.x = (unsigned)f2b(v.x) | ((unsigned)f2b(v.y) << 16);
  u.y = (unsigned)f2b(v.z) | ((unsigned)f2b(v.w) << 16);
  *reinterpret_cast<uint2*>(p) = u;
}

// ---- device helpers for weight prep ----
__device__ inline void wprep2_dev(const float* __restrict__ w, ushort* __restrict__ o,
                                  int Cout, int Cin, int K, int CK, int CoutPad, int tid){
  int ci32 = tid & 31;
  int co = (tid >> 5) % CoutPad;
  int ck = (tid / (32*CoutPad)) % CK;
  int tap = tid / (32*CoutPad*CK);
  int ci = ck*32 + ci32;
  float v = 0.f;
  if (co < Cout && ci < Cin) v = w[(size_t)(co*Cin + ci)*K*K + tap];
  o[tid] = f2b(v);
}
__device__ inline void wprep_dev(const float* __restrict__ w, ushort* __restrict__ o, int tid){
  int k = tid >> 10;
  int r = tid & 1023;
  int co = r >> 5;
  int ci = r & 31;
  o[tid] = f2b(w[k*1024 + ci*32 + co]);
}

// ---- one mega prep kernel: 12 weight preps + grid clear ----
__global__ void k_prep(
    const float* wf1s, const float* wf2s, const float* wf4s, const float* wdns,
    const float* wp0s, const float* wp1s, const float* wp2s, const float* wp3s,
    const float* wes, const float* ws1s, const float* ws2s, const float* ws3s,
    ushort* wf1, ushort* wf2, ushort* wf4, ushort* wdn,
    ushort* wp0, ushort* wp1, ushort* wp2, ushort* wp3,
    ushort* w2e, ushort* w2s1, ushort* w2s2, ushort* w2s3,
    int* grid){
  int bid = blockIdx.x;
  int tx = threadIdx.x;
  if (bid < 270){ int t = bid*256+tx; if (t < 69120) wprep2_dev(wf1s, wf1, 80, 80, 3, 3, 80, t); return; }
  bid -= 270;
  if (bid < 108){ int t = bid*256+tx; if (t < 27648) wprep2_dev(wf2s, wf2, 40, 40, 3, 2, 48, t); return; }
  bid -= 108;
  if (bid < 36){ int t = bid*256+tx; if (t < 9216) wprep2_dev(wf4s, wf4, 24, 24, 3, 1, 32, t); return; }
  bid -= 36;
  if (bid < 20){ int t = bid*256+tx; if (t < 5120) wprep2_dev(wdns, wdn, 32, 144, 1, 5, 32, t); return; }
  bid -= 20;
  if (bid < 36){ int t = bid*256+tx; if (t < 9216) wprep2_dev(wp0s, wp0, 32, 32, 3, 1, 32, t); return; }
  bid -= 36;
  if (bid < 36){ int t = bid*256+tx; if (t < 9216) wprep2_dev(wp1s, wp1, 32, 32, 3, 1, 32, t); return; }
  bid -= 36;
  if (bid < 36){ int t = bid*256+tx; if (t < 9216) wprep2_dev(wp2s, wp2, 32, 32, 3, 1, 32, t); return; }
  bid -= 36;
  if (bid < 36){ int t = bid*256+tx; if (t < 9216) wprep2_dev(wp3s, wp3, 32, 32, 3, 1, 32, t); return; }
  bid -= 36;
  if (bid < 108){ int t = bid*256+tx; if (t < 27648) wprep_dev(wes, w2e, t); return; }
  bid -= 108;
  if (bid < 108){ int t = bid*256+tx; if (t < 27648) wprep_dev(ws1s, w2s1, t); return; }
  bid -= 108;
  if (bid < 108){ int t = bid*256+tx; if (t < 27648) wprep_dev(ws2s, w2s2, t); return; }
  bid -= 108;
  if (bid < 108){ int t = bid*256+tx; if (t < 27648) wprep_dev(ws3s, w2s3, t); return; }
  bid -= 108;
  { int t = bid*256+tx; if (t < GS*GS*GS) grid[t] = -1; }
}

// ---- merged NCHW fp32 -> NHWC bf16 (3 tensors, channel-padded) ----
__device__ inline void nhwcb_dev(const float* __restrict__ in, ushort* __restrict__ out,
                                 int C, int Cpad, int H, int W, int tid){
  int c = tid % Cpad;
  int x = (tid / Cpad) % W;
  int y = (tid / (Cpad*W)) % H;
  int v = tid / (Cpad*W*H);
  out[tid] = (c < C) ? f2b(in[((size_t)(v*C + c)*H + y)*W + x]) : (ushort)0;
}
__global__ void k_nhwcb3(const float* f1, const float* f2, const float* f4,
                         ushort* o1, ushort* o2, ushort* o4){
  int t = blockIdx.x*256 + threadIdx.x;
  const int R1 = 9*30*40*96, R2 = 9*60*80*64, R3 = 9*120*160*32;
  if (t < R1){ nhwcb_dev(f1, o1, 80, 96, 30, 40, t); return; }
  t -= R1;
  if (t < R2){ nhwcb_dev(f2, o2, 40, 64, 60, 80, t); return; }
  t -= R2;
  if (t < R3){ nhwcb_dev(f4, o4, 24, 32, 120, 160, t); }
}

// ---- implicit-GEMM conv via MFMA. wave=64 pixels (4 M-tiles), NT n-tiles ----
template<int CK, int NT, int TAPS>
__global__ __launch_bounds__(256) void k_conv_mfma(
    const ushort* __restrict__ fin, const ushort* __restrict__ w2,
    const float* __restrict__ bias, ushort* __restrict__ outp,
    int H, int W, int total, int Cout, int outStride, int outOff,
    const ushort* __restrict__ skipin){
  constexpr int CIN = CK*32;
  constexpr int COP = NT*16;
  int lane = threadIdx.x & 63;
  int wave = threadIdx.x >> 6;
  int vbase = blockIdx.x*256 + wave*64;
  int m = lane & 15, q = lane >> 4;
  int HW = H*W;
  int p[4], py[4], px[4]; bool pin[4];
  #pragma unroll
  for (int t = 0; t < 4; ++t){
    int pp = vbase + t*16 + m;
    pin[t] = pp < total;
    if (pp > total-1) pp = total-1;
    p[t] = pp;
    int v = pp / HW; int rem = pp - v*HW;
    int y = rem / W;
    py[t] = y; px[t] = rem - y*W;
  }
  f32x4v acc[4][NT];
  #pragma unroll
  for (int t = 0; t < 4; ++t)
    #pragma unroll
    for (int n = 0; n < NT; ++n) acc[t][n] = 0.f;
  bf16x8 z = (short)0;

  #pragma unroll 1
  for (int tap = 0; tap < TAPS; ++tap){
    int dy = (TAPS == 9) ? tap/3 - 1 : 0;
    int dx = (TAPS == 9) ? tap%3 - 1 : 0;
    int off = dy*W + dx;
    bool val[4];
    #pragma unroll
    for (int t = 0; t < 4; ++t)
      val[t] = pin[t] && ((unsigned)(py[t]+dy) < (unsigned)H)
                      && ((unsigned)(px[t]+dx) < (unsigned)W);
    #pragma unroll
    for (int ck = 0; ck < CK; ++ck){
      bf16x8 Af[4], Bf[NT];
      #pragma unroll
      for (int t = 0; t < 4; ++t){
        size_t idx = val[t] ? (size_t)(p[t]+off) : 0;
        bf16x8 a = *(const bf16x8*)(fin + idx*CIN + ck*32 + q*8);
        Af[t] = val[t] ? a : z;
      }
      #pragma unroll
      for (int n = 0; n < NT; ++n)
        Bf[n] = *(const bf16x8*)(w2 + ((size_t)((tap*CK+ck)*COP + n*16 + m))*32 + q*8);
      #pragma unroll
      for (int t = 0; t < 4; ++t)
        #pragma unroll
        for (int n = 0; n < NT; ++n)
          acc[t][n] = __builtin_amdgcn_mfma_f32_16x16x32_bf16(Af[t], Bf[n], acc[t][n], 0, 0, 0);
    }
  }

  #pragma unroll
  for (int n = 0; n < NT; ++n){
    int co = n*16 + m;
    bool cok = co < Cout;
    float bs = cok ? bias[co] : 0.f;
    #pragma unroll
    for (int t = 0; t < 4; ++t){
      #pragma unroll
      for (int r = 0; r < 4; ++r){
        int pp = vbase + t*16 + q*4 + r;
        if (pp < total && cok){
          float x = fmaxf(acc[t][n][r] + bs, 0.f);
          if (skipin) x += b2f(skipin[(size_t)pp*CIN + co]);
          outp[(size_t)pp*outStride + outOff + co] = f2b(x);
        }
      }
    }
  }
}

// ---- merged resize + pool (+ fcat pad-zero) ----
__global__ void k_respool(const ushort* __restrict__ t1, const ushort* __restrict__ t4,
                          ushort* __restrict__ fc){
  int tid = blockIdx.x*256 + threadIdx.x;
  if (tid < 864000){
    // bilinear 2x upsample: t1 (V,30,40,80) -> fc[...,0:80)
    int c4 = tid % 20;
    int x  = (tid / 20) % 80;
    int y  = (tid / 1600) % 60;
    int v  = tid / 96000;
    int c = c4*4;
    int ky = y >> 1; int y0, y1; float wy0, wy1;
    if ((y & 1) == 0){ y0 = ky-1; y1 = ky; wy0 = 0.25f; wy1 = 0.75f; if (y0 < 0){ y0 = 0; wy0 = 0.f; wy1 = 1.f; } }
    else             { y0 = ky; y1 = ky+1; wy0 = 0.75f; wy1 = 0.25f; if (y1 > 29){ y1 = 29; wy1 = 0.f; wy0 = 1.f; } }
    int kx = x >> 1; int x0, x1; float wx0, wx1;
    if ((x & 1) == 0){ x0 = kx-1; x1 = kx; wx0 = 0.25f; wx1 = 0.75f; if (x0 < 0){ x0 = 0; wx0 = 0.f; wx1 = 1.f; } }
    else             { x0 = kx; x1 = kx+1; wx0 = 0.75f; wx1 = 0.25f; if (x1 > 39){ x1 = 39; wx1 = 0.f; wx0 = 1.f; } }
    float4 a00 = ld4b(t1 + ((size_t)(v*30 + y0)*40 + x0)*80 + c);
    float4 a01 = ld4b(t1 + ((size_t)(v*30 + y0)*40 + x1)*80 + c);
    float4 a10 = ld4b(t1 + ((size_t)(v*30 + y1)*40 + x0)*80 + c);
    float4 a11 = ld4b(t1 + ((size_t)(v*30 + y1)*40 + x1)*80 + c);
    float w00 = wy0*wx0, w01 = wy0*wx1, w10 = wy1*wx0, w11 = wy1*wx1;
    float4 r;
    r.x = w00*a00.x + w01*a01.x + w10*a10.x + w11*a11.x;
    r.y = w00*a00.y + w01*a01.y + w10*a10.y + w11*a11.y;
    r.z = w00*a00.z + w01*a01.z + w10*a10.z + w11*a11.z;
    r.w = w00*a00.w + w01*a01.w + w10*a10.w + w11*a11.w;
    st4b(fc + ((size_t)(v*60 + y)*80 + x)*160 + c, r);
    return;
  }
  int t = tid - 864000;
  if (t >= 432000) return;
  // pool (c4<6) + pad zero (c4>=6): fc[...,120:144) and [144,160)
  int c4 = t % 10;
  int x  = (t / 10) % 80;
  int y  = (t / 800) % 60;
  int v  = t / 48000;
  if (c4 < 6){
    int c = c4*4;
    const ushort* b0 = t4 + ((size_t)(v*120 + 2*y)*160 + 2*x)*24 + c;
    float4 a = ld4b(b0), b = ld4b(b0 + 24), cc = ld4b(b0 + 160*24), d = ld4b(b0 + 160*24 + 24);
    float4 r;
    r.x = 0.25f*(a.x + b.x + cc.x + d.x);
    r.y = 0.25f*(a.y + b.y + cc.y + d.y);
    r.z = 0.25f*(a.z + b.z + cc.z + d.z);
    r.w = 0.25f*(a.w + b.w + cc.w + d.w);
    st4b(fc + ((size_t)(v*60 + y)*80 + x)*160 + 120 + c, r);
  } else {
    float4 zz = {0.f,0.f,0.f,0.f};
    st4b(fc + ((size_t)(v*60 + y)*80 + x)*160 + 144 + (c4-6)*4, zz);
  }
}

// ---- grid scatter + coords passthrough + projection/sample-table + count ----
__global__ void k_scatter(const int* __restrict__ coords, const int* __restrict__ stage,
                          int* __restrict__ grid, int* __restrict__ scn,
                          float* __restrict__ coords_out,
                          const float* __restrict__ origin, const float* __restrict__ vsz,
                          const float* __restrict__ KR,
                          uint4* __restrict__ samp, float* __restrict__ cnt){
  int n = blockIdx.x*256 + threadIdx.x;
  if (n >= NVOX) return;
  int c0 = coords[n*4], c1 = coords[n*4+1], c2 = coords[n*4+2], c3 = coords[n*4+3];
  coords_out[n*4+0] = (float)c0;
  coords_out[n*4+1] = (float)c1;
  coords_out[n*4+2] = (float)c2;
  coords_out[n*4+3] = (float)c3;
  int sh = 2 - stage[0];
  int s1 = c1 >> sh, s2 = c2 >> sh, s3 = c3 >> sh;
  scn[n*3+0] = s1; scn[n*3+1] = s2; scn[n*3+2] = s3;
  grid[(s1*GS + s2)*GS + s3] = n;

  float vs = vsz[0];
  float wx = (float)c1*vs + origin[0];
  float wy = (float)c2*vs + origin[1];
  float wz = (float)c3*vs + origin[2];
  float den = 0.f;
  #pragma unroll 1
  for (int v = 0; v < VN; ++v){
    const float* P = KR + v*12;
    float ix = P[0]*wx + P[1]*wy + P[2]*wz + P[3];
    float iy = P[4]*wx + P[5]*wy + P[6]*wz + P[7];
    float iz = P[8]*wx + P[9]*wy + P[10]*wz + P[11];
    float rz = 1.f/iz;
    float gx = 2.f*(ix*rz)/159.f - 1.f;
    float gy = 2.f*(iy*rz)/119.f - 1.f;
    bool ok = (fabsf(gx) <= 1.f) && (fabsf(gy) <= 1.f) && (iz > 0.f);
    float px = ok ? (gx + 1.f)*0.5f*79.f : 0.f;
    float py = ok ? (gy + 1.f)*0.5f*59.f : 0.f;
    float x0f = floorf(px), y0f = floorf(py);
    float fx = px - x0f, fy = py - y0f;
    int idx = (int)y0f*80 + (int)x0f;
    float mf = ok ? 1.f : 0.f;
    float w00 = (1.f-fx)*(1.f-fy)*mf, w01 = fx*(1.f-fy)*mf;
    float w10 = (1.f-fx)*fy*mf,       w11 = fx*fy*mf;
    uint4 s;
    s.x = (unsigned)idx;
    s.y = (unsigned)f2b(w00) | ((unsigned)f2b(w01) << 16);
    s.z = (unsigned)f2b(w10) | ((unsigned)f2b(w11) << 16);
    s.w = 0;
    samp[(size_t)v*NVOX + n] = s;
    den += mf;
  }
  cnt[n] = den;
}

// ---- neighbor index precompute + per-16-voxel k-slice occupancy mask ----
__global__ void k_nbr(const int* __restrict__ scn, const int* __restrict__ grid,
                      int* __restrict__ nbr, unsigned* __restrict__ gmask16){
  int n = blockIdx.x*256 + threadIdx.x;
  if (n >= NVOX) return;
  int lane = threadIdx.x & 63;
  int sx = scn[n*3+0], sy = scn[n*3+1], sz = scn[n*3+2];
  unsigned msk = 0;
  #pragma unroll 1
  for (int k = 0; k < 27; ++k){
    int dx = k/9 - 1, dy = (k/3)%3 - 1, dz = k%3 - 1;
    int nx = sx+dx, ny = sy+dy, nz = sz+dz;
    int idx = -1;
    if (((unsigned)nx < 96u) && ((unsigned)ny < 96u) && ((unsigned)nz < 96u))
      idx = grid[(nx*GS + ny)*GS + nz];
    nbr[k*NVOX + n] = idx;
    unsigned long long b = __ballot(idx >= 0);
    unsigned sub = (unsigned)((b >> ((lane >> 4)*16)) & 0xFFFFull);
    if (sub) msk |= (1u << k);
  }
  if ((lane & 15) == 0) gmask16[n >> 4] = msk;
}

// ---- sampling from precomputed table + masked mean/var + bn0 ----
// 8 lanes per voxel, 4 channels per lane
__global__ __launch_bounds__(256) void k_sample(
    const ushort* __restrict__ fuse, const uint4* __restrict__ samp,
    const float* __restrict__ cnt, const float* __restrict__ bn0g,
    const float* __restrict__ bn0b, ushort* __restrict__ F0){
  int tid = blockIdx.x*256 + threadIdx.x;
  int vox = tid >> 3;
  int c4 = tid & 7;
  int c = c4*4;
  float s0=0.f,s1=0.f,s2=0.f,s3=0.f;
  float q0=0.f,q1=0.f,q2=0.f,q3=0.f;
  #pragma unroll 1
  for (int v = 0; v < VN; ++v){
    uint4 sv = samp[(size_t)v*NVOX + vox];
    float w00 = blo(sv.y), w01 = bhi(sv.y);
    float w10 = blo(sv.z), w11 = bhi(sv.z);
    const ushort* bp = fuse + (size_t)v*153600 + (size_t)sv.x*32 + c;
    float4 a00 = ld4b(bp);
    float4 a01 = ld4b(bp + 32);
    float4 a10 = ld4b(bp + 2560);
    float4 a11 = ld4b(bp + 2592);
    float g0 = w00*a00.x + w01*a01.x + w10*a10.x + w11*a11.x;
    float g1 = w00*a00.y + w01*a01.y + w10*a10.y + w11*a11.y;
    float g2 = w00*a00.z + w01*a01.z + w10*a10.z + w11*a11.z;
    float g3 = w00*a00.w + w01*a01.w + w10*a10.w + w11*a11.w;
    s0 += g0; q0 += g0*g0;
    s1 += g1; q1 += g1*g1;
    s2 += g2; q2 += g2*g2;
    s3 += g3; q3 += g3*g3;
  }
  float iden = 1.f/cnt[vox];
  float m0 = s0*iden, m1 = s1*iden, m2 = s2*iden, m3 = s3*iden;
  float4 g = ld4(bn0g + c);
  float4 b = ld4(bn0b + c);
  float4 r;
  r.x = g.x*fmaxf(q0*iden - m0*m0, 0.f)*INVS + b.x;
  r.y = g.y*fmaxf(q1*iden - m1*m1, 0.f)*INVS + b.y;
  r.z = g.z*fmaxf(q2*iden - m2*m2, 0.f)*INVS + b.z;
  r.w = g.w*fmaxf(q3*iden - m3*m3, 0.f)*INVS + b.w;
  st4b(F0 + (size_t)vox*32 + c, r);
}

// ---- subm sparse conv 32->32 via MFMA bf16, 16 voxels/wave, k-slice skip ----
template<int MODE>
__global__ __launch_bounds__(256, 8) void k_subm_mfma(
    const ushort* __restrict__ fin, const ushort* __restrict__ w2,
    const int* __restrict__ nbr, const unsigned* __restrict__ gmask16,
    const float* __restrict__ lng, const float* __restrict__ lnb,
    ushort* __restrict__ fout){
  int lane = threadIdx.x & 63;
  int wave = threadIdx.x >> 6;
  int vb = blockIdx.x*64 + wave*16;
  int m = lane & 15;
  int q = lane >> 4;

  f32x4v acc0 = 0.f, acc1 = 0.f;
  bf16x8 zc = (short)0;
  unsigned rem = gmask16[vb >> 4];
  int id = -1;
  int k = -1;
  if (rem){
    k = __ffs(rem) - 1; rem &= rem - 1;
    id = nbr[(size_t)k*NVOX + vb + m];
  }
  while (k >= 0){
    bf16x8 A;
    {
      bf16x8 a = *(const bf16x8*)(fin + (size_t)(id < 0 ? 0 : id)*32 + q*8);
      A = (id < 0) ? zc : a;
    }
    bf16x8 b0 = *(const bf16x8*)(w2 + (size_t)(k*32 + m)*32 + q*8);
    bf16x8 b1 = *(const bf16x8*)(w2 + (size_t)(k*32 + 16 + m)*32 + q*8);
    int k2 = -1, id2 = -1;
    if (rem){
      k2 = __ffs(rem) - 1; rem &= rem - 1;
      id2 = nbr[(size_t)k2*NVOX + vb + m];
    }
    acc0 = __builtin_amdgcn_mfma_f32_16x16x32_bf16(A, b0, acc0, 0, 0, 0);
    acc1 = __builtin_amdgcn_mfma_f32_16x16x32_bf16(A, b1, acc1, 0, 0, 0);
    id = id2; k = k2;
  }

  int ch0 = m, ch1 = 16 + m;
  float g0 = 0.f, g1 = 0.f, bb0 = 0.f, bb1 = 0.f;
  if (MODE == 1){ g0 = lng[ch0]; g1 = lng[ch1]; bb0 = lnb[ch0]; bb1 = lnb[ch1]; }
  #pragma unroll
  for (int r = 0; r < 4; ++r){
    int vox = vb + q*4 + r;
    float x0 = fmaxf(acc0[r], 0.f);
    float x1 = fmaxf(acc1[r], 0.f);
    if (MODE == 1){
      x0 += b2f(fin[(size_t)vox*32 + ch0]);
      x1 += b2f(fin[(size_t)vox*32 + ch1]);
      float s = x0 + x1;
      s += __shfl_xor(s, 1, 16);
      s += __shfl_xor(s, 2, 16);
      s += __shfl_xor(s, 4, 16);
      s += __shfl_xor(s, 8, 16);
      float mean = s * (1.f/32.f);
      float d0 = x0 - mean, d1 = x1 - mean;
      float v2 = d0*d0 + d1*d1;
      v2 += __shfl_xor(v2, 1, 16);
      v2 += __shfl_xor(v2, 2, 16);
      v2 += __shfl_xor(v2, 4, 16);
      v2 += __shfl_xor(v2, 8, 16);
      float rs = 1.f / sqrtf(v2*(1.f/32.f) + 1e-5f);
      x0 = d0*rs*g0 + bb0;
      x1 = d1*rs*g1 + bb1;
    }
    fout[(size_t)vox*32 + ch0] = f2b(x0);
    fout[(size_t)vox*32 + ch1] = f2b(x1);
  }
}

// ---- final subm 32->1 + bn, k-slice skip by per-16 mask ----
__global__ __launch_bounds__(256) void k_s4(
    const ushort* __restrict__ fin, const float* __restrict__ w4,
    const int* __restrict__ nbr, const unsigned* __restrict__ gmask16,
    const float* __restrict__ bn4g, const float* __restrict__ bn4b,
    float* __restrict__ occ){
  int n = blockIdx.x*256 + threadIdx.x;
  if (n >= NVOX) return;
  unsigned gm = gmask16[n >> 4];
  float acc = 0.f;
  #pragma unroll 1
  for (int k = 0; k < 27; ++k){
    if (!((gm >> k) & 1u)) continue;
    int idx = nbr[(size_t)k*NVOX + n];
    if (idx >= 0){
      const uint4* r4 = (const uint4*)(fin + (size_t)idx*32);
      const float* wk = w4 + k*32;
      #pragma unroll
      for (int u = 0; u < 4; ++u){
        uint4 d = r4[u];
        const float* w8 = wk + u*8;
        acc += blo(d.x)*w8[0] + bhi(d.x)*w8[1];
        acc += blo(d.y)*w8[2] + bhi(d.y)*w8[3];
        acc += blo(d.z)*w8[4] + bhi(d.z)*w8[5];
        acc += blo(d.w)*w8[6] + bhi(d.w)*w8[7];
      }
    }
  }
  occ[n] = bn4g[0]*acc*INVS + bn4b[0];
}

extern "C" void kernel_launch(void* const* d_in, const int* in_sizes, int n_in,
                              void* d_out, int out_size, void* d_ws, size_t ws_size,
                              hipStream_t stream){
  const float* feats1 = (const float*)d_in[0];
  const float* feats2 = (const float*)d_in[1];
  const float* feats4 = (const float*)d_in[2];
  const int*   coords = (const int*)d_in[3];
  const float* origin = (const float*)d_in[4];
  const float* vsz    = (const float*)d_in[5];
  const float* KR     = (const float*)d_in[6];
  const float* w_f1 = (const float*)d_in[7];  const float* b_f1 = (const float*)d_in[8];
  const float* w_f2 = (const float*)d_in[9];  const float* b_f2 = (const float*)d_in[10];
  const float* w_f4 = (const float*)d_in[11]; const float* b_f4 = (const float*)d_in[12];
  const float* w_dn = (const float*)d_in[13]; const float* b_dn = (const float*)d_in[14];
  const float* w_p[4] = {(const float*)d_in[15], (const float*)d_in[17],
                         (const float*)d_in[19], (const float*)d_in[21]};
  const float* b_p[4] = {(const float*)d_in[16], (const float*)d_in[18],
                         (const float*)d_in[20], (const float*)d_in[22]};
  const float* bn0g = (const float*)d_in[23]; const float* bn0b = (const float*)d_in[24];
  const float* w_elan = (const float*)d_in[25];
  const float* w_s1 = (const float*)d_in[26]; const float* ln1g = (const float*)d_in[27]; const float* ln1b = (const float*)d_in[28];
  const float* w_s2 = (const float*)d_in[29]; const float* ln2g = (const float*)d_in[30]; const float* ln2b = (const float*)d_in[31];
  const float* w_s3 = (const float*)d_in[32]; const float* ln3g = (const float*)d_in[33]; const float* ln3b = (const float*)d_in[34];
  const float* w_s4 = (const float*)d_in[35]; const float* bn4g = (const float*)d_in[36]; const float* bn4b = (const float*)d_in[37];
  const int* stage  = (const int*)d_in[38];
  float* out = (float*)d_out;
  char* base = (char*)d_ws;

  size_t off = 0;
  auto alloc = [&](size_t bytes)->char*{ char* p = base + off; off += (bytes + 255) & ~(size_t)255; return p; };
  ushort* nhwc1 = (ushort*)alloc((size_t)9*30*40*96*2);
  ushort* nhwc2 = (ushort*)alloc((size_t)9*60*80*64*2);
  ushort* nhwc4 = (ushort*)alloc((size_t)9*120*160*32*2);
  ushort* t1    = (ushort*)alloc((size_t)9*30*40*80*2);
  ushort* t4    = (ushort*)alloc((size_t)9*120*160*24*2);
  ushort* fcat  = (ushort*)alloc((size_t)9*60*80*160*2);
  ushort* A     = (ushort*)alloc((size_t)9*60*80*32*2);
  ushort* B     = (ushort*)alloc((size_t)9*60*80*32*2);
  ushort* Fb0   = (ushort*)alloc((size_t)NVOX*32*2);
  ushort* Fb1   = (ushort*)alloc((size_t)NVOX*32*2);
  int*    nbr   = (int*)alloc((size_t)27*NVOX*4);
  int*    grid  = (int*)alloc((size_t)GS*GS*GS*4);
  int*    scn   = (int*)alloc((size_t)NVOX*3*4);
  unsigned* gmask16 = (unsigned*)alloc((size_t)(NVOX/16)*4);
  ushort* wf1   = (ushort*)alloc(9*3*80*32*2);
  ushort* wf2   = (ushort*)alloc(9*2*48*32*2);
  ushort* wf4   = (ushort*)alloc(9*1*32*32*2);
  ushort* wdn   = (ushort*)alloc(1*5*32*32*2);
  ushort* wp0   = (ushort*)alloc(9*1*32*32*2);
  ushort* wp1   = (ushort*)alloc(9*1*32*32*2);
  ushort* wp2   = (ushort*)alloc(9*1*32*32*2);
  ushort* wp3   = (ushort*)alloc(9*1*32*32*2);
  ushort* w2e   = (ushort*)alloc(27*1024*2);
  ushort* w2s1  = (ushort*)alloc(27*1024*2);
  ushort* w2s2  = (ushort*)alloc(27*1024*2);
  ushort* w2s3  = (ushort*)alloc(27*1024*2);
  // samp table (9*NVOX uint4 = 18.9 MB) aliases nhwc2..t4 (dead before k_scatter)
  uint4* samp = (uint4*)nhwc2;

  auto nb = [](int total){ return (total + 255)/256; };

  // mega prep: 12 weight preps + grid clear (4466 blocks)
  k_prep<<<4466,256,0,stream>>>(
      w_f1, w_f2, w_f4, w_dn, w_p[0], w_p[1], w_p[2], w_p[3],
      w_elan, w_s1, w_s2, w_s3,
      wf1, wf2, wf4, wdn, wp0, wp1, wp2, wp3, w2e, w2s1, w2s2, w2s3, grid);

  // NCHW -> NHWC bf16 padded (all 3 tensors)
  k_nhwcb3<<<nb(9*30*40*96 + 9*60*80*64 + 9*120*160*32),256,0,stream>>>(
      feats1, feats2, feats4, nhwc1, nhwc2, nhwc4);

  // head convs
  k_conv_mfma<3,5,9><<<nb(10800),256,0,stream>>>(nhwc1, wf1, b_f1, t1, 30, 40, 10800, 80, 80, 0, nullptr);
  k_conv_mfma<2,3,9><<<nb(43200),256,0,stream>>>(nhwc2, wf2, b_f2, fcat, 60, 80, 43200, 40, 160, 80, nullptr);
  k_conv_mfma<1,2,9><<<nb(172800),256,0,stream>>>(nhwc4, wf4, b_f4, t4, 120, 160, 172800, 24, 24, 0, nullptr);

  // resize + pool + pad-zero
  k_respool<<<nb(864000 + 432000),256,0,stream>>>(t1, t4, fcat);

  // down conv (1x1) + 4 residual blocks
  k_conv_mfma<5,2,1><<<nb(43200),256,0,stream>>>(fcat, wdn, b_dn, A, 60, 80, 43200, 32, 32, 0, nullptr);
  k_conv_mfma<1,2,9><<<nb(43200),256,0,stream>>>(A, wp0, b_p[0], B, 60, 80, 43200, 32, 32, 0, A);
  k_conv_mfma<1,2,9><<<nb(43200),256,0,stream>>>(B, wp1, b_p[1], A, 60, 80, 43200, 32, 32, 0, B);
  k_conv_mfma<1,2,9><<<nb(43200),256,0,stream>>>(A, wp2, b_p[2], B, 60, 80, 43200, 32, 32, 0, A);
  k_conv_mfma<1,2,9><<<nb(43200),256,0,stream>>>(B, wp3, b_p[3], A, 60, 80, 43200, 32, 32, 0, B);

  // scatter (+ sample table + count) ; neighbor table (+ per-16 masks)
  k_scatter<<<nb(NVOX),256,0,stream>>>(coords, stage, grid, scn, out + NVOX,
                                       origin, vsz, KR, samp, out + 5*NVOX);
  k_nbr<<<nb(NVOX),256,0,stream>>>(scn, grid, nbr, gmask16);

  // sampling -> F0 bf16
  k_sample<<<NVOX/32,256,0,stream>>>(A, samp, out + 5*NVOX, bn0g, bn0b, Fb0);

  // sparse conv stack (MFMA, 16 voxels/wave)
  k_subm_mfma<0><<<NVOX/64,256,0,stream>>>(Fb0, w2e,  nbr, gmask16, nullptr, nullptr, Fb1);
  k_subm_mfma<1><<<NVOX/64,256,0,stream>>>(Fb1, w2s1, nbr, gmask16, ln1g, ln1b, Fb0);
  k_subm_mfma<1><<<NVOX/64,256,0,stream>>>(Fb0, w2s2, nbr, gmask16, ln2g, ln2b, Fb1);
  k_subm_mfma<1><<<NVOX/64,256,0,stream>>>(Fb1, w2s3, nbr, gmask16, ln3g, ln3b, Fb0);
  k_s4<<<nb(NVOX),256,0,stream>>>(Fb0, w_s4, nbr, gmask16, bn4g, bn4b, out);
}

// Round 6
// 389.659 us; speedup vs baseline: 8.6389x; 1.1688x over previous
//
#include <hip/hip_runtime.h>
#include <math.h>

#define VN 9
#define NVOX 131072
#define GS 96
static constexpr float INVS = 0.9999950000374997f; // 1/sqrt(1+1e-5)

typedef short bf16x8 __attribute__((ext_vector_type(8)));
typedef float f32x4v __attribute__((ext_vector_type(4)));

__device__ inline float4 ld4(const float* p){ return *reinterpret_cast<const float4*>(p); }

__device__ inline ushort f2b(float f){
  unsigned u = __float_as_uint(f);
  unsigned r = (u + 0x7fffu + ((u >> 16) & 1u)) >> 16;
  return (ushort)r;
}
__device__ inline float b2f(ushort s){ return __uint_as_float(((unsigned)s) << 16); }
__device__ inline float blo(unsigned u){ return __uint_as_float(u << 16); }
__device__ inline float bhi(unsigned u){ return __uint_as_float(u & 0xffff0000u); }

__device__ inline float4 ld4b(const ushort* p){
  uint2 u = *reinterpret_cast<const uint2*>(p);
  float4 r; r.x = blo(u.x); r.y = bhi(u.x); r.z = blo(u.y); r.w = bhi(u.y); return r;
}
__device__ inline void st4b(ushort* p, float4 v){
  uint2 u;
  u.x = (unsigned)f2b(v.x) | ((unsigned)f2b(v.y) << 16);
  u.y = (unsigned)f2b(v.z) | ((unsigned)f2b(v.w) << 16);
  *reinterpret_cast<uint2*>(p) = u;
}

// ---- device helpers for weight prep ----
__device__ inline void wprep2_dev(const float* __restrict__ w, ushort* __restrict__ o,
                                  int Cout, int Cin, int K, int CK, int CoutPad, int tid){
  int ci32 = tid & 31;
  int co = (tid >> 5) % CoutPad;
  int ck = (tid / (32*CoutPad)) % CK;
  int tap = tid / (32*CoutPad*CK);
  int ci = ck*32 + ci32;
  float v = 0.f;
  if (co < Cout && ci < Cin) v = w[(size_t)(co*Cin + ci)*K*K + tap];
  o[tid] = f2b(v);
}
__device__ inline void wprep_dev(const float* __restrict__ w, ushort* __restrict__ o, int tid){
  int k = tid >> 10;
  int r = tid & 1023;
  int co = r >> 5;
  int ci = r & 31;
  o[tid] = f2b(w[k*1024 + ci*32 + co]);
}

// ---- NCHW fp32 -> NHWC bf16 via LDS tile: 64 px x Cpad ch per block ----
__device__ inline void nhwc_tile_dev(const float* __restrict__ in, ushort* __restrict__ out,
                                     int C, int Cpad, int HW, int tile, int tilesPerV,
                                     float* lds, int tx){
  int v  = tile / tilesPerV;
  int p0 = (tile - v*tilesPerV) * 64;
  const float* ip = in + (size_t)v*C*HW + p0;
  // read: coalesced along pixels
  int iters = Cpad >> 2;               // each iter: 4 ch x 64 px
  for (int i = 0; i < iters; ++i){
    int idx = i*256 + tx;
    int c = idx >> 6;
    int p = idx & 63;
    float val = 0.f;
    if (c < C && (p0 + p) < HW) val = ip[(size_t)c*HW + p];
    lds[c*65 + p] = val;
  }
  __syncthreads();
  // write: packed 4-ch uint2 stores, coalesced along channels
  int groups = Cpad >> 2;
  int tot = 64*groups;
  for (int basei = 0; basei < tot; basei += 256){
    int idx = basei + tx;
    if (idx < tot){
      int g  = idx % groups;
      int px = idx / groups;
      if ((p0 + px) < HW){
        float4 r;
        r.x = lds[(g*4+0)*65 + px];
        r.y = lds[(g*4+1)*65 + px];
        r.z = lds[(g*4+2)*65 + px];
        r.w = lds[(g*4+3)*65 + px];
        st4b(out + (size_t)(v*HW + p0 + px)*Cpad + g*4, r);
      }
    }
  }
}

// ---- mega prep kernel: 12 weight preps + grid clear + 3x NHWC transpose ----
__global__ __launch_bounds__(256) void k_prep(
    const float* wf1s, const float* wf2s, const float* wf4s, const float* wdns,
    const float* wp0s, const float* wp1s, const float* wp2s, const float* wp3s,
    const float* wes, const float* ws1s, const float* ws2s, const float* ws3s,
    ushort* wf1, ushort* wf2, ushort* wf4, ushort* wdn,
    ushort* wp0, ushort* wp1, ushort* wp2, ushort* wp3,
    ushort* w2e, ushort* w2s1, ushort* w2s2, ushort* w2s3,
    int* grid,
    const float* f1, const float* f2, const float* f4,
    ushort* o1, ushort* o2, ushort* o4){
  __shared__ float lds[96*65];
  int bid = blockIdx.x;
  int tx = threadIdx.x;
  if (bid < 270){ int t = bid*256+tx; if (t < 69120) wprep2_dev(wf1s, wf1, 80, 80, 3, 3, 80, t); return; }
  bid -= 270;
  if (bid < 108){ int t = bid*256+tx; if (t < 27648) wprep2_dev(wf2s, wf2, 40, 40, 3, 2, 48, t); return; }
  bid -= 108;
  if (bid < 36){ int t = bid*256+tx; if (t < 9216) wprep2_dev(wf4s, wf4, 24, 24, 3, 1, 32, t); return; }
  bid -= 36;
  if (bid < 20){ int t = bid*256+tx; if (t < 5120) wprep2_dev(wdns, wdn, 32, 144, 1, 5, 32, t); return; }
  bid -= 20;
  if (bid < 36){ int t = bid*256+tx; if (t < 9216) wprep2_dev(wp0s, wp0, 32, 32, 3, 1, 32, t); return; }
  bid -= 36;
  if (bid < 36){ int t = bid*256+tx; if (t < 9216) wprep2_dev(wp1s, wp1, 32, 32, 3, 1, 32, t); return; }
  bid -= 36;
  if (bid < 36){ int t = bid*256+tx; if (t < 9216) wprep2_dev(wp2s, wp2, 32, 32, 3, 1, 32, t); return; }
  bid -= 36;
  if (bid < 36){ int t = bid*256+tx; if (t < 9216) wprep2_dev(wp3s, wp3, 32, 32, 3, 1, 32, t); return; }
  bid -= 36;
  if (bid < 108){ int t = bid*256+tx; if (t < 27648) wprep_dev(wes, w2e, t); return; }
  bid -= 108;
  if (bid < 108){ int t = bid*256+tx; if (t < 27648) wprep_dev(ws1s, w2s1, t); return; }
  bid -= 108;
  if (bid < 108){ int t = bid*256+tx; if (t < 27648) wprep_dev(ws2s, w2s2, t); return; }
  bid -= 108;
  if (bid < 108){ int t = bid*256+tx; if (t < 27648) wprep_dev(ws3s, w2s3, t); return; }
  bid -= 108;
  if (bid < 3456){ int t = bid*256+tx; if (t < GS*GS*GS) grid[t] = -1; return; }
  bid -= 3456;
  if (bid < 171){ nhwc_tile_dev(f1, o1, 80, 96, 1200, bid, 19, lds, tx); return; }
  bid -= 171;
  if (bid < 675){ nhwc_tile_dev(f2, o2, 40, 64, 4800, bid, 75, lds, tx); return; }
  bid -= 675;
  if (bid < 2700){ nhwc_tile_dev(f4, o4, 24, 32, 19200, bid, 300, lds, tx); }
}

// ---- implicit-GEMM conv via MFMA. wave = MT*16 pixels, NT n-tiles ----
template<int CK, int NT, int TAPS, int MT>
__global__ __launch_bounds__(256) void k_conv_mfma(
    const ushort* __restrict__ fin, const ushort* __restrict__ w2,
    const float* __restrict__ bias, ushort* __restrict__ outp,
    int H, int W, int total, int Cout, int outStride, int outOff,
    const ushort* __restrict__ skipin){
  constexpr int CIN = CK*32;
  constexpr int COP = NT*16;
  int lane = threadIdx.x & 63;
  int wave = threadIdx.x >> 6;
  int vbase = blockIdx.x*(MT*64) + wave*(MT*16);
  int m = lane & 15, q = lane >> 4;
  int HW = H*W;
  int p[MT], py[MT], px[MT]; bool pin[MT];
  #pragma unroll
  for (int t = 0; t < MT; ++t){
    int pp = vbase + t*16 + m;
    pin[t] = pp < total;
    if (pp > total-1) pp = total-1;
    p[t] = pp;
    int v = pp / HW; int rem = pp - v*HW;
    int y = rem / W;
    py[t] = y; px[t] = rem - y*W;
  }
  f32x4v acc[MT][NT];
  #pragma unroll
  for (int t = 0; t < MT; ++t)
    #pragma unroll
    for (int n = 0; n < NT; ++n) acc[t][n] = 0.f;
  bf16x8 z = (short)0;

  #pragma unroll 1
  for (int tap = 0; tap < TAPS; ++tap){
    int dy = (TAPS == 9) ? tap/3 - 1 : 0;
    int dx = (TAPS == 9) ? tap%3 - 1 : 0;
    int off = dy*W + dx;
    bool val[MT];
    #pragma unroll
    for (int t = 0; t < MT; ++t)
      val[t] = pin[t] && ((unsigned)(py[t]+dy) < (unsigned)H)
                      && ((unsigned)(px[t]+dx) < (unsigned)W);
    #pragma unroll
    for (int ck = 0; ck < CK; ++ck){
      bf16x8 Af[MT], Bf[NT];
      #pragma unroll
      for (int t = 0; t < MT; ++t){
        size_t idx = val[t] ? (size_t)(p[t]+off) : 0;
        bf16x8 a = *(const bf16x8*)(fin + idx*CIN + ck*32 + q*8);
        Af[t] = val[t] ? a : z;
      }
      #pragma unroll
      for (int n = 0; n < NT; ++n)
        Bf[n] = *(const bf16x8*)(w2 + ((size_t)((tap*CK+ck)*COP + n*16 + m))*32 + q*8);
      #pragma unroll
      for (int t = 0; t < MT; ++t)
        #pragma unroll
        for (int n = 0; n < NT; ++n)
          acc[t][n] = __builtin_amdgcn_mfma_f32_16x16x32_bf16(Af[t], Bf[n], acc[t][n], 0, 0, 0);
    }
  }

  #pragma unroll
  for (int n = 0; n < NT; ++n){
    int co = n*16 + m;
    bool cok = co < Cout;
    float bs = cok ? bias[co] : 0.f;
    #pragma unroll
    for (int t = 0; t < MT; ++t){
      #pragma unroll
      for (int r = 0; r < 4; ++r){
        int pp = vbase + t*16 + q*4 + r;
        if (pp < total && cok){
          float x = fmaxf(acc[t][n][r] + bs, 0.f);
          if (skipin) x += b2f(skipin[(size_t)pp*CIN + co]);
          outp[(size_t)pp*outStride + outOff + co] = f2b(x);
        }
      }
    }
  }
}

// ---- merged resize + pool (+ fcat pad-zero) ----
__global__ void k_respool(const ushort* __restrict__ t1, const ushort* __restrict__ t4,
                          ushort* __restrict__ fc){
  int tid = blockIdx.x*256 + threadIdx.x;
  if (tid < 864000){
    int c4 = tid % 20;
    int x  = (tid / 20) % 80;
    int y  = (tid / 1600) % 60;
    int v  = tid / 96000;
    int c = c4*4;
    int ky = y >> 1; int y0, y1; float wy0, wy1;
    if ((y & 1) == 0){ y0 = ky-1; y1 = ky; wy0 = 0.25f; wy1 = 0.75f; if (y0 < 0){ y0 = 0; wy0 = 0.f; wy1 = 1.f; } }
    else             { y0 = ky; y1 = ky+1; wy0 = 0.75f; wy1 = 0.25f; if (y1 > 29){ y1 = 29; wy1 = 0.f; wy0 = 1.f; } }
    int kx = x >> 1; int x0, x1; float wx0, wx1;
    if ((x & 1) == 0){ x0 = kx-1; x1 = kx; wx0 = 0.25f; wx1 = 0.75f; if (x0 < 0){ x0 = 0; wx0 = 0.f; wx1 = 1.f; } }
    else             { x0 = kx; x1 = kx+1; wx0 = 0.75f; wx1 = 0.25f; if (x1 > 39){ x1 = 39; wx1 = 0.f; wx0 = 1.f; } }
    float4 a00 = ld4b(t1 + ((size_t)(v*30 + y0)*40 + x0)*80 + c);
    float4 a01 = ld4b(t1 + ((size_t)(v*30 + y0)*40 + x1)*80 + c);
    float4 a10 = ld4b(t1 + ((size_t)(v*30 + y1)*40 + x0)*80 + c);
    float4 a11 = ld4b(t1 + ((size_t)(v*30 + y1)*40 + x1)*80 + c);
    float w00 = wy0*wx0, w01 = wy0*wx1, w10 = wy1*wx0, w11 = wy1*wx1;
    float4 r;
    r.x = w00*a00.x + w01*a01.x + w10*a10.x + w11*a11.x;
    r.y = w00*a00.y + w01*a01.y + w10*a10.y + w11*a11.y;
    r.z = w00*a00.z + w01*a01.z + w10*a10.z + w11*a11.z;
    r.w = w00*a00.w + w01*a01.w + w10*a10.w + w11*a11.w;
    st4b(fc + ((size_t)(v*60 + y)*80 + x)*160 + c, r);
    return;
  }
  int t = tid - 864000;
  if (t >= 432000) return;
  int c4 = t % 10;
  int x  = (t / 10) % 80;
  int y  = (t / 800) % 60;
  int v  = t / 48000;
  if (c4 < 6){
    int c = c4*4;
    const ushort* b0 = t4 + ((size_t)(v*120 + 2*y)*160 + 2*x)*24 + c;
    float4 a = ld4b(b0), b = ld4b(b0 + 24), cc = ld4b(b0 + 160*24), d = ld4b(b0 + 160*24 + 24);
    float4 r;
    r.x = 0.25f*(a.x + b.x + cc.x + d.x);
    r.y = 0.25f*(a.y + b.y + cc.y + d.y);
    r.z = 0.25f*(a.z + b.z + cc.z + d.z);
    r.w = 0.25f*(a.w + b.w + cc.w + d.w);
    st4b(fc + ((size_t)(v*60 + y)*80 + x)*160 + 120 + c, r);
  } else {
    float4 zz = {0.f,0.f,0.f,0.f};
    st4b(fc + ((size_t)(v*60 + y)*80 + x)*160 + 144 + (c4-6)*4, zz);
  }
}

// ---- grid scatter + coords passthrough + projection/sample-table + count ----
__global__ void k_scatter(const int* __restrict__ coords, const int* __restrict__ stage,
                          int* __restrict__ grid, int* __restrict__ scn,
                          float* __restrict__ coords_out,
                          const float* __restrict__ origin, const float* __restrict__ vsz,
                          const float* __restrict__ KR,
                          uint4* __restrict__ samp, float* __restrict__ cnt){
  int n = blockIdx.x*256 + threadIdx.x;
  if (n >= NVOX) return;
  int c0 = coords[n*4], c1 = coords[n*4+1], c2 = coords[n*4+2], c3 = coords[n*4+3];
  coords_out[n*4+0] = (float)c0;
  coords_out[n*4+1] = (float)c1;
  coords_out[n*4+2] = (float)c2;
  coords_out[n*4+3] = (float)c3;
  int sh = 2 - stage[0];
  int s1 = c1 >> sh, s2 = c2 >> sh, s3 = c3 >> sh;
  scn[n*3+0] = s1; scn[n*3+1] = s2; scn[n*3+2] = s3;
  grid[(s1*GS + s2)*GS + s3] = n;

  float vs = vsz[0];
  float wx = (float)c1*vs + origin[0];
  float wy = (float)c2*vs + origin[1];
  float wz = (float)c3*vs + origin[2];
  float den = 0.f;
  #pragma unroll 1
  for (int v = 0; v < VN; ++v){
    const float* P = KR + v*12;
    float ix = P[0]*wx + P[1]*wy + P[2]*wz + P[3];
    float iy = P[4]*wx + P[5]*wy + P[6]*wz + P[7];
    float iz = P[8]*wx + P[9]*wy + P[10]*wz + P[11];
    float rz = 1.f/iz;
    float gx = 2.f*(ix*rz)/159.f - 1.f;
    float gy = 2.f*(iy*rz)/119.f - 1.f;
    bool ok = (fabsf(gx) <= 1.f) && (fabsf(gy) <= 1.f) && (iz > 0.f);
    float px = ok ? (gx + 1.f)*0.5f*79.f : 0.f;
    float py = ok ? (gy + 1.f)*0.5f*59.f : 0.f;
    float x0f = floorf(px), y0f = floorf(py);
    float fx = px - x0f, fy = py - y0f;
    int idx = (int)y0f*80 + (int)x0f;
    float mf = ok ? 1.f : 0.f;
    float w00 = (1.f-fx)*(1.f-fy)*mf, w01 = fx*(1.f-fy)*mf;
    float w10 = (1.f-fx)*fy*mf,       w11 = fx*fy*mf;
    uint4 s;
    s.x = (unsigned)idx;
    s.y = (unsigned)f2b(w00) | ((unsigned)f2b(w01) << 16);
    s.z = (unsigned)f2b(w10) | ((unsigned)f2b(w11) << 16);
    s.w = 0;
    samp[(size_t)v*NVOX + n] = s;
    den += mf;
  }
  cnt[n] = den;
}

// ---- merged: nbr-table build (blocks 0..511) + sampling (blocks 512..4607) ----
__global__ __launch_bounds__(256) void k_nbr_sample(
    const int* __restrict__ scn, const int* __restrict__ grid,
    int* __restrict__ nbr, unsigned* __restrict__ gmask16,
    const ushort* __restrict__ fuse, const uint4* __restrict__ samp,
    const float* __restrict__ cnt, const float* __restrict__ bn0g,
    const float* __restrict__ bn0b, ushort* __restrict__ F0){
  if (blockIdx.x < 512){
    int n = blockIdx.x*256 + threadIdx.x;
    int lane = threadIdx.x & 63;
    int sx = scn[n*3+0], sy = scn[n*3+1], sz = scn[n*3+2];
    unsigned msk = 0;
    #pragma unroll 1
    for (int k = 0; k < 27; ++k){
      int dx = k/9 - 1, dy = (k/3)%3 - 1, dz = k%3 - 1;
      int nx = sx+dx, ny = sy+dy, nz = sz+dz;
      int idx = -1;
      if (((unsigned)nx < 96u) && ((unsigned)ny < 96u) && ((unsigned)nz < 96u))
        idx = grid[(nx*GS + ny)*GS + nz];
      nbr[k*NVOX + n] = idx;
      unsigned long long b = __ballot(idx >= 0);
      unsigned sub = (unsigned)((b >> ((lane >> 4)*16)) & 0xFFFFull);
      if (sub) msk |= (1u << k);
    }
    if ((lane & 15) == 0) gmask16[n >> 4] = msk;
    return;
  }
  int tid = (blockIdx.x - 512)*256 + threadIdx.x;
  int vox = tid >> 3;
  int c4 = tid & 7;
  int c = c4*4;
  float s0=0.f,s1=0.f,s2=0.f,s3=0.f;
  float q0=0.f,q1=0.f,q2=0.f,q3=0.f;
  #pragma unroll 1
  for (int v = 0; v < VN; ++v){
    uint4 sv = samp[(size_t)v*NVOX + vox];
    float w00 = blo(sv.y), w01 = bhi(sv.y);
    float w10 = blo(sv.z), w11 = bhi(sv.z);
    const ushort* bp = fuse + (size_t)v*153600 + (size_t)sv.x*32 + c;
    float4 a00 = ld4b(bp);
    float4 a01 = ld4b(bp + 32);
    float4 a10 = ld4b(bp + 2560);
    float4 a11 = ld4b(bp + 2592);
    float g0 = w00*a00.x + w01*a01.x + w10*a10.x + w11*a11.x;
    float g1 = w00*a00.y + w01*a01.y + w10*a10.y + w11*a11.y;
    float g2 = w00*a00.z + w01*a01.z + w10*a10.z + w11*a11.z;
    float g3 = w00*a00.w + w01*a01.w + w10*a10.w + w11*a11.w;
    s0 += g0; q0 += g0*g0;
    s1 += g1; q1 += g1*g1;
    s2 += g2; q2 += g2*g2;
    s3 += g3; q3 += g3*g3;
  }
  float iden = 1.f/cnt[vox];
  float m0 = s0*iden, m1 = s1*iden, m2 = s2*iden, m3 = s3*iden;
  float4 g = ld4(bn0g + c);
  float4 b = ld4(bn0b + c);
  float4 r;
  r.x = g.x*fmaxf(q0*iden - m0*m0, 0.f)*INVS + b.x;
  r.y = g.y*fmaxf(q1*iden - m1*m1, 0.f)*INVS + b.y;
  r.z = g.z*fmaxf(q2*iden - m2*m2, 0.f)*INVS + b.z;
  r.w = g.w*fmaxf(q3*iden - m3*m3, 0.f)*INVS + b.w;
  st4b(F0 + (size_t)vox*32 + c, r);
}

// ---- subm sparse conv 32->32 via MFMA bf16, 16 voxels/wave, k-slice skip ----
template<int MODE>
__global__ __launch_bounds__(256, 8) void k_subm_mfma(
    const ushort* __restrict__ fin, const ushort* __restrict__ w2,
    const int* __restrict__ nbr, const unsigned* __restrict__ gmask16,
    const float* __restrict__ lng, const float* __restrict__ lnb,
    ushort* __restrict__ fout){
  int lane = threadIdx.x & 63;
  int wave = threadIdx.x >> 6;
  int vb = blockIdx.x*64 + wave*16;
  int m = lane & 15;
  int q = lane >> 4;

  f32x4v acc0 = 0.f, acc1 = 0.f;
  bf16x8 zc = (short)0;
  unsigned rem = gmask16[vb >> 4];
  int id = -1;
  int k = -1;
  if (rem){
    k = __ffs(rem) - 1; rem &= rem - 1;
    id = nbr[(size_t)k*NVOX + vb + m];
  }
  while (k >= 0){
    bf16x8 A;
    {
      bf16x8 a = *(const bf16x8*)(fin + (size_t)(id < 0 ? 0 : id)*32 + q*8);
      A = (id < 0) ? zc : a;
    }
    bf16x8 b0 = *(const bf16x8*)(w2 + (size_t)(k*32 + m)*32 + q*8);
    bf16x8 b1 = *(const bf16x8*)(w2 + (size_t)(k*32 + 16 + m)*32 + q*8);
    int k2 = -1, id2 = -1;
    if (rem){
      k2 = __ffs(rem) - 1; rem &= rem - 1;
      id2 = nbr[(size_t)k2*NVOX + vb + m];
    }
    acc0 = __builtin_amdgcn_mfma_f32_16x16x32_bf16(A, b0, acc0, 0, 0, 0);
    acc1 = __builtin_amdgcn_mfma_f32_16x16x32_bf16(A, b1, acc1, 0, 0, 0);
    id = id2; k = k2;
  }

  int ch0 = m, ch1 = 16 + m;
  float g0 = 0.f, g1 = 0.f, bb0 = 0.f, bb1 = 0.f;
  if (MODE == 1){ g0 = lng[ch0]; g1 = lng[ch1]; bb0 = lnb[ch0]; bb1 = lnb[ch1]; }
  #pragma unroll
  for (int r = 0; r < 4; ++r){
    int vox = vb + q*4 + r;
    float x0 = fmaxf(acc0[r], 0.f);
    float x1 = fmaxf(acc1[r], 0.f);
    if (MODE == 1){
      x0 += b2f(fin[(size_t)vox*32 + ch0]);
      x1 += b2f(fin[(size_t)vox*32 + ch1]);
      float s = x0 + x1;
      s += __shfl_xor(s, 1, 16);
      s += __shfl_xor(s, 2, 16);
      s += __shfl_xor(s, 4, 16);
      s += __shfl_xor(s, 8, 16);
      float mean = s * (1.f/32.f);
      float d0 = x0 - mean, d1 = x1 - mean;
      float v2 = d0*d0 + d1*d1;
      v2 += __shfl_xor(v2, 1, 16);
      v2 += __shfl_xor(v2, 2, 16);
      v2 += __shfl_xor(v2, 4, 16);
      v2 += __shfl_xor(v2, 8, 16);
      float rs = 1.f / sqrtf(v2*(1.f/32.f) + 1e-5f);
      x0 = d0*rs*g0 + bb0;
      x1 = d1*rs*g1 + bb1;
    }
    fout[(size_t)vox*32 + ch0] = f2b(x0);
    fout[(size_t)vox*32 + ch1] = f2b(x1);
  }
}

// ---- final subm 32->1 + bn, k-slice skip by per-16 mask ----
__global__ __launch_bounds__(256) void k_s4(
    const ushort* __restrict__ fin, const float* __restrict__ w4,
    const int* __restrict__ nbr, const unsigned* __restrict__ gmask16,
    const float* __restrict__ bn4g, const float* __restrict__ bn4b,
    float* __restrict__ occ){
  int n = blockIdx.x*256 + threadIdx.x;
  if (n >= NVOX) return;
  unsigned gm = gmask16[n >> 4];
  float acc = 0.f;
  #pragma unroll 1
  for (int k = 0; k < 27; ++k){
    if (!((gm >> k) & 1u)) continue;
    int idx = nbr[(size_t)k*NVOX + n];
    if (idx >= 0){
      const uint4* r4 = (const uint4*)(fin + (size_t)idx*32);
      const float* wk = w4 + k*32;
      #pragma unroll
      for (int u = 0; u < 4; ++u){
        uint4 d = r4[u];
        const float* w8 = wk + u*8;
        acc += blo(d.x)*w8[0] + bhi(d.x)*w8[1];
        acc += blo(d.y)*w8[2] + bhi(d.y)*w8[3];
        acc += blo(d.z)*w8[4] + bhi(d.z)*w8[5];
        acc += blo(d.w)*w8[6] + bhi(d.w)*w8[7];
      }
    }
  }
  occ[n] = bn4g[0]*acc*INVS + bn4b[0];
}

extern "C" void kernel_launch(void* const* d_in, const int* in_sizes, int n_in,
                              void* d_out, int out_size, void* d_ws, size_t ws_size,
                              hipStream_t stream){
  const float* feats1 = (const float*)d_in[0];
  const float* feats2 = (const float*)d_in[1];
  const float* feats4 = (const float*)d_in[2];
  const int*   coords = (const int*)d_in[3];
  const float* origin = (const float*)d_in[4];
  const float* vsz    = (const float*)d_in[5];
  const float* KR     = (const float*)d_in[6];
  const float* w_f1 = (const float*)d_in[7];  const float* b_f1 = (const float*)d_in[8];
  const float* w_f2 = (const float*)d_in[9];  const float* b_f2 = (const float*)d_in[10];
  const float* w_f4 = (const float*)d_in[11]; const float* b_f4 = (const float*)d_in[12];
  const float* w_dn = (const float*)d_in[13]; const float* b_dn = (const float*)d_in[14];
  const float* w_p[4] = {(const float*)d_in[15], (const float*)d_in[17],
                         (const float*)d_in[19], (const float*)d_in[21]};
  const float* b_p[4] = {(const float*)d_in[16], (const float*)d_in[18],
                         (const float*)d_in[20], (const float*)d_in[22]};
  const float* bn0g = (const float*)d_in[23]; const float* bn0b = (const float*)d_in[24];
  const float* w_elan = (const float*)d_in[25];
  const float* w_s1 = (const float*)d_in[26]; const float* ln1g = (const float*)d_in[27]; const float* ln1b = (const float*)d_in[28];
  const float* w_s2 = (const float*)d_in[29]; const float* ln2g = (const float*)d_in[30]; const float* ln2b = (const float*)d_in[31];
  const float* w_s3 = (const float*)d_in[32]; const float* ln3g = (const float*)d_in[33]; const float* ln3b = (const float*)d_in[34];
  const float* w_s4 = (const float*)d_in[35]; const float* bn4g = (const float*)d_in[36]; const float* bn4b = (const float*)d_in[37];
  const int* stage  = (const int*)d_in[38];
  float* out = (float*)d_out;
  char* base = (char*)d_ws;

  size_t off = 0;
  auto alloc = [&](size_t bytes)->char*{ char* p = base + off; off += (bytes + 255) & ~(size_t)255; return p; };
  ushort* nhwc1 = (ushort*)alloc((size_t)9*30*40*96*2);
  ushort* nhwc2 = (ushort*)alloc((size_t)9*60*80*64*2);
  ushort* nhwc4 = (ushort*)alloc((size_t)9*120*160*32*2);
  ushort* t1    = (ushort*)alloc((size_t)9*30*40*80*2);
  ushort* t4    = (ushort*)alloc((size_t)9*120*160*24*2);
  ushort* fcat  = (ushort*)alloc((size_t)9*60*80*160*2);
  ushort* A     = (ushort*)alloc((size_t)9*60*80*32*2);
  ushort* B     = (ushort*)alloc((size_t)9*60*80*32*2);
  ushort* Fb0   = (ushort*)alloc((size_t)NVOX*32*2);
  ushort* Fb1   = (ushort*)alloc((size_t)NVOX*32*2);
  int*    nbr   = (int*)alloc((size_t)27*NVOX*4);
  int*    grid  = (int*)alloc((size_t)GS*GS*GS*4);
  int*    scn   = (int*)alloc((size_t)NVOX*3*4);
  unsigned* gmask16 = (unsigned*)alloc((size_t)(NVOX/16)*4);
  ushort* wf1   = (ushort*)alloc(9*3*80*32*2);
  ushort* wf2   = (ushort*)alloc(9*2*48*32*2);
  ushort* wf4   = (ushort*)alloc(9*1*32*32*2);
  ushort* wdn   = (ushort*)alloc(1*5*32*32*2);
  ushort* wp0   = (ushort*)alloc(9*1*32*32*2);
  ushort* wp1   = (ushort*)alloc(9*1*32*32*2);
  ushort* wp2   = (ushort*)alloc(9*1*32*32*2);
  ushort* wp3   = (ushort*)alloc(9*1*32*32*2);
  ushort* w2e   = (ushort*)alloc(27*1024*2);
  ushort* w2s1  = (ushort*)alloc(27*1024*2);
  ushort* w2s2  = (ushort*)alloc(27*1024*2);
  ushort* w2s3  = (ushort*)alloc(27*1024*2);
  // samp table (9*NVOX uint4 = 18.9 MB) aliases nhwc2..t4 (dead before k_scatter)
  uint4* samp = (uint4*)nhwc2;

  auto nb = [](int total){ return (total + 255)/256; };

  // mega prep: weight preps + grid clear + NHWC transposes (8012 blocks)
  k_prep<<<8012,256,0,stream>>>(
      w_f1, w_f2, w_f4, w_dn, w_p[0], w_p[1], w_p[2], w_p[3],
      w_elan, w_s1, w_s2, w_s3,
      wf1, wf2, wf4, wdn, wp0, wp1, wp2, wp3, w2e, w2s1, w2s2, w2s3, grid,
      feats1, feats2, feats4, nhwc1, nhwc2, nhwc4);

  // head convs
  k_conv_mfma<3,5,9,1><<<169,256,0,stream>>>(nhwc1, wf1, b_f1, t1, 30, 40, 10800, 80, 80, 0, nullptr);
  k_conv_mfma<2,3,9,1><<<675,256,0,stream>>>(nhwc2, wf2, b_f2, fcat, 60, 80, 43200, 40, 160, 80, nullptr);
  k_conv_mfma<1,2,9,4><<<675,256,0,stream>>>(nhwc4, wf4, b_f4, t4, 120, 160, 172800, 24, 24, 0, nullptr);

  // resize + pool + pad-zero
  k_respool<<<nb(864000 + 432000),256,0,stream>>>(t1, t4, fcat);

  // down conv (1x1) + 4 residual blocks (64 px/block -> 675 blocks each)
  k_conv_mfma<5,2,1,1><<<675,256,0,stream>>>(fcat, wdn, b_dn, A, 60, 80, 43200, 32, 32, 0, nullptr);
  k_conv_mfma<1,2,9,1><<<675,256,0,stream>>>(A, wp0, b_p[0], B, 60, 80, 43200, 32, 32, 0, A);
  k_conv_mfma<1,2,9,1><<<675,256,0,stream>>>(B, wp1, b_p[1], A, 60, 80, 43200, 32, 32, 0, B);
  k_conv_mfma<1,2,9,1><<<675,256,0,stream>>>(A, wp2, b_p[2], B, 60, 80, 43200, 32, 32, 0, A);
  k_conv_mfma<1,2,9,1><<<675,256,0,stream>>>(B, wp3, b_p[3], A, 60, 80, 43200, 32, 32, 0, B);

  // scatter (+ sample table + count)
  k_scatter<<<nb(NVOX),256,0,stream>>>(coords, stage, grid, scn, out + NVOX,
                                       origin, vsz, KR, samp, out + 5*NVOX);

  // nbr-table + sampling in one launch
  k_nbr_sample<<<512 + NVOX/32,256,0,stream>>>(scn, grid, nbr, gmask16,
                                               A, samp, out + 5*NVOX, bn0g, bn0b, Fb0);

  // sparse conv stack (MFMA, 16 voxels/wave)
  k_subm_mfma<0><<<NVOX/64,256,0,stream>>>(Fb0, w2e,  nbr, gmask16, nullptr, nullptr, Fb1);
  k_subm_mfma<1><<<NVOX/64,256,0,stream>>>(Fb1, w2s1, nbr, gmask16, ln1g, ln1b, Fb0);
  k_subm_mfma<1><<<NVOX/64,256,0,stream>>>(Fb0, w2s2, nbr, gmask16, ln2g, ln2b, Fb1);
  k_subm_mfma<1><<<NVOX/64,256,0,stream>>>(Fb1, w2s3, nbr, gmask16, ln3g, ln3b, Fb0);
  k_s4<<<nb(NVOX),256,0,stream>>>(Fb0, w_s4, nbr, gmask16, bn4g, bn4b, out);
}

// Round 7
// 366.596 us; speedup vs baseline: 9.1824x; 1.0629x over previous
//
#include <hip/hip_runtime.h>
#include <math.h>

#define VN 9
#define NVOX 131072
#define GS 96
static constexpr float INVS = 0.9999950000374997f; // 1/sqrt(1+1e-5)

typedef short bf16x8 __attribute__((ext_vector_type(8)));
typedef float f32x4v __attribute__((ext_vector_type(4)));

__device__ inline float4 ld4(const float* p){ return *reinterpret_cast<const float4*>(p); }

__device__ inline ushort f2b(float f){
  unsigned u = __float_as_uint(f);
  unsigned r = (u + 0x7fffu + ((u >> 16) & 1u)) >> 16;
  return (ushort)r;
}
__device__ inline float b2f(ushort s){ return __uint_as_float(((unsigned)s) << 16); }
__device__ inline float blo(unsigned u){ return __uint_as_float(u << 16); }
__device__ inline float bhi(unsigned u){ return __uint_as_float(u & 0xffff0000u); }

__device__ inline float4 ld4b(const ushort* p){
  uint2 u = *reinterpret_cast<const uint2*>(p);
  float4 r; r.x = blo(u.x); r.y = bhi(u.x); r.z = blo(u.y); r.w = bhi(u.y); return r;
}
__device__ inline void st4b(ushort* p, float4 v){
  uint2 u;
  u.x = (unsigned)f2b(v.x) | ((unsigned)f2b(v.y) << 16);
  u.y = (unsigned)f2b(v.z) | ((unsigned)f2b(v.w) << 16);
  *reinterpret_cast<uint2*>(p) = u;
}

// ---- weight prep helpers ----
__device__ inline void wprep2_dev(const float* __restrict__ w, ushort* __restrict__ o,
                                  int Cout, int Cin, int K, int CK, int CoutPad, int tid){
  int ci32 = tid & 31;
  int co = (tid >> 5) % CoutPad;
  int ck = (tid / (32*CoutPad)) % CK;
  int tap = tid / (32*CoutPad*CK);
  int ci = ck*32 + ci32;
  float v = 0.f;
  if (co < Cout && ci < Cin) v = w[(size_t)(co*Cin + ci)*K*K + tap];
  o[tid] = f2b(v);
}
__device__ inline void wprep_dev(const float* __restrict__ w, ushort* __restrict__ o, int tid){
  int k = tid >> 10;
  int r = tid & 1023;
  int co = r >> 5;
  int ci = r & 31;
  o[tid] = f2b(w[k*1024 + ci*32 + co]);
}

// ---- NCHW fp32 -> NHWC bf16 via LDS tile ----
__device__ inline void nhwc_tile_dev(const float* __restrict__ in, ushort* __restrict__ out,
                                     int C, int Cpad, int HW, int tile, int tilesPerV,
                                     float* lds, int tx){
  int v  = tile / tilesPerV;
  int p0 = (tile - v*tilesPerV) * 64;
  const float* ip = in + (size_t)v*C*HW + p0;
  int iters = Cpad >> 2;
  for (int i = 0; i < iters; ++i){
    int idx = i*256 + tx;
    int c = idx >> 6;
    int p = idx & 63;
    float val = 0.f;
    if (c < C && (p0 + p) < HW) val = ip[(size_t)c*HW + p];
    lds[c*65 + p] = val;
  }
  __syncthreads();
  int groups = Cpad >> 2;
  int tot = 64*groups;
  for (int basei = 0; basei < tot; basei += 256){
    int idx = basei + tx;
    if (idx < tot){
      int g  = idx % groups;
      int px = idx / groups;
      if ((p0 + px) < HW){
        float4 r;
        r.x = lds[(g*4+0)*65 + px];
        r.y = lds[(g*4+1)*65 + px];
        r.z = lds[(g*4+2)*65 + px];
        r.w = lds[(g*4+3)*65 + px];
        st4b(out + (size_t)(v*HW + p0 + px)*Cpad + g*4, r);
      }
    }
  }
}

// ---- mega prep kernel: weight preps + grid clear + NHWC transposes ----
__global__ __launch_bounds__(256) void k_prep(
    const float* wf1s, const float* wf2s, const float* wf4s, const float* wdns,
    const float* wp0s, const float* wp1s, const float* wp2s, const float* wp3s,
    const float* wes, const float* ws1s, const float* ws2s, const float* ws3s,
    ushort* wf1, ushort* wf2, ushort* wf4, ushort* wdn,
    ushort* wp0, ushort* wp1, ushort* wp2, ushort* wp3,
    ushort* w2e, ushort* w2s1, ushort* w2s2, ushort* w2s3,
    int* grid,
    const float* f1, const float* f2, const float* f4,
    ushort* o1, ushort* o2, ushort* o4){
  __shared__ float lds[96*65];
  int bid = blockIdx.x;
  int tx = threadIdx.x;
  if (bid < 270){ int t = bid*256+tx; if (t < 69120) wprep2_dev(wf1s, wf1, 80, 80, 3, 3, 80, t); return; }
  bid -= 270;
  if (bid < 108){ int t = bid*256+tx; if (t < 27648) wprep2_dev(wf2s, wf2, 40, 40, 3, 2, 48, t); return; }
  bid -= 108;
  if (bid < 36){ int t = bid*256+tx; if (t < 9216) wprep2_dev(wf4s, wf4, 24, 24, 3, 1, 32, t); return; }
  bid -= 36;
  if (bid < 20){ int t = bid*256+tx; if (t < 5120) wprep2_dev(wdns, wdn, 32, 144, 1, 5, 32, t); return; }
  bid -= 20;
  if (bid < 36){ int t = bid*256+tx; if (t < 9216) wprep2_dev(wp0s, wp0, 32, 32, 3, 1, 32, t); return; }
  bid -= 36;
  if (bid < 36){ int t = bid*256+tx; if (t < 9216) wprep2_dev(wp1s, wp1, 32, 32, 3, 1, 32, t); return; }
  bid -= 36;
  if (bid < 36){ int t = bid*256+tx; if (t < 9216) wprep2_dev(wp2s, wp2, 32, 32, 3, 1, 32, t); return; }
  bid -= 36;
  if (bid < 36){ int t = bid*256+tx; if (t < 9216) wprep2_dev(wp3s, wp3, 32, 32, 3, 1, 32, t); return; }
  bid -= 36;
  if (bid < 108){ int t = bid*256+tx; if (t < 27648) wprep_dev(wes, w2e, t); return; }
  bid -= 108;
  if (bid < 108){ int t = bid*256+tx; if (t < 27648) wprep_dev(ws1s, w2s1, t); return; }
  bid -= 108;
  if (bid < 108){ int t = bid*256+tx; if (t < 27648) wprep_dev(ws2s, w2s2, t); return; }
  bid -= 108;
  if (bid < 108){ int t = bid*256+tx; if (t < 27648) wprep_dev(ws3s, w2s3, t); return; }
  bid -= 108;
  if (bid < 3456){ int t = bid*256+tx; if (t < GS*GS*GS) grid[t] = -1; return; }
  bid -= 3456;
  if (bid < 171){ nhwc_tile_dev(f1, o1, 80, 96, 1200, bid, 19, lds, tx); return; }
  bid -= 171;
  if (bid < 675){ nhwc_tile_dev(f2, o2, 40, 64, 4800, bid, 75, lds, tx); return; }
  bid -= 675;
  if (bid < 2700){ nhwc_tile_dev(f4, o4, 24, 32, 19200, bid, 300, lds, tx); }
}

// ---- implicit-GEMM conv via MFMA (device body) ----
template<int CK, int NT, int TAPS, int MT>
__device__ void conv_dev(
    const ushort* __restrict__ fin, const ushort* __restrict__ w2,
    const float* __restrict__ bias, ushort* __restrict__ outp,
    int H, int W, int total, int Cout, int outStride, int outOff,
    const ushort* __restrict__ skipin, int bid, int tid){
  constexpr int CIN = CK*32;
  constexpr int COP = NT*16;
  int lane = tid & 63;
  int wave = tid >> 6;
  int vbase = bid*(MT*64) + wave*(MT*16);
  int m = lane & 15, q = lane >> 4;
  int HW = H*W;
  int p[MT], py[MT], px[MT]; bool pin[MT];
  #pragma unroll
  for (int t = 0; t < MT; ++t){
    int pp = vbase + t*16 + m;
    pin[t] = pp < total;
    if (pp > total-1) pp = total-1;
    p[t] = pp;
    int v = pp / HW; int rem = pp - v*HW;
    int y = rem / W;
    py[t] = y; px[t] = rem - y*W;
  }
  f32x4v acc[MT][NT];
  #pragma unroll
  for (int t = 0; t < MT; ++t)
    #pragma unroll
    for (int n = 0; n < NT; ++n) acc[t][n] = 0.f;
  bf16x8 z = (short)0;

  #pragma unroll 1
  for (int tap = 0; tap < TAPS; ++tap){
    int dy = (TAPS == 9) ? tap/3 - 1 : 0;
    int dx = (TAPS == 9) ? tap%3 - 1 : 0;
    int off = dy*W + dx;
    bool val[MT];
    #pragma unroll
    for (int t = 0; t < MT; ++t)
      val[t] = pin[t] && ((unsigned)(py[t]+dy) < (unsigned)H)
                      && ((unsigned)(px[t]+dx) < (unsigned)W);
    #pragma unroll
    for (int ck = 0; ck < CK; ++ck){
      bf16x8 Af[MT], Bf[NT];
      #pragma unroll
      for (int t = 0; t < MT; ++t){
        size_t idx = val[t] ? (size_t)(p[t]+off) : 0;
        bf16x8 a = *(const bf16x8*)(fin + idx*CIN + ck*32 + q*8);
        Af[t] = val[t] ? a : z;
      }
      #pragma unroll
      for (int n = 0; n < NT; ++n)
        Bf[n] = *(const bf16x8*)(w2 + ((size_t)((tap*CK+ck)*COP + n*16 + m))*32 + q*8);
      #pragma unroll
      for (int t = 0; t < MT; ++t)
        #pragma unroll
        for (int n = 0; n < NT; ++n)
          acc[t][n] = __builtin_amdgcn_mfma_f32_16x16x32_bf16(Af[t], Bf[n], acc[t][n], 0, 0, 0);
    }
  }

  #pragma unroll
  for (int n = 0; n < NT; ++n){
    int co = n*16 + m;
    bool cok = co < Cout;
    float bs = cok ? bias[co] : 0.f;
    #pragma unroll
    for (int t = 0; t < MT; ++t){
      #pragma unroll
      for (int r = 0; r < 4; ++r){
        int pp = vbase + t*16 + q*4 + r;
        if (pp < total && cok){
          float x = fmaxf(acc[t][n][r] + bs, 0.f);
          if (skipin) x += b2f(skipin[(size_t)pp*CIN + co]);
          outp[(size_t)pp*outStride + outOff + co] = f2b(x);
        }
      }
    }
  }
}

template<int CK, int NT, int TAPS, int MT>
__global__ __launch_bounds__(256) void k_conv_mfma(
    const ushort* __restrict__ fin, const ushort* __restrict__ w2,
    const float* __restrict__ bias, ushort* __restrict__ outp,
    int H, int W, int total, int Cout, int outStride, int outOff,
    const ushort* __restrict__ skipin){
  conv_dev<CK,NT,TAPS,MT>(fin, w2, bias, outp, H, W, total, Cout, outStride, outOff,
                          skipin, blockIdx.x, threadIdx.x);
}

// ---- scatter device: grid scatter + coords + sample table + count ----
__device__ void scatter_dev(const int* __restrict__ coords, const int* __restrict__ stage,
                            int* __restrict__ grid, int* __restrict__ scn,
                            float* __restrict__ coords_out,
                            const float* __restrict__ origin, const float* __restrict__ vsz,
                            const float* __restrict__ KR,
                            uint4* __restrict__ samp, float* __restrict__ cnt, int n){
  int c0 = coords[n*4], c1 = coords[n*4+1], c2 = coords[n*4+2], c3 = coords[n*4+3];
  coords_out[n*4+0] = (float)c0;
  coords_out[n*4+1] = (float)c1;
  coords_out[n*4+2] = (float)c2;
  coords_out[n*4+3] = (float)c3;
  int sh = 2 - stage[0];
  int s1 = c1 >> sh, s2 = c2 >> sh, s3 = c3 >> sh;
  scn[n*3+0] = s1; scn[n*3+1] = s2; scn[n*3+2] = s3;
  grid[(s1*GS + s2)*GS + s3] = n;

  float vs = vsz[0];
  float wx = (float)c1*vs + origin[0];
  float wy = (float)c2*vs + origin[1];
  float wz = (float)c3*vs + origin[2];
  float den = 0.f;
  #pragma unroll 1
  for (int v = 0; v < VN; ++v){
    const float* P = KR + v*12;
    float ix = P[0]*wx + P[1]*wy + P[2]*wz + P[3];
    float iy = P[4]*wx + P[5]*wy + P[6]*wz + P[7];
    float iz = P[8]*wx + P[9]*wy + P[10]*wz + P[11];
    float rz = 1.f/iz;
    float gx = 2.f*(ix*rz)/159.f - 1.f;
    float gy = 2.f*(iy*rz)/119.f - 1.f;
    bool ok = (fabsf(gx) <= 1.f) && (fabsf(gy) <= 1.f) && (iz > 0.f);
    float px = ok ? (gx + 1.f)*0.5f*79.f : 0.f;
    float py = ok ? (gy + 1.f)*0.5f*59.f : 0.f;
    float x0f = floorf(px), y0f = floorf(py);
    float fx = px - x0f, fy = py - y0f;
    int idx = (int)y0f*80 + (int)x0f;
    float mf = ok ? 1.f : 0.f;
    float w00 = (1.f-fx)*(1.f-fy)*mf, w01 = fx*(1.f-fy)*mf;
    float w10 = (1.f-fx)*fy*mf,       w11 = fx*fy*mf;
    uint4 s;
    s.x = (unsigned)idx;
    s.y = (unsigned)f2b(w00) | ((unsigned)f2b(w01) << 16);
    s.z = (unsigned)f2b(w10) | ((unsigned)f2b(w11) << 16);
    s.w = 0;
    samp[(size_t)v*NVOX + n] = s;
    den += mf;
  }
  cnt[n] = den;
}

// ---- merged: 3 head convs + scatter (169 + 675 + 675 + 512 = 2031 blocks) ----
__global__ __launch_bounds__(256) void k_heads(
    const ushort* nhwc1, const ushort* wf1, const float* b_f1, ushort* t1,
    const ushort* nhwc2, const ushort* wf2, const float* b_f2, ushort* fcat,
    const ushort* nhwc4, const ushort* wf4, const float* b_f4, ushort* t4,
    const int* coords, const int* stage, int* grid, int* scn, float* coords_out,
    const float* origin, const float* vsz, const float* KR, uint4* samp, float* cnt){
  int bid = blockIdx.x;
  int tid = threadIdx.x;
  if (bid < 169){ conv_dev<3,5,9,1>(nhwc1, wf1, b_f1, t1, 30, 40, 10800, 80, 80, 0, nullptr, bid, tid); return; }
  bid -= 169;
  if (bid < 675){ conv_dev<2,3,9,1>(nhwc2, wf2, b_f2, fcat, 60, 80, 43200, 40, 160, 80, nullptr, bid, tid); return; }
  bid -= 675;
  if (bid < 675){ conv_dev<1,2,9,4>(nhwc4, wf4, b_f4, t4, 120, 160, 172800, 24, 24, 0, nullptr, bid, tid); return; }
  bid -= 675;
  { int n = bid*256 + tid;
    scatter_dev(coords, stage, grid, scn, coords_out, origin, vsz, KR, samp, cnt, n); }
}

// ---- merged: resize+pool+padzero (5063 blocks) + slice-split nbr build (2048) ----
__global__ __launch_bounds__(256) void k_respool_nbr(
    const ushort* __restrict__ t1, const ushort* __restrict__ t4, ushort* __restrict__ fc,
    const int* __restrict__ scn, const int* __restrict__ grid,
    int* __restrict__ nbr, unsigned* __restrict__ gmask16){
  __shared__ unsigned m16[4];
  int bid = blockIdx.x;
  int tidx = threadIdx.x;
  if (bid < 5063){
    int tid = bid*256 + tidx;
    if (tid < 864000){
      int c4 = tid % 20;
      int x  = (tid / 20) % 80;
      int y  = (tid / 1600) % 60;
      int v  = tid / 96000;
      int c = c4*4;
      int ky = y >> 1; int y0, y1; float wy0, wy1;
      if ((y & 1) == 0){ y0 = ky-1; y1 = ky; wy0 = 0.25f; wy1 = 0.75f; if (y0 < 0){ y0 = 0; wy0 = 0.f; wy1 = 1.f; } }
      else             { y0 = ky; y1 = ky+1; wy0 = 0.75f; wy1 = 0.25f; if (y1 > 29){ y1 = 29; wy1 = 0.f; wy0 = 1.f; } }
      int kx = x >> 1; int x0, x1; float wx0, wx1;
      if ((x & 1) == 0){ x0 = kx-1; x1 = kx; wx0 = 0.25f; wx1 = 0.75f; if (x0 < 0){ x0 = 0; wx0 = 0.f; wx1 = 1.f; } }
      else             { x0 = kx; x1 = kx+1; wx0 = 0.75f; wx1 = 0.25f; if (x1 > 39){ x1 = 39; wx1 = 0.f; wx0 = 1.f; } }
      float4 a00 = ld4b(t1 + ((size_t)(v*30 + y0)*40 + x0)*80 + c);
      float4 a01 = ld4b(t1 + ((size_t)(v*30 + y0)*40 + x1)*80 + c);
      float4 a10 = ld4b(t1 + ((size_t)(v*30 + y1)*40 + x0)*80 + c);
      float4 a11 = ld4b(t1 + ((size_t)(v*30 + y1)*40 + x1)*80 + c);
      float w00 = wy0*wx0, w01 = wy0*wx1, w10 = wy1*wx0, w11 = wy1*wx1;
      float4 r;
      r.x = w00*a00.x + w01*a01.x + w10*a10.x + w11*a11.x;
      r.y = w00*a00.y + w01*a01.y + w10*a10.y + w11*a11.y;
      r.z = w00*a00.z + w01*a01.z + w10*a10.z + w11*a11.z;
      r.w = w00*a00.w + w01*a01.w + w10*a10.w + w11*a11.w;
      st4b(fc + ((size_t)(v*60 + y)*80 + x)*160 + c, r);
      return;
    }
    int t = tid - 864000;
    if (t >= 432000) return;
    int c4 = t % 10;
    int x  = (t / 10) % 80;
    int y  = (t / 800) % 60;
    int v  = t / 48000;
    if (c4 < 6){
      int c = c4*4;
      const ushort* b0 = t4 + ((size_t)(v*120 + 2*y)*160 + 2*x)*24 + c;
      float4 a = ld4b(b0), b = ld4b(b0 + 24), cc = ld4b(b0 + 160*24), d = ld4b(b0 + 160*24 + 24);
      float4 r;
      r.x = 0.25f*(a.x + b.x + cc.x + d.x);
      r.y = 0.25f*(a.y + b.y + cc.y + d.y);
      r.z = 0.25f*(a.z + b.z + cc.z + d.z);
      r.w = 0.25f*(a.w + b.w + cc.w + d.w);
      st4b(fc + ((size_t)(v*60 + y)*80 + x)*160 + 120 + c, r);
    } else {
      float4 zz = {0.f,0.f,0.f,0.f};
      st4b(fc + ((size_t)(v*60 + y)*80 + x)*160 + 144 + (c4-6)*4, zz);
    }
    return;
  }
  // ---- nbr build: block handles 64 voxels; wave w handles ~7 slices ----
  bid -= 5063;
  if (tidx < 4) m16[tidx] = 0;
  __syncthreads();
  int vb = bid*64;
  int lane = tidx & 63;
  int wv = tidx >> 6;
  int n = vb + lane;
  int sx = scn[n*3+0], sy = scn[n*3+1], sz = scn[n*3+2];
  int k0 = wv*7;
  int k1 = min(27, k0 + 7);
  unsigned msk = 0;
  #pragma unroll 1
  for (int k = k0; k < k1; ++k){
    int dx = k/9 - 1, dy = (k/3)%3 - 1, dz = k%3 - 1;
    int nx = sx+dx, ny = sy+dy, nz = sz+dz;
    int idx = -1;
    if (((unsigned)nx < 96u) && ((unsigned)ny < 96u) && ((unsigned)nz < 96u))
      idx = grid[(nx*GS + ny)*GS + nz];
    nbr[(size_t)k*NVOX + n] = idx;
    unsigned long long b = __ballot(idx >= 0);
    unsigned sub = (unsigned)((b >> ((lane >> 4)*16)) & 0xFFFFull);
    if (sub) msk |= (1u << k);
  }
  if ((lane & 15) == 0 && msk) atomicOr(&m16[lane >> 4], msk);
  __syncthreads();
  if (tidx < 4) gmask16[(vb >> 4) + tidx] = m16[tidx];
}

// ---- sampling from table + masked mean/var + bn0 (samp prefetch) ----
__global__ __launch_bounds__(256) void k_sample(
    const ushort* __restrict__ fuse, const uint4* __restrict__ samp,
    const float* __restrict__ cnt, const float* __restrict__ bn0g,
    const float* __restrict__ bn0b, ushort* __restrict__ F0){
  int tid = blockIdx.x*256 + threadIdx.x;
  int vox = tid >> 3;
  int c4 = tid & 7;
  int c = c4*4;
  float s0=0.f,s1=0.f,s2=0.f,s3=0.f;
  float q0=0.f,q1=0.f,q2=0.f,q3=0.f;
  uint4 sv = samp[vox];
  #pragma unroll 1
  for (int v = 0; v < VN; ++v){
    uint4 svn = sv;
    if (v+1 < VN) svn = samp[(size_t)(v+1)*NVOX + vox];
    float w00 = blo(sv.y), w01 = bhi(sv.y);
    float w10 = blo(sv.z), w11 = bhi(sv.z);
    const ushort* bp = fuse + (size_t)v*153600 + (size_t)sv.x*32 + c;
    float4 a00 = ld4b(bp);
    float4 a01 = ld4b(bp + 32);
    float4 a10 = ld4b(bp + 2560);
    float4 a11 = ld4b(bp + 2592);
    float g0 = w00*a00.x + w01*a01.x + w10*a10.x + w11*a11.x;
    float g1 = w00*a00.y + w01*a01.y + w10*a10.y + w11*a11.y;
    float g2 = w00*a00.z + w01*a01.z + w10*a10.z + w11*a11.z;
    float g3 = w00*a00.w + w01*a01.w + w10*a10.w + w11*a11.w;
    s0 += g0; q0 += g0*g0;
    s1 += g1; q1 += g1*g1;
    s2 += g2; q2 += g2*g2;
    s3 += g3; q3 += g3*g3;
    sv = svn;
  }
  float iden = 1.f/cnt[vox];
  float m0 = s0*iden, m1 = s1*iden, m2 = s2*iden, m3 = s3*iden;
  float4 g = ld4(bn0g + c);
  float4 b = ld4(bn0b + c);
  float4 r;
  r.x = g.x*fmaxf(q0*iden - m0*m0, 0.f)*INVS + b.x;
  r.y = g.y*fmaxf(q1*iden - m1*m1, 0.f)*INVS + b.y;
  r.z = g.z*fmaxf(q2*iden - m2*m2, 0.f)*INVS + b.z;
  r.w = g.w*fmaxf(q3*iden - m3*m3, 0.f)*INVS + b.w;
  st4b(F0 + (size_t)vox*32 + c, r);
}

// ---- subm sparse conv 32->32 via MFMA bf16, 16 vox/wave, 2-deep pipeline ----
template<int MODE>
__global__ __launch_bounds__(256, 8) void k_subm_mfma(
    const ushort* __restrict__ fin, const ushort* __restrict__ w2,
    const int* __restrict__ nbr, const unsigned* __restrict__ gmask16,
    const float* __restrict__ lng, const float* __restrict__ lnb,
    ushort* __restrict__ fout){
  int lane = threadIdx.x & 63;
  int wave = threadIdx.x >> 6;
  int vb = blockIdx.x*64 + wave*16;
  int m = lane & 15;
  int q = lane >> 4;

  f32x4v acc0 = 0.f, acc1 = 0.f;
  bf16x8 zc = (short)0;
  unsigned rem = gmask16[vb >> 4];
  int k0 = -1, k1 = -1;
  int id0 = -1, id1 = -1;
  if (rem){ k0 = __ffs(rem) - 1; rem &= rem - 1; id0 = nbr[(size_t)k0*NVOX + vb + m]; }
  if (rem){ k1 = __ffs(rem) - 1; rem &= rem - 1; id1 = nbr[(size_t)k1*NVOX + vb + m]; }
  bf16x8 A0 = zc;
  if (k0 >= 0){
    bf16x8 a = *(const bf16x8*)(fin + (size_t)(id0 < 0 ? 0 : id0)*32 + q*8);
    A0 = (id0 < 0) ? zc : a;
  }
  while (k0 >= 0){
    // prefetch slice k1's A-frag and slice k2's ids before MFMAing slice k0
    bf16x8 A1 = zc;
    if (k1 >= 0){
      bf16x8 a = *(const bf16x8*)(fin + (size_t)(id1 < 0 ? 0 : id1)*32 + q*8);
      A1 = (id1 < 0) ? zc : a;
    }
    int k2 = -1, id2 = -1;
    if (rem){ k2 = __ffs(rem) - 1; rem &= rem - 1; id2 = nbr[(size_t)k2*NVOX + vb + m]; }
    bf16x8 b0 = *(const bf16x8*)(w2 + (size_t)(k0*32 + m)*32 + q*8);
    bf16x8 b1 = *(const bf16x8*)(w2 + (size_t)(k0*32 + 16 + m)*32 + q*8);
    acc0 = __builtin_amdgcn_mfma_f32_16x16x32_bf16(A0, b0, acc0, 0, 0, 0);
    acc1 = __builtin_amdgcn_mfma_f32_16x16x32_bf16(A0, b1, acc1, 0, 0, 0);
    A0 = A1; id1 = id2; k0 = k1; k1 = k2;
  }

  int ch0 = m, ch1 = 16 + m;
  float g0 = 0.f, g1 = 0.f, bb0 = 0.f, bb1 = 0.f;
  if (MODE == 1){ g0 = lng[ch0]; g1 = lng[ch1]; bb0 = lnb[ch0]; bb1 = lnb[ch1]; }
  #pragma unroll
  for (int r = 0; r < 4; ++r){
    int vox = vb + q*4 + r;
    float x0 = fmaxf(acc0[r], 0.f);
    float x1 = fmaxf(acc1[r], 0.f);
    if (MODE == 1){
      x0 += b2f(fin[(size_t)vox*32 + ch0]);
      x1 += b2f(fin[(size_t)vox*32 + ch1]);
      float s = x0 + x1;
      s += __shfl_xor(s, 1, 16);
      s += __shfl_xor(s, 2, 16);
      s += __shfl_xor(s, 4, 16);
      s += __shfl_xor(s, 8, 16);
      float mean = s * (1.f/32.f);
      float d0 = x0 - mean, d1 = x1 - mean;
      float v2 = d0*d0 + d1*d1;
      v2 += __shfl_xor(v2, 1, 16);
      v2 += __shfl_xor(v2, 2, 16);
      v2 += __shfl_xor(v2, 4, 16);
      v2 += __shfl_xor(v2, 8, 16);
      float rs = 1.f / sqrtf(v2*(1.f/32.f) + 1e-5f);
      x0 = d0*rs*g0 + bb0;
      x1 = d1*rs*g1 + bb1;
    }
    fout[(size_t)vox*32 + ch0] = f2b(x0);
    fout[(size_t)vox*32 + ch1] = f2b(x1);
  }
}

// ---- final subm 32->1 + bn, idx prefetch ----
__global__ __launch_bounds__(256) void k_s4(
    const ushort* __restrict__ fin, const float* __restrict__ w4,
    const int* __restrict__ nbr, const unsigned* __restrict__ gmask16,
    const float* __restrict__ bn4g, const float* __restrict__ bn4b,
    float* __restrict__ occ){
  int n = blockIdx.x*256 + threadIdx.x;
  if (n >= NVOX) return;
  unsigned rem = gmask16[n >> 4];
  float acc = 0.f;
  int k = -1, idx = -1;
  if (rem){ k = __ffs(rem) - 1; rem &= rem - 1; idx = nbr[(size_t)k*NVOX + n]; }
  while (k >= 0){
    int k2 = -1, idx2 = -1;
    if (rem){ k2 = __ffs(rem) - 1; rem &= rem - 1; idx2 = nbr[(size_t)k2*NVOX + n]; }
    if (idx >= 0){
      const uint4* r4 = (const uint4*)(fin + (size_t)idx*32);
      const float* wk = w4 + k*32;
      #pragma unroll
      for (int u = 0; u < 4; ++u){
        uint4 d = r4[u];
        const float* w8 = wk + u*8;
        acc += blo(d.x)*w8[0] + bhi(d.x)*w8[1];
        acc += blo(d.y)*w8[2] + bhi(d.y)*w8[3];
        acc += blo(d.z)*w8[4] + bhi(d.z)*w8[5];
        acc += blo(d.w)*w8[6] + bhi(d.w)*w8[7];
      }
    }
    k = k2; idx = idx2;
  }
  occ[n] = bn4g[0]*acc*INVS + bn4b[0];
}

extern "C" void kernel_launch(void* const* d_in, const int* in_sizes, int n_in,
                              void* d_out, int out_size, void* d_ws, size_t ws_size,
                              hipStream_t stream){
  const float* feats1 = (const float*)d_in[0];
  const float* feats2 = (const float*)d_in[1];
  const float* feats4 = (const float*)d_in[2];
  const int*   coords = (const int*)d_in[3];
  const float* origin = (const float*)d_in[4];
  const float* vsz    = (const float*)d_in[5];
  const float* KR     = (const float*)d_in[6];
  const float* w_f1 = (const float*)d_in[7];  const float* b_f1 = (const float*)d_in[8];
  const float* w_f2 = (const float*)d_in[9];  const float* b_f2 = (const float*)d_in[10];
  const float* w_f4 = (const float*)d_in[11]; const float* b_f4 = (const float*)d_in[12];
  const float* w_dn = (const float*)d_in[13]; const float* b_dn = (const float*)d_in[14];
  const float* w_p[4] = {(const float*)d_in[15], (const float*)d_in[17],
                         (const float*)d_in[19], (const float*)d_in[21]};
  const float* b_p[4] = {(const float*)d_in[16], (const float*)d_in[18],
                         (const float*)d_in[20], (const float*)d_in[22]};
  const float* bn0g = (const float*)d_in[23]; const float* bn0b = (const float*)d_in[24];
  const float* w_elan = (const float*)d_in[25];
  const float* w_s1 = (const float*)d_in[26]; const float* ln1g = (const float*)d_in[27]; const float* ln1b = (const float*)d_in[28];
  const float* w_s2 = (const float*)d_in[29]; const float* ln2g = (const float*)d_in[30]; const float* ln2b = (const float*)d_in[31];
  const float* w_s3 = (const float*)d_in[32]; const float* ln3g = (const float*)d_in[33]; const float* ln3b = (const float*)d_in[34];
  const float* w_s4 = (const float*)d_in[35]; const float* bn4g = (const float*)d_in[36]; const float* bn4b = (const float*)d_in[37];
  const int* stage  = (const int*)d_in[38];
  float* out = (float*)d_out;
  char* base = (char*)d_ws;

  size_t off = 0;
  auto alloc = [&](size_t bytes)->char*{ char* p = base + off; off += (bytes + 255) & ~(size_t)255; return p; };
  ushort* nhwc1 = (ushort*)alloc((size_t)9*30*40*96*2);
  ushort* nhwc2 = (ushort*)alloc((size_t)9*60*80*64*2);
  ushort* nhwc4 = (ushort*)alloc((size_t)9*120*160*32*2);
  ushort* t1    = (ushort*)alloc((size_t)9*30*40*80*2);
  ushort* t4    = (ushort*)alloc((size_t)9*120*160*24*2);
  ushort* fcat  = (ushort*)alloc((size_t)9*60*80*160*2);
  ushort* A     = (ushort*)alloc((size_t)9*60*80*32*2);
  ushort* B     = (ushort*)alloc((size_t)9*60*80*32*2);
  ushort* Fb0   = (ushort*)alloc((size_t)NVOX*32*2);
  ushort* Fb1   = (ushort*)alloc((size_t)NVOX*32*2);
  int*    nbr   = (int*)alloc((size_t)27*NVOX*4);
  int*    grid  = (int*)alloc((size_t)GS*GS*GS*4);
  int*    scn   = (int*)alloc((size_t)NVOX*3*4);
  unsigned* gmask16 = (unsigned*)alloc((size_t)(NVOX/16)*4);
  ushort* wf1   = (ushort*)alloc(9*3*80*32*2);
  ushort* wf2   = (ushort*)alloc(9*2*48*32*2);
  ushort* wf4   = (ushort*)alloc(9*1*32*32*2);
  ushort* wdn   = (ushort*)alloc(1*5*32*32*2);
  ushort* wp0   = (ushort*)alloc(9*1*32*32*2);
  ushort* wp1   = (ushort*)alloc(9*1*32*32*2);
  ushort* wp2   = (ushort*)alloc(9*1*32*32*2);
  ushort* wp3   = (ushort*)alloc(9*1*32*32*2);
  ushort* w2e   = (ushort*)alloc(27*1024*2);
  ushort* w2s1  = (ushort*)alloc(27*1024*2);
  ushort* w2s2  = (ushort*)alloc(27*1024*2);
  ushort* w2s3  = (ushort*)alloc(27*1024*2);
  // samp table (9*NVOX uint4 = 18.9 MB) aliases nhwc2..t4 head (dead before k_heads' scatter)
  uint4* samp = (uint4*)nhwc2;

  auto nb = [](int total){ return (total + 255)/256; };

  // 1. mega prep
  k_prep<<<8012,256,0,stream>>>(
      w_f1, w_f2, w_f4, w_dn, w_p[0], w_p[1], w_p[2], w_p[3],
      w_elan, w_s1, w_s2, w_s3,
      wf1, wf2, wf4, wdn, wp0, wp1, wp2, wp3, w2e, w2s1, w2s2, w2s3, grid,
      feats1, feats2, feats4, nhwc1, nhwc2, nhwc4);

  // 2. head convs + scatter (samp aliases nhwc2: conv f2 reads nhwc2 in the same
  //    launch, but scatter writes samp only at v*NVOX..; nhwc2 region spans the
  //    first 5.5 MB of samp's 18.9 MB; conv f2 blocks and scatter blocks overlap
  //    in time -> ensure no alias conflict: move samp to t4+fcat region instead.
  //    (t4 written in this launch too!) -> use Fb1 region? Fb1 is 8.4 MB < 18.9.
  //    Safe choice: nbr region (14.2 MB) still too small; keep samp on its own:
  //    it fits after gmask16 allocations below? Simplest: give samp dedicated room.
  k_heads<<<2031,256,0,stream>>>(
      nhwc1, wf1, b_f1, t1,
      nhwc2, wf2, b_f2, fcat,
      nhwc4, wf4, b_f4, t4,
      coords, stage, grid, scn, out + NVOX,
      origin, vsz, KR, (uint4*)(base + off), out + 5*NVOX);
  uint4* samp2 = (uint4*)(base + off);  // dedicated 18.9 MB tail region
  (void)samp;

  // 3. respool + nbr build
  k_respool_nbr<<<5063 + 2048,256,0,stream>>>(t1, t4, fcat, scn, grid, nbr, gmask16);

  // 4-8. down conv + residual chain
  k_conv_mfma<5,2,1,1><<<675,256,0,stream>>>(fcat, wdn, b_dn, A, 60, 80, 43200, 32, 32, 0, nullptr);
  k_conv_mfma<1,2,9,1><<<675,256,0,stream>>>(A, wp0, b_p[0], B, 60, 80, 43200, 32, 32, 0, A);
  k_conv_mfma<1,2,9,1><<<675,256,0,stream>>>(B, wp1, b_p[1], A, 60, 80, 43200, 32, 32, 0, B);
  k_conv_mfma<1,2,9,1><<<675,256,0,stream>>>(A, wp2, b_p[2], B, 60, 80, 43200, 32, 32, 0, A);
  k_conv_mfma<1,2,9,1><<<675,256,0,stream>>>(B, wp3, b_p[3], A, 60, 80, 43200, 32, 32, 0, B);

  // 9. sampling -> F0
  k_sample<<<NVOX/32,256,0,stream>>>(A, samp2, out + 5*NVOX, bn0g, bn0b, Fb0);

  // 10-13. sparse conv stack
  k_subm_mfma<0><<<NVOX/64,256,0,stream>>>(Fb0, w2e,  nbr, gmask16, nullptr, nullptr, Fb1);
  k_subm_mfma<1><<<NVOX/64,256,0,stream>>>(Fb1, w2s1, nbr, gmask16, ln1g, ln1b, Fb0);
  k_subm_mfma<1><<<NVOX/64,256,0,stream>>>(Fb0, w2s2, nbr, gmask16, ln2g, ln2b, Fb1);
  k_subm_mfma<1><<<NVOX/64,256,0,stream>>>(Fb1, w2s3, nbr, gmask16, ln3g, ln3b, Fb0);

  // 14. final head
  k_s4<<<nb(NVOX),256,0,stream>>>(Fb0, w_s4, nbr, gmask16, bn4g, bn4b, out);
}

// Round 8
// 353.452 us; speedup vs baseline: 9.5238x; 1.0372x over previous
//
#include <hip/hip_runtime.h>
#include <math.h>

#define VN 9
#define NVOX 131072
#define GS 96
static constexpr float INVS = 0.9999950000374997f; // 1/sqrt(1+1e-5)

typedef short bf16x8 __attribute__((ext_vector_type(8)));
typedef float f32x4v __attribute__((ext_vector_type(4)));

__device__ inline float4 ld4(const float* p){ return *reinterpret_cast<const float4*>(p); }

__device__ inline ushort f2b(float f){
  unsigned u = __float_as_uint(f);
  unsigned r = (u + 0x7fffu + ((u >> 16) & 1u)) >> 16;
  return (ushort)r;
}
__device__ inline float b2f(ushort s){ return __uint_as_float(((unsigned)s) << 16); }
__device__ inline float blo(unsigned u){ return __uint_as_float(u << 16); }
__device__ inline float bhi(unsigned u){ return __uint_as_float(u & 0xffff0000u); }

__device__ inline float4 ld4b(const ushort* p){
  uint2 u = *reinterpret_cast<const uint2*>(p);
  float4 r; r.x = blo(u.x); r.y = bhi(u.x); r.z = blo(u.y); r.w = bhi(u.y); return r;
}
__device__ inline void st4b(ushort* p, float4 v){
  uint2 u;
  u.x = (unsigned)f2b(v.x) | ((unsigned)f2b(v.y) << 16);
  u.y = (unsigned)f2b(v.z) | ((unsigned)f2b(v.w) << 16);
  *reinterpret_cast<uint2*>(p) = u;
}

// ---- weight prep helpers ----
__device__ inline void wprep2_dev(const float* __restrict__ w, ushort* __restrict__ o,
                                  int Cout, int Cin, int K, int CK, int CoutPad, int tid){
  int ci32 = tid & 31;
  int co = (tid >> 5) % CoutPad;
  int ck = (tid / (32*CoutPad)) % CK;
  int tap = tid / (32*CoutPad*CK);
  int ci = ck*32 + ci32;
  float v = 0.f;
  if (co < Cout && ci < Cin) v = w[(size_t)(co*Cin + ci)*K*K + tap];
  o[tid] = f2b(v);
}
__device__ inline void wprep_dev(const float* __restrict__ w, ushort* __restrict__ o, int tid){
  int k = tid >> 10;
  int r = tid & 1023;
  int co = r >> 5;
  int ci = r & 31;
  o[tid] = f2b(w[k*1024 + ci*32 + co]);
}

// ---- NCHW fp32 -> NHWC bf16 via LDS tile ----
__device__ inline void nhwc_tile_dev(const float* __restrict__ in, ushort* __restrict__ out,
                                     int C, int Cpad, int HW, int tile, int tilesPerV,
                                     float* lds, int tx){
  int v  = tile / tilesPerV;
  int p0 = (tile - v*tilesPerV) * 64;
  const float* ip = in + (size_t)v*C*HW + p0;
  int iters = Cpad >> 2;
  for (int i = 0; i < iters; ++i){
    int idx = i*256 + tx;
    int c = idx >> 6;
    int p = idx & 63;
    float val = 0.f;
    if (c < C && (p0 + p) < HW) val = ip[(size_t)c*HW + p];
    lds[c*65 + p] = val;
  }
  __syncthreads();
  int groups = Cpad >> 2;
  int tot = 64*groups;
  for (int basei = 0; basei < tot; basei += 256){
    int idx = basei + tx;
    if (idx < tot){
      int g  = idx % groups;
      int px = idx / groups;
      if ((p0 + px) < HW){
        float4 r;
        r.x = lds[(g*4+0)*65 + px];
        r.y = lds[(g*4+1)*65 + px];
        r.z = lds[(g*4+2)*65 + px];
        r.w = lds[(g*4+3)*65 + px];
        st4b(out + (size_t)(v*HW + p0 + px)*Cpad + g*4, r);
      }
    }
  }
}

// ---- mega prep kernel: weight preps + grid clear + NHWC transposes ----
__global__ __launch_bounds__(256) void k_prep(
    const float* wf1s, const float* wf2s, const float* wf4s, const float* wdns,
    const float* wp0s, const float* wp1s, const float* wp2s, const float* wp3s,
    const float* wes, const float* ws1s, const float* ws2s, const float* ws3s,
    ushort* wf1, ushort* wf2, ushort* wf4, ushort* wdn,
    ushort* wp0, ushort* wp1, ushort* wp2, ushort* wp3,
    ushort* w2e, ushort* w2s1, ushort* w2s2, ushort* w2s3,
    int* grid,
    const float* f1, const float* f2, const float* f4,
    ushort* o1, ushort* o2, ushort* o4){
  __shared__ float lds[96*65];
  int bid = blockIdx.x;
  int tx = threadIdx.x;
  if (bid < 270){ int t = bid*256+tx; if (t < 69120) wprep2_dev(wf1s, wf1, 80, 80, 3, 3, 80, t); return; }
  bid -= 270;
  if (bid < 108){ int t = bid*256+tx; if (t < 27648) wprep2_dev(wf2s, wf2, 40, 40, 3, 2, 48, t); return; }
  bid -= 108;
  if (bid < 36){ int t = bid*256+tx; if (t < 9216) wprep2_dev(wf4s, wf4, 24, 24, 3, 1, 32, t); return; }
  bid -= 36;
  if (bid < 20){ int t = bid*256+tx; if (t < 5120) wprep2_dev(wdns, wdn, 32, 144, 1, 5, 32, t); return; }
  bid -= 20;
  if (bid < 36){ int t = bid*256+tx; if (t < 9216) wprep2_dev(wp0s, wp0, 32, 32, 3, 1, 32, t); return; }
  bid -= 36;
  if (bid < 36){ int t = bid*256+tx; if (t < 9216) wprep2_dev(wp1s, wp1, 32, 32, 3, 1, 32, t); return; }
  bid -= 36;
  if (bid < 36){ int t = bid*256+tx; if (t < 9216) wprep2_dev(wp2s, wp2, 32, 32, 3, 1, 32, t); return; }
  bid -= 36;
  if (bid < 36){ int t = bid*256+tx; if (t < 9216) wprep2_dev(wp3s, wp3, 32, 32, 3, 1, 32, t); return; }
  bid -= 36;
  if (bid < 108){ int t = bid*256+tx; if (t < 27648) wprep_dev(wes, w2e, t); return; }
  bid -= 108;
  if (bid < 108){ int t = bid*256+tx; if (t < 27648) wprep_dev(ws1s, w2s1, t); return; }
  bid -= 108;
  if (bid < 108){ int t = bid*256+tx; if (t < 27648) wprep_dev(ws2s, w2s2, t); return; }
  bid -= 108;
  if (bid < 108){ int t = bid*256+tx; if (t < 27648) wprep_dev(ws3s, w2s3, t); return; }
  bid -= 108;
  if (bid < 3456){ int t = bid*256+tx; if (t < GS*GS*GS) grid[t] = -1; return; }
  bid -= 3456;
  if (bid < 171){ nhwc_tile_dev(f1, o1, 80, 96, 1200, bid, 19, lds, tx); return; }
  bid -= 171;
  if (bid < 675){ nhwc_tile_dev(f2, o2, 40, 64, 4800, bid, 75, lds, tx); return; }
  bid -= 675;
  if (bid < 2700){ nhwc_tile_dev(f4, o4, 24, 32, 19200, bid, 300, lds, tx); }
}

// ---- implicit-GEMM conv via MFMA, register path (for f1/f2/1x1) ----
template<int CK, int NT, int TAPS, int MT>
__device__ void conv_dev(
    const ushort* __restrict__ fin, const ushort* __restrict__ w2,
    const float* __restrict__ bias, ushort* __restrict__ outp,
    int H, int W, int total, int Cout, int outStride, int outOff,
    const ushort* __restrict__ skipin, int bid, int tid){
  constexpr int CIN = CK*32;
  constexpr int COP = NT*16;
  int lane = tid & 63;
  int wave = tid >> 6;
  int vbase = bid*(MT*64) + wave*(MT*16);
  int m = lane & 15, q = lane >> 4;
  int HW = H*W;
  int p[MT], py[MT], px[MT]; bool pin[MT];
  #pragma unroll
  for (int t = 0; t < MT; ++t){
    int pp = vbase + t*16 + m;
    pin[t] = pp < total;
    if (pp > total-1) pp = total-1;
    p[t] = pp;
    int v = pp / HW; int rem = pp - v*HW;
    int y = rem / W;
    py[t] = y; px[t] = rem - y*W;
  }
  f32x4v acc[MT][NT];
  #pragma unroll
  for (int t = 0; t < MT; ++t)
    #pragma unroll
    for (int n = 0; n < NT; ++n) acc[t][n] = 0.f;
  bf16x8 z = (short)0;

  #pragma unroll 1
  for (int tap = 0; tap < TAPS; ++tap){
    int dy = (TAPS == 9) ? tap/3 - 1 : 0;
    int dx = (TAPS == 9) ? tap%3 - 1 : 0;
    int off = dy*W + dx;
    bool val[MT];
    #pragma unroll
    for (int t = 0; t < MT; ++t)
      val[t] = pin[t] && ((unsigned)(py[t]+dy) < (unsigned)H)
                      && ((unsigned)(px[t]+dx) < (unsigned)W);
    #pragma unroll
    for (int ck = 0; ck < CK; ++ck){
      bf16x8 Af[MT], Bf[NT];
      #pragma unroll
      for (int t = 0; t < MT; ++t){
        size_t idx = val[t] ? (size_t)(p[t]+off) : 0;
        bf16x8 a = *(const bf16x8*)(fin + idx*CIN + ck*32 + q*8);
        Af[t] = val[t] ? a : z;
      }
      #pragma unroll
      for (int n = 0; n < NT; ++n)
        Bf[n] = *(const bf16x8*)(w2 + ((size_t)((tap*CK+ck)*COP + n*16 + m))*32 + q*8);
      #pragma unroll
      for (int t = 0; t < MT; ++t)
        #pragma unroll
        for (int n = 0; n < NT; ++n)
          acc[t][n] = __builtin_amdgcn_mfma_f32_16x16x32_bf16(Af[t], Bf[n], acc[t][n], 0, 0, 0);
    }
  }

  #pragma unroll
  for (int n = 0; n < NT; ++n){
    int co = n*16 + m;
    bool cok = co < Cout;
    float bs = cok ? bias[co] : 0.f;
    #pragma unroll
    for (int t = 0; t < MT; ++t){
      #pragma unroll
      for (int r = 0; r < 4; ++r){
        int pp = vbase + t*16 + q*4 + r;
        if (pp < total && cok){
          float x = fmaxf(acc[t][n][r] + bs, 0.f);
          if (skipin) x += b2f(skipin[(size_t)pp*CIN + co]);
          outp[(size_t)pp*outStride + outOff + co] = f2b(x);
        }
      }
    }
  }
}

template<int CK, int NT, int TAPS, int MT>
__global__ __launch_bounds__(256) void k_conv_mfma(
    const ushort* __restrict__ fin, const ushort* __restrict__ w2,
    const float* __restrict__ bias, ushort* __restrict__ outp,
    int H, int W, int total, int Cout, int outStride, int outOff,
    const ushort* __restrict__ skipin){
  conv_dev<CK,NT,TAPS,MT>(fin, w2, bias, outp, H, W, total, Cout, outStride, outOff,
                          skipin, blockIdx.x, threadIdx.x);
}

// ---- LDS-tiled 3x3 conv, CIN=32. Tile TH x 16 px, halo patch (TH+2)x18x36 in LDS.
// RPW = TH/4 rows per wave; M-tile = one row of 16 px.
template<int TH, int NT>
__device__ void conv_lds_dev(
    const ushort* __restrict__ fin, const ushort* __restrict__ w2,
    const float* __restrict__ bias, ushort* __restrict__ outp,
    int H, int W, int Cout, int outStride,
    const ushort* __restrict__ skipin, ushort* lds, int bid, int tid){
  constexpr int RPW = TH/4;
  constexpr int PS = 36;             // padded channel stride (18 banks -> 2-way free)
  int xtiles = W >> 4;
  int ytiles = (H + TH - 1) / TH;
  int v  = bid / (ytiles*xtiles);
  int rem = bid - v*(ytiles*xtiles);
  int ty = (rem / xtiles) * TH;
  int tx = (rem % xtiles) * 16;
  const ushort* ibase = fin + (size_t)v*H*W*32;
  // load halo patch (TH+2) x 18 x 32ch
  for (int i = tid; i < (TH+2)*18*4; i += 256){
    int chunk = i & 3;
    int pxi = i >> 2;
    int ly = pxi / 18, lx = pxi - ly*18;
    int gy = ty + ly - 1, gx = tx + lx - 1;
    uint4 d = {0,0,0,0};
    if ((unsigned)gy < (unsigned)H && (unsigned)gx < (unsigned)W)
      d = *(const uint4*)(ibase + ((size_t)gy*W + gx)*32 + chunk*8);
    *(uint4*)(lds + (size_t)(ly*18 + lx)*PS + chunk*8) = d;
  }
  __syncthreads();
  int lane = tid & 63;
  int wave = tid >> 6;
  int m = lane & 15, q = lane >> 4;
  f32x4v acc[RPW][NT];
  #pragma unroll
  for (int t = 0; t < RPW; ++t)
    #pragma unroll
    for (int n = 0; n < NT; ++n) acc[t][n] = 0.f;

  #pragma unroll 1
  for (int tap = 0; tap < 9; ++tap){
    int dy = tap/3 - 1, dx = tap%3 - 1;
    bf16x8 Af[RPW], Bf[NT];
    #pragma unroll
    for (int t = 0; t < RPW; ++t){
      int ly = wave*RPW + t + 1 + dy;
      int lx = m + 1 + dx;
      Af[t] = *(const bf16x8*)(lds + (size_t)(ly*18 + lx)*PS + q*8);
    }
    #pragma unroll
    for (int n = 0; n < NT; ++n)
      Bf[n] = *(const bf16x8*)(w2 + ((size_t)(tap*(NT*16) + n*16 + m))*32 + q*8);
    #pragma unroll
    for (int t = 0; t < RPW; ++t)
      #pragma unroll
      for (int n = 0; n < NT; ++n)
        acc[t][n] = __builtin_amdgcn_mfma_f32_16x16x32_bf16(Af[t], Bf[n], acc[t][n], 0, 0, 0);
  }

  // epilogue: C row = q*4+r (x within row-tile), col = m (out ch within n-tile)
  #pragma unroll
  for (int n = 0; n < NT; ++n){
    int co = n*16 + m;
    bool cok = co < Cout;
    float bs = cok ? bias[co] : 0.f;
    #pragma unroll
    for (int t = 0; t < RPW; ++t){
      int y = ty + wave*RPW + t;
      #pragma unroll
      for (int r = 0; r < 4; ++r){
        int x = tx + q*4 + r;
        if (y < H && cok){
          size_t pp = (size_t)(v*H + y)*W + x;
          float val = fmaxf(acc[t][n][r] + bs, 0.f);
          if (skipin) val += b2f(skipin[pp*32 + co]);
          outp[pp*outStride + co] = f2b(val);
        }
      }
    }
  }
}

// chain conv: TH=4 -> patch 6x18x36 = 7.8 KB, 675 blocks
__global__ __launch_bounds__(256) void k_conv_lds4(
    const ushort* __restrict__ fin, const ushort* __restrict__ w2,
    const float* __restrict__ bias, ushort* __restrict__ outp,
    const ushort* __restrict__ skipin){
  __shared__ ushort lds[6*18*36];
  conv_lds_dev<4,2>(fin, w2, bias, outp, 60, 80, 32, 32, skipin, lds, blockIdx.x, threadIdx.x);
}

// ---- scatter device: grid scatter + coords + sample table + count ----
__device__ void scatter_dev(const int* __restrict__ coords, const int* __restrict__ stage,
                            int* __restrict__ grid, int* __restrict__ scn,
                            float* __restrict__ coords_out,
                            const float* __restrict__ origin, const float* __restrict__ vsz,
                            const float* __restrict__ KR,
                            uint4* __restrict__ samp, float* __restrict__ cnt, int n){
  int c0 = coords[n*4], c1 = coords[n*4+1], c2 = coords[n*4+2], c3 = coords[n*4+3];
  coords_out[n*4+0] = (float)c0;
  coords_out[n*4+1] = (float)c1;
  coords_out[n*4+2] = (float)c2;
  coords_out[n*4+3] = (float)c3;
  int sh = 2 - stage[0];
  int s1 = c1 >> sh, s2 = c2 >> sh, s3 = c3 >> sh;
  scn[n*3+0] = s1; scn[n*3+1] = s2; scn[n*3+2] = s3;
  grid[(s1*GS + s2)*GS + s3] = n;

  float vs = vsz[0];
  float wx = (float)c1*vs + origin[0];
  float wy = (float)c2*vs + origin[1];
  float wz = (float)c3*vs + origin[2];
  float den = 0.f;
  #pragma unroll 1
  for (int v = 0; v < VN; ++v){
    const float* P = KR + v*12;
    float ix = P[0]*wx + P[1]*wy + P[2]*wz + P[3];
    float iy = P[4]*wx + P[5]*wy + P[6]*wz + P[7];
    float iz = P[8]*wx + P[9]*wy + P[10]*wz + P[11];
    float gx = 2.f*(ix/iz)/159.f - 1.f;   // exact div: match reference rounding
    float gy = 2.f*(iy/iz)/119.f - 1.f;
    bool ok = (fabsf(gx) <= 1.f) && (fabsf(gy) <= 1.f) && (iz > 0.f);
    float px = ok ? (gx + 1.f)*0.5f*79.f : 0.f;
    float py = ok ? (gy + 1.f)*0.5f*59.f : 0.f;
    float x0f = floorf(px), y0f = floorf(py);
    float fx = px - x0f, fy = py - y0f;
    int idx = (int)y0f*80 + (int)x0f;
    float mf = ok ? 1.f : 0.f;
    float w00 = (1.f-fx)*(1.f-fy)*mf, w01 = fx*(1.f-fy)*mf;
    float w10 = (1.f-fx)*fy*mf,       w11 = fx*fy*mf;
    uint4 s;
    s.x = (unsigned)idx;
    s.y = (unsigned)f2b(w00) | ((unsigned)f2b(w01) << 16);
    s.z = (unsigned)f2b(w10) | ((unsigned)f2b(w11) << 16);
    s.w = 0;
    samp[(size_t)v*NVOX + n] = s;
    den += mf;
  }
  cnt[n] = den;
}

// ---- merged: f1 conv (169) + f4 LDS conv (720) + f2 conv (675) + scatter (512) ----
__global__ __launch_bounds__(256) void k_heads(
    const ushort* nhwc1, const ushort* wf1, const float* b_f1, ushort* t1,
    const ushort* nhwc2, const ushort* wf2, const float* b_f2, ushort* fcat,
    const ushort* nhwc4, const ushort* wf4, const float* b_f4, ushort* t4,
    const int* coords, const int* stage, int* grid, int* scn, float* coords_out,
    const float* origin, const float* vsz, const float* KR, uint4* samp, float* cnt){
  __shared__ ushort lds[18*18*36];
  int bid = blockIdx.x;
  int tid = threadIdx.x;
  if (bid < 169){ conv_dev<3,5,9,1>(nhwc1, wf1, b_f1, t1, 30, 40, 10800, 80, 80, 0, nullptr, bid, tid); return; }
  bid -= 169;
  if (bid < 720){ conv_lds_dev<16,2>(nhwc4, wf4, b_f4, t4, 120, 160, 24, 24, nullptr, lds, bid, tid); return; }
  bid -= 720;
  if (bid < 675){ conv_dev<2,3,9,1>(nhwc2, wf2, b_f2, fcat, 60, 80, 43200, 40, 160, 80, nullptr, bid, tid); return; }
  bid -= 675;
  { int n = bid*256 + tid;
    scatter_dev(coords, stage, grid, scn, coords_out, origin, vsz, KR, samp, cnt, n); }
}

// ---- merged: resize+pool+padzero (5063 blocks) + slice-split nbr build (2048) ----
__global__ __launch_bounds__(256) void k_respool_nbr(
    const ushort* __restrict__ t1, const ushort* __restrict__ t4, ushort* __restrict__ fc,
    const int* __restrict__ scn, const int* __restrict__ grid,
    int* __restrict__ nbr, unsigned* __restrict__ gmask16){
  __shared__ unsigned m16[4];
  int bid = blockIdx.x;
  int tidx = threadIdx.x;
  if (bid < 5063){
    int tid = bid*256 + tidx;
    if (tid < 864000){
      int c4 = tid % 20;
      int x  = (tid / 20) % 80;
      int y  = (tid / 1600) % 60;
      int v  = tid / 96000;
      int c = c4*4;
      int ky = y >> 1; int y0, y1; float wy0, wy1;
      if ((y & 1) == 0){ y0 = ky-1; y1 = ky; wy0 = 0.25f; wy1 = 0.75f; if (y0 < 0){ y0 = 0; wy0 = 0.f; wy1 = 1.f; } }
      else             { y0 = ky; y1 = ky+1; wy0 = 0.75f; wy1 = 0.25f; if (y1 > 29){ y1 = 29; wy1 = 0.f; wy0 = 1.f; } }
      int kx = x >> 1; int x0, x1; float wx0, wx1;
      if ((x & 1) == 0){ x0 = kx-1; x1 = kx; wx0 = 0.25f; wx1 = 0.75f; if (x0 < 0){ x0 = 0; wx0 = 0.f; wx1 = 1.f; } }
      else             { x0 = kx; x1 = kx+1; wx0 = 0.75f; wx1 = 0.25f; if (x1 > 39){ x1 = 39; wx1 = 0.f; wx0 = 1.f; } }
      float4 a00 = ld4b(t1 + ((size_t)(v*30 + y0)*40 + x0)*80 + c);
      float4 a01 = ld4b(t1 + ((size_t)(v*30 + y0)*40 + x1)*80 + c);
      float4 a10 = ld4b(t1 + ((size_t)(v*30 + y1)*40 + x0)*80 + c);
      float4 a11 = ld4b(t1 + ((size_t)(v*30 + y1)*40 + x1)*80 + c);
      float w00 = wy0*wx0, w01 = wy0*wx1, w10 = wy1*wx0, w11 = wy1*wx1;
      float4 r;
      r.x = w00*a00.x + w01*a01.x + w10*a10.x + w11*a11.x;
      r.y = w00*a00.y + w01*a01.y + w10*a10.y + w11*a11.y;
      r.z = w00*a00.z + w01*a01.z + w10*a10.z + w11*a11.z;
      r.w = w00*a00.w + w01*a01.w + w10*a10.w + w11*a11.w;
      st4b(fc + ((size_t)(v*60 + y)*80 + x)*160 + c, r);
      return;
    }
    int t = tid - 864000;
    if (t >= 432000) return;
    int c4 = t % 10;
    int x  = (t / 10) % 80;
    int y  = (t / 800) % 60;
    int v  = t / 48000;
    if (c4 < 6){
      int c = c4*4;
      const ushort* b0 = t4 + ((size_t)(v*120 + 2*y)*160 + 2*x)*24 + c;
      float4 a = ld4b(b0), b = ld4b(b0 + 24), cc = ld4b(b0 + 160*24), d = ld4b(b0 + 160*24 + 24);
      float4 r;
      r.x = 0.25f*(a.x + b.x + cc.x + d.x);
      r.y = 0.25f*(a.y + b.y + cc.y + d.y);
      r.z = 0.25f*(a.z + b.z + cc.z + d.z);
      r.w = 0.25f*(a.w + b.w + cc.w + d.w);
      st4b(fc + ((size_t)(v*60 + y)*80 + x)*160 + 120 + c, r);
    } else {
      float4 zz = {0.f,0.f,0.f,0.f};
      st4b(fc + ((size_t)(v*60 + y)*80 + x)*160 + 144 + (c4-6)*4, zz);
    }
    return;
  }
  bid -= 5063;
  if (tidx < 4) m16[tidx] = 0;
  __syncthreads();
  int vb = bid*64;
  int lane = tidx & 63;
  int wv = tidx >> 6;
  int n = vb + lane;
  int sx = scn[n*3+0], sy = scn[n*3+1], sz = scn[n*3+2];
  int k0 = wv*7;
  int k1 = min(27, k0 + 7);
  unsigned msk = 0;
  #pragma unroll 1
  for (int k = k0; k < k1; ++k){
    int dx = k/9 - 1, dy = (k/3)%3 - 1, dz = k%3 - 1;
    int nx = sx+dx, ny = sy+dy, nz = sz+dz;
    int idx = -1;
    if (((unsigned)nx < 96u) && ((unsigned)ny < 96u) && ((unsigned)nz < 96u))
      idx = grid[(nx*GS + ny)*GS + nz];
    nbr[(size_t)k*NVOX + n] = idx;
    unsigned long long b = __ballot(idx >= 0);
    unsigned sub = (unsigned)((b >> ((lane >> 4)*16)) & 0xFFFFull);
    if (sub) msk |= (1u << k);
  }
  if ((lane & 15) == 0 && msk) atomicOr(&m16[lane >> 4], msk);
  __syncthreads();
  if (tidx < 4) gmask16[(vb >> 4) + tidx] = m16[tidx];
}

// ---- sampling from table + masked mean/var + bn0 ----
__global__ __launch_bounds__(256) void k_sample(
    const ushort* __restrict__ fuse, const uint4* __restrict__ samp,
    const float* __restrict__ cnt, const float* __restrict__ bn0g,
    const float* __restrict__ bn0b, ushort* __restrict__ F0){
  int tid = blockIdx.x*256 + threadIdx.x;
  int vox = tid >> 3;
  int c4 = tid & 7;
  int c = c4*4;
  float s0=0.f,s1=0.f,s2=0.f,s3=0.f;
  float q0=0.f,q1=0.f,q2=0.f,q3=0.f;
  uint4 sv = samp[vox];
  #pragma unroll 1
  for (int v = 0; v < VN; ++v){
    uint4 svn = sv;
    if (v+1 < VN) svn = samp[(size_t)(v+1)*NVOX + vox];
    float w00 = blo(sv.y), w01 = bhi(sv.y);
    float w10 = blo(sv.z), w11 = bhi(sv.z);
    const ushort* bp = fuse + (size_t)v*153600 + (size_t)sv.x*32 + c;
    float4 a00 = ld4b(bp);
    float4 a01 = ld4b(bp + 32);
    float4 a10 = ld4b(bp + 2560);
    float4 a11 = ld4b(bp + 2592);
    float g0 = w00*a00.x + w01*a01.x + w10*a10.x + w11*a11.x;
    float g1 = w00*a00.y + w01*a01.y + w10*a10.y + w11*a11.y;
    float g2 = w00*a00.z + w01*a01.z + w10*a10.z + w11*a11.z;
    float g3 = w00*a00.w + w01*a01.w + w10*a10.w + w11*a11.w;
    s0 += g0; q0 += g0*g0;
    s1 += g1; q1 += g1*g1;
    s2 += g2; q2 += g2*g2;
    s3 += g3; q3 += g3*g3;
    sv = svn;
  }
  float iden = 1.f/cnt[vox];
  float m0 = s0*iden, m1 = s1*iden, m2 = s2*iden, m3 = s3*iden;
  float4 g = ld4(bn0g + c);
  float4 b = ld4(bn0b + c);
  float4 r;
  r.x = g.x*fmaxf(q0*iden - m0*m0, 0.f)*INVS + b.x;
  r.y = g.y*fmaxf(q1*iden - m1*m1, 0.f)*INVS + b.y;
  r.z = g.z*fmaxf(q2*iden - m2*m2, 0.f)*INVS + b.z;
  r.w = g.w*fmaxf(q3*iden - m3*m3, 0.f)*INVS + b.w;
  st4b(F0 + (size_t)vox*32 + c, r);
}

// ---- subm sparse conv 32->32 via MFMA bf16, 16 vox/wave, 2-deep pipeline ----
template<int MODE>
__global__ __launch_bounds__(256, 8) void k_subm_mfma(
    const ushort* __restrict__ fin, const ushort* __restrict__ w2,
    const int* __restrict__ nbr, const unsigned* __restrict__ gmask16,
    const float* __restrict__ lng, const float* __restrict__ lnb,
    ushort* __restrict__ fout){
  int lane = threadIdx.x & 63;
  int wave = threadIdx.x >> 6;
  int vb = blockIdx.x*64 + wave*16;
  int m = lane & 15;
  int q = lane >> 4;

  f32x4v acc0 = 0.f, acc1 = 0.f;
  bf16x8 zc = (short)0;
  unsigned rem = gmask16[vb >> 4];
  int k0 = -1, k1 = -1;
  int id0 = -1, id1 = -1;
  if (rem){ k0 = __ffs(rem) - 1; rem &= rem - 1; id0 = nbr[(size_t)k0*NVOX + vb + m]; }
  if (rem){ k1 = __ffs(rem) - 1; rem &= rem - 1; id1 = nbr[(size_t)k1*NVOX + vb + m]; }
  bf16x8 A0 = zc;
  if (k0 >= 0){
    bf16x8 a = *(const bf16x8*)(fin + (size_t)(id0 < 0 ? 0 : id0)*32 + q*8);
    A0 = (id0 < 0) ? zc : a;
  }
  while (k0 >= 0){
    bf16x8 A1 = zc;
    if (k1 >= 0){
      bf16x8 a = *(const bf16x8*)(fin + (size_t)(id1 < 0 ? 0 : id1)*32 + q*8);
      A1 = (id1 < 0) ? zc : a;
    }
    int k2 = -1, id2 = -1;
    if (rem){ k2 = __ffs(rem) - 1; rem &= rem - 1; id2 = nbr[(size_t)k2*NVOX + vb + m]; }
    bf16x8 b0 = *(const bf16x8*)(w2 + (size_t)(k0*32 + m)*32 + q*8);
    bf16x8 b1 = *(const bf16x8*)(w2 + (size_t)(k0*32 + 16 + m)*32 + q*8);
    acc0 = __builtin_amdgcn_mfma_f32_16x16x32_bf16(A0, b0, acc0, 0, 0, 0);
    acc1 = __builtin_amdgcn_mfma_f32_16x16x32_bf16(A0, b1, acc1, 0, 0, 0);
    A0 = A1; id1 = id2; k0 = k1; k1 = k2;
  }

  int ch0 = m, ch1 = 16 + m;
  float g0 = 0.f, g1 = 0.f, bb0 = 0.f, bb1 = 0.f;
  if (MODE == 1){ g0 = lng[ch0]; g1 = lng[ch1]; bb0 = lnb[ch0]; bb1 = lnb[ch1]; }
  #pragma unroll
  for (int r = 0; r < 4; ++r){
    int vox = vb + q*4 + r;
    float x0 = fmaxf(acc0[r], 0.f);
    float x1 = fmaxf(acc1[r], 0.f);
    if (MODE == 1){
      x0 += b2f(fin[(size_t)vox*32 + ch0]);
      x1 += b2f(fin[(size_t)vox*32 + ch1]);
      float s = x0 + x1;
      s += __shfl_xor(s, 1, 16);
      s += __shfl_xor(s, 2, 16);
      s += __shfl_xor(s, 4, 16);
      s += __shfl_xor(s, 8, 16);
      float mean = s * (1.f/32.f);
      float d0 = x0 - mean, d1 = x1 - mean;
      float v2 = d0*d0 + d1*d1;
      v2 += __shfl_xor(v2, 1, 16);
      v2 += __shfl_xor(v2, 2, 16);
      v2 += __shfl_xor(v2, 4, 16);
      v2 += __shfl_xor(v2, 8, 16);
      float rs = 1.f / sqrtf(v2*(1.f/32.f) + 1e-5f);
      x0 = d0*rs*g0 + bb0;
      x1 = d1*rs*g1 + bb1;
    }
    fout[(size_t)vox*32 + ch0] = f2b(x0);
    fout[(size_t)vox*32 + ch1] = f2b(x1);
  }
}

// ---- final subm 32->1 + bn, idx prefetch ----
__global__ __launch_bounds__(256) void k_s4(
    const ushort* __restrict__ fin, const float* __restrict__ w4,
    const int* __restrict__ nbr, const unsigned* __restrict__ gmask16,
    const float* __restrict__ bn4g, const float* __restrict__ bn4b,
    float* __restrict__ occ){
  int n = blockIdx.x*256 + threadIdx.x;
  if (n >= NVOX) return;
  unsigned rem = gmask16[n >> 4];
  float acc = 0.f;
  int k = -1, idx = -1;
  if (rem){ k = __ffs(rem) - 1; rem &= rem - 1; idx = nbr[(size_t)k*NVOX + n]; }
  while (k >= 0){
    int k2 = -1, idx2 = -1;
    if (rem){ k2 = __ffs(rem) - 1; rem &= rem - 1; idx2 = nbr[(size_t)k2*NVOX + n]; }
    if (idx >= 0){
      const uint4* r4 = (const uint4*)(fin + (size_t)idx*32);
      const float* wk = w4 + k*32;
      #pragma unroll
      for (int u = 0; u < 4; ++u){
        uint4 d = r4[u];
        const float* w8 = wk + u*8;
        acc += blo(d.x)*w8[0] + bhi(d.x)*w8[1];
        acc += blo(d.y)*w8[2] + bhi(d.y)*w8[3];
        acc += blo(d.z)*w8[4] + bhi(d.z)*w8[5];
        acc += blo(d.w)*w8[6] + bhi(d.w)*w8[7];
      }
    }
    k = k2; idx = idx2;
  }
  occ[n] = bn4g[0]*acc*INVS + bn4b[0];
}

extern "C" void kernel_launch(void* const* d_in, const int* in_sizes, int n_in,
                              void* d_out, int out_size, void* d_ws, size_t ws_size,
                              hipStream_t stream){
  const float* feats1 = (const float*)d_in[0];
  const float* feats2 = (const float*)d_in[1];
  const float* feats4 = (const float*)d_in[2];
  const int*   coords = (const int*)d_in[3];
  const float* origin = (const float*)d_in[4];
  const float* vsz    = (const float*)d_in[5];
  const float* KR     = (const float*)d_in[6];
  const float* w_f1 = (const float*)d_in[7];  const float* b_f1 = (const float*)d_in[8];
  const float* w_f2 = (const float*)d_in[9];  const float* b_f2 = (const float*)d_in[10];
  const float* w_f4 = (const float*)d_in[11]; const float* b_f4 = (const float*)d_in[12];
  const float* w_dn = (const float*)d_in[13]; const float* b_dn = (const float*)d_in[14];
  const float* w_p[4] = {(const float*)d_in[15], (const float*)d_in[17],
                         (const float*)d_in[19], (const float*)d_in[21]};
  const float* b_p[4] = {(const float*)d_in[16], (const float*)d_in[18],
                         (const float*)d_in[20], (const float*)d_in[22]};
  const float* bn0g = (const float*)d_in[23]; const float* bn0b = (const float*)d_in[24];
  const float* w_elan = (const float*)d_in[25];
  const float* w_s1 = (const float*)d_in[26]; const float* ln1g = (const float*)d_in[27]; const float* ln1b = (const float*)d_in[28];
  const float* w_s2 = (const float*)d_in[29]; const float* ln2g = (const float*)d_in[30]; const float* ln2b = (const float*)d_in[31];
  const float* w_s3 = (const float*)d_in[32]; const float* ln3g = (const float*)d_in[33]; const float* ln3b = (const float*)d_in[34];
  const float* w_s4 = (const float*)d_in[35]; const float* bn4g = (const float*)d_in[36]; const float* bn4b = (const float*)d_in[37];
  const int* stage  = (const int*)d_in[38];
  float* out = (float*)d_out;
  char* base = (char*)d_ws;

  size_t off = 0;
  auto alloc = [&](size_t bytes)->char*{ char* p = base + off; off += (bytes + 255) & ~(size_t)255; return p; };
  ushort* nhwc1 = (ushort*)alloc((size_t)9*30*40*96*2);
  ushort* nhwc2 = (ushort*)alloc((size_t)9*60*80*64*2);
  ushort* nhwc4 = (ushort*)alloc((size_t)9*120*160*32*2);
  ushort* t1    = (ushort*)alloc((size_t)9*30*40*80*2);
  ushort* t4    = (ushort*)alloc((size_t)9*120*160*24*2);
  ushort* fcat  = (ushort*)alloc((size_t)9*60*80*160*2);
  ushort* A     = (ushort*)alloc((size_t)9*60*80*32*2);
  ushort* B     = (ushort*)alloc((size_t)9*60*80*32*2);
  ushort* Fb0   = (ushort*)alloc((size_t)NVOX*32*2);
  ushort* Fb1   = (ushort*)alloc((size_t)NVOX*32*2);
  int*    nbr   = (int*)alloc((size_t)27*NVOX*4);
  int*    grid  = (int*)alloc((size_t)GS*GS*GS*4);
  int*    scn   = (int*)alloc((size_t)NVOX*3*4);
  unsigned* gmask16 = (unsigned*)alloc((size_t)(NVOX/16)*4);
  ushort* wf1   = (ushort*)alloc(9*3*80*32*2);
  ushort* wf2   = (ushort*)alloc(9*2*48*32*2);
  ushort* wf4   = (ushort*)alloc(9*1*32*32*2);
  ushort* wdn   = (ushort*)alloc(1*5*32*32*2);
  ushort* wp0   = (ushort*)alloc(9*1*32*32*2);
  ushort* wp1   = (ushort*)alloc(9*1*32*32*2);
  ushort* wp2   = (ushort*)alloc(9*1*32*32*2);
  ushort* wp3   = (ushort*)alloc(9*1*32*32*2);
  ushort* w2e   = (ushort*)alloc(27*1024*2);
  ushort* w2s1  = (ushort*)alloc(27*1024*2);
  ushort* w2s2  = (ushort*)alloc(27*1024*2);
  ushort* w2s3  = (ushort*)alloc(27*1024*2);
  uint4* samp = (uint4*)alloc((size_t)VN*NVOX*16);  // dedicated 18.9 MB

  auto nb = [](int total){ return (total + 255)/256; };

  // 1. mega prep
  k_prep<<<8012,256,0,stream>>>(
      w_f1, w_f2, w_f4, w_dn, w_p[0], w_p[1], w_p[2], w_p[3],
      w_elan, w_s1, w_s2, w_s3,
      wf1, wf2, wf4, wdn, wp0, wp1, wp2, wp3, w2e, w2s1, w2s2, w2s3, grid,
      feats1, feats2, feats4, nhwc1, nhwc2, nhwc4);

  // 2. head convs (f1 reg-path, f4 LDS-tiled, f2 reg-path) + scatter
  k_heads<<<169 + 720 + 675 + 512,256,0,stream>>>(
      nhwc1, wf1, b_f1, t1,
      nhwc2, wf2, b_f2, fcat,
      nhwc4, wf4, b_f4, t4,
      coords, stage, grid, scn, out + NVOX,
      origin, vsz, KR, samp, out + 5*NVOX);

  // 3. respool + nbr build
  k_respool_nbr<<<5063 + 2048,256,0,stream>>>(t1, t4, fcat, scn, grid, nbr, gmask16);

  // 4-8. down conv (1x1 reg-path) + 4 LDS-tiled residual convs
  k_conv_mfma<5,2,1,1><<<675,256,0,stream>>>(fcat, wdn, b_dn, A, 60, 80, 43200, 32, 32, 0, nullptr);
  k_conv_lds4<<<675,256,0,stream>>>(A, wp0, b_p[0], B, A);
  k_conv_lds4<<<675,256,0,stream>>>(B, wp1, b_p[1], A, B);
  k_conv_lds4<<<675,256,0,stream>>>(A, wp2, b_p[2], B, A);
  k_conv_lds4<<<675,256,0,stream>>>(B, wp3, b_p[3], A, B);

  // 9. sampling -> F0
  k_sample<<<NVOX/32,256,0,stream>>>(A, samp, out + 5*NVOX, bn0g, bn0b, Fb0);

  // 10-13. sparse conv stack
  k_subm_mfma<0><<<NVOX/64,256,0,stream>>>(Fb0, w2e,  nbr, gmask16, nullptr, nullptr, Fb1);
  k_subm_mfma<1><<<NVOX/64,256,0,stream>>>(Fb1, w2s1, nbr, gmask16, ln1g, ln1b, Fb0);
  k_subm_mfma<1><<<NVOX/64,256,0,stream>>>(Fb0, w2s2, nbr, gmask16, ln2g, ln2b, Fb1);
  k_subm_mfma<1><<<NVOX/64,256,0,stream>>>(Fb1, w2s3, nbr, gmask16, ln3g, ln3b, Fb0);

  // 14. final head
  k_s4<<<nb(NVOX),256,0,stream>>>(Fb0, w_s4, nbr, gmask16, bn4g, bn4b, out);
}